// Round 1
// baseline (951.424 us; speedup 1.0000x reference)
//
#include <hip/hip_runtime.h>
#include <hip/hip_bf16.h>
#include <math.h>

typedef __bf16 bf16;
typedef __bf16 v8bf __attribute__((ext_vector_type(8)));
typedef __bf16 v4bf __attribute__((ext_vector_type(4)));
typedef float f32x4 __attribute__((ext_vector_type(4)));

// ---------------------------------------------------------------------------
// Shared MFMA core: 128x128 block tile, BK=64, 256 threads = 4 waves (2x2 of
// 64x64 per-wave tiles). LDS tiles are [128 rows][128 bytes] bf16 with XOR
// swizzle: physical colbyte = logical colbyte ^ ((row&7)<<4).
// MFMA 16x16x32 bf16: A row = lane&15, B col = lane&15, 8 consecutive k per
// lane at colbyte 16*(lane>>4); C/D: col=lane&15, row=4*(lane>>4)+reg.
// ---------------------------------------------------------------------------
__device__ __forceinline__ void tile_compute(const char* ldsA, const char* ldsB,
                                             f32x4 (&acc)[4][4], int wr, int wc, int lane) {
  const int l15 = lane & 15;
  const int colb = (lane >> 4) << 4;
  #pragma unroll
  for (int kk = 0; kk < 2; ++kk) {
    v8bf a[4], b[4];
    #pragma unroll
    for (int i = 0; i < 4; ++i) {
      int ra = wr * 64 + i * 16 + l15;
      int ca = ((kk << 6) | colb) ^ ((ra & 7) << 4);
      a[i] = *(const v8bf*)(ldsA + ra * 128 + ca);
    }
    #pragma unroll
    for (int j = 0; j < 4; ++j) {
      int rb = wc * 64 + j * 16 + l15;
      int cb = ((kk << 6) | colb) ^ ((rb & 7) << 4);
      b[j] = *(const v8bf*)(ldsB + rb * 128 + cb);
    }
    #pragma unroll
    for (int i = 0; i < 4; ++i)
      #pragma unroll
      for (int j = 0; j < 4; ++j)
        acc[i][j] = __builtin_amdgcn_mfma_f32_16x16x32_bf16(a[i], b[j], acc[i][j], 0, 0, 0);
  }
}

template<typename OutT, bool RELU>
__device__ __forceinline__ void store_tile(OutT* __restrict__ C, int m0, int c0,
                                           f32x4 (&acc)[4][4], int lane) {
  const int rbase = (lane >> 4) << 2;
  const int cl = lane & 15;
  #pragma unroll
  for (int i = 0; i < 4; ++i)
    #pragma unroll
    for (int j = 0; j < 4; ++j)
      #pragma unroll
      for (int r = 0; r < 4; ++r) {
        float v = acc[i][j][r];
        if (RELU) v = fmaxf(v, 0.f);
        C[(size_t)(m0 + i * 16 + rbase + r) * 512 + (c0 + j * 16 + cl)] = (OutT)v;
      }
}

// ---------------------------------------------------------------------------
// G1: 1x1 reduce conv + ReLU.  A (chunk of 8192 rows) = interact^T bf16
// [m][2304], B = w_reduce bf16 [512][2304].  Out f1 bf16 NHWC [32768][512].
// ---------------------------------------------------------------------------
__global__ __launch_bounds__(256)
void k_gemm_reduce(const bf16* __restrict__ A, const bf16* __restrict__ B,
                   bf16* __restrict__ f1, int mbase)
{
  __shared__ __attribute__((aligned(16))) char lds[32768];
  char* ldsA = lds; char* ldsB = lds + 16384;
  const int t = threadIdx.x, lane = t & 63, w = t >> 6, wr = w >> 1, wc = w & 1;
  const int tr = t >> 3;
  const int clog = (t & 7) << 4;
  const int cphys = clog ^ ((tr & 7) << 4);
  const bf16* pa[4]; const bf16* pb[4]; int ldso[4];
  #pragma unroll
  for (int i = 0; i < 4; ++i) {
    int r = i * 32 + tr;
    ldso[i] = r * 128 + cphys;
    pa[i] = A + (size_t)(blockIdx.x * 128 + r) * 2304 + (clog >> 1);
    pb[i] = B + (size_t)(blockIdx.y * 128 + r) * 2304 + (clog >> 1);
  }
  f32x4 acc[4][4] = {};
  v8bf ra[4], rb[4];
  #pragma unroll
  for (int i = 0; i < 4; ++i) { ra[i] = *(const v8bf*)pa[i]; rb[i] = *(const v8bf*)pb[i]; }
  for (int k0 = 0; k0 < 2304; k0 += 64) {
    __syncthreads();
    #pragma unroll
    for (int i = 0; i < 4; ++i) { *(v8bf*)(ldsA + ldso[i]) = ra[i]; *(v8bf*)(ldsB + ldso[i]) = rb[i]; }
    __syncthreads();
    if (k0 + 64 < 2304) {
      #pragma unroll
      for (int i = 0; i < 4; ++i) {
        ra[i] = *(const v8bf*)(pa[i] + k0 + 64);
        rb[i] = *(const v8bf*)(pb[i] + k0 + 64);
      }
    }
    tile_compute(ldsA, ldsB, acc, wr, wc, lane);
  }
  store_tile<bf16, true>(f1, mbase + blockIdx.x * 128 + wr * 64,
                         blockIdx.y * 128 + wc * 64, acc, lane);
}

// ---------------------------------------------------------------------------
// G2: 3x3 VALID conv (16x16 -> 14x14), implicit GEMM over 9 taps x 512.
// f1 bf16 NHWC [n*256 + y*16+x][512]; wt [tap][co][ci] bf16; out f14 f32
// NHWC [n*196 + y*14+x][512].
// ---------------------------------------------------------------------------
__global__ __launch_bounds__(256)
void k_conv_rsize(const bf16* __restrict__ f1, const bf16* __restrict__ wt,
                  float* __restrict__ f14)
{
  __shared__ __attribute__((aligned(16))) char lds[32768];
  char* ldsA = lds; char* ldsB = lds + 16384;
  const int t = threadIdx.x, lane = t & 63, w = t >> 6, wr = w >> 1, wc = w & 1;
  const int tr = t >> 3;
  const int clog = (t & 7) << 4;
  const int cphys = clog ^ ((tr & 7) << 4);
  int ldso[4], base[4]; const bf16* pb[4];
  #pragma unroll
  for (int i = 0; i < 4; ++i) {
    int r = i * 32 + tr;
    ldso[i] = r * 128 + cphys;
    int m = blockIdx.x * 128 + r;
    int n = m / 196, rem = m - n * 196;
    int y = rem / 14, x = rem - (rem / 14) * 14;
    base[i] = n * 256 + y * 16 + x;
    pb[i] = wt + (size_t)(blockIdx.y * 128 + r) * 512 + (clog >> 1);
  }
  f32x4 acc[4][4] = {};
  v8bf ra[4], rb[4];
  auto loadAB = [&](int ks) {
    int tap = ks >> 3, koff = (ks & 7) << 6;
    int dy = tap / 3, dx = tap - dy * 3;
    #pragma unroll
    for (int i = 0; i < 4; ++i) {
      ra[i] = *(const v8bf*)(f1 + (size_t)(base[i] + dy * 16 + dx) * 512 + koff + (clog >> 1));
      rb[i] = *(const v8bf*)(pb[i] + (size_t)tap * 262144 + koff);
    }
  };
  loadAB(0);
  for (int ks = 0; ks < 72; ++ks) {
    __syncthreads();
    #pragma unroll
    for (int i = 0; i < 4; ++i) { *(v8bf*)(ldsA + ldso[i]) = ra[i]; *(v8bf*)(ldsB + ldso[i]) = rb[i]; }
    __syncthreads();
    if (ks + 1 < 72) loadAB(ks + 1);
    tile_compute(ldsA, ldsB, acc, wr, wc, lane);
  }
  store_tile<float, false>(f14, blockIdx.x * 128 + wr * 64,
                           blockIdx.y * 128 + wc * 64, acc, lane);
}

// ---------------------------------------------------------------------------
// G4/G5: 3x3 SAME conv (pad=1) on 7x7. fin bf16 NHWC [n*49 + y*7+x][512];
// invalid taps read a zero page. Out = q/k/v (bf16) or virt2 (f32).
// ---------------------------------------------------------------------------
template<typename OutT>
__global__ __launch_bounds__(256)
void k_conv_pad(const bf16* __restrict__ fin, const bf16* __restrict__ wt,
                OutT* __restrict__ outp, const bf16* __restrict__ zp)
{
  __shared__ __attribute__((aligned(16))) char lds[32768];
  char* ldsA = lds; char* ldsB = lds + 16384;
  const int t = threadIdx.x, lane = t & 63, w = t >> 6, wr = w >> 1, wc = w & 1;
  const int tr = t >> 3;
  const int clog = (t & 7) << 4;
  const int cphys = clog ^ ((tr & 7) << 4);
  int ldso[4], nn[4], yy[4], xx[4]; const bf16* pb[4];
  #pragma unroll
  for (int i = 0; i < 4; ++i) {
    int r = i * 32 + tr;
    ldso[i] = r * 128 + cphys;
    int m = blockIdx.x * 128 + r;
    int n = m / 49, rem = m - n * 49;
    nn[i] = n; yy[i] = rem / 7; xx[i] = rem - 7 * (rem / 7);
    pb[i] = wt + (size_t)(blockIdx.y * 128 + r) * 512 + (clog >> 1);
  }
  f32x4 acc[4][4] = {};
  v8bf ra[4], rb[4];
  auto loadAB = [&](int ks) {
    int tap = ks >> 3, koff = (ks & 7) << 6;
    int dy = tap / 3, dx = tap - dy * 3;
    #pragma unroll
    for (int i = 0; i < 4; ++i) {
      int iy = yy[i] + dy - 1, ix = xx[i] + dx - 1;
      const bf16* p = ((unsigned)iy < 7u && (unsigned)ix < 7u)
          ? fin + (size_t)(nn[i] * 49 + iy * 7 + ix) * 512 + koff + (clog >> 1)
          : zp;
      ra[i] = *(const v8bf*)p;
      rb[i] = *(const v8bf*)(pb[i] + (size_t)tap * 262144 + koff);
    }
  };
  loadAB(0);
  for (int ks = 0; ks < 72; ++ks) {
    __syncthreads();
    #pragma unroll
    for (int i = 0; i < 4; ++i) { *(v8bf*)(ldsA + ldso[i]) = ra[i]; *(v8bf*)(ldsB + ldso[i]) = rb[i]; }
    __syncthreads();
    if (ks + 1 < 72) loadAB(ks + 1);
    tile_compute(ldsA, ldsB, acc, wr, wc, lane);
  }
  store_tile<OutT, false>(outp, blockIdx.x * 128 + wr * 64,
                          blockIdx.y * 128 + wc * 64, acc, lane);
}

// ---------------------------------------------------------------------------
// P0: per-chunk transpose+cast interact_feat (n,2304,256) f32 -> A1 bf16
// rows (nl*256+p) x 2304. grid (72, 8, 32), block 256, 32x32 LDS tiles.
// ---------------------------------------------------------------------------
__global__ void k_tin(const float* __restrict__ in, bf16* __restrict__ A1, int n0)
{
  __shared__ float tile[32][33];
  const int k0 = blockIdx.x * 32, p0 = blockIdx.y * 32, nl = blockIdx.z;
  const int n = n0 + nl;
  const int r = threadIdx.x >> 5, c = threadIdx.x & 31;
  const float* src = in + (size_t)n * 2304 * 256;
  #pragma unroll
  for (int rr = r; rr < 32; rr += 8) tile[rr][c] = src[(size_t)(k0 + rr) * 256 + p0 + c];
  __syncthreads();
  bf16* dst = A1 + (size_t)nl * 256 * 2304;
  #pragma unroll
  for (int rr = r; rr < 32; rr += 8) dst[(size_t)(p0 + rr) * 2304 + k0 + c] = (bf16)tile[c][rr];
}

// P1: cast w_reduce f32 -> bf16 (same (co,ci) layout)
__global__ void k_castw(const float* __restrict__ wsrc, bf16* __restrict__ wb, int nelem)
{
  int idx = (blockIdx.x * 256 + threadIdx.x) * 4;
  if (idx >= nelem) return;
  float4 v = *(const float4*)(wsrc + idx);
  v4bf o; o[0] = (bf16)v.x; o[1] = (bf16)v.y; o[2] = (bf16)v.z; o[3] = (bf16)v.w;
  *(v4bf*)(wb + idx) = o;
}

// P2: transpose+cast the five 3x3 weights (co,ci,3,3) -> [tensor][tap][co][ci]
__global__ void k_wtrans(const float* __restrict__ s0, const float* __restrict__ s1,
                         const float* __restrict__ s2, const float* __restrict__ s3,
                         const float* __restrict__ s4, bf16* __restrict__ wt)
{
  const float* src;
  switch (blockIdx.y) {
    case 0: src = s0; break; case 1: src = s1; break; case 2: src = s2; break;
    case 3: src = s3; break; default: src = s4; break;
  }
  bf16* dst = wt + (size_t)blockIdx.y * 2359296;
  int q = blockIdx.x * 256 + threadIdx.x;   // (co*512+ci), 0..262143
  const float* sp = src + (size_t)q * 9;
  float tmp[9];
  #pragma unroll
  for (int e = 0; e < 9; ++e) tmp[e] = sp[e];
  #pragma unroll
  for (int e = 0; e < 9; ++e) dst[(size_t)e * 262144 + q] = (bf16)tmp[e];
}

// K3: maxpool 3x3 stride2 pad1, 14x14 -> 7x7 (NHWC), dual bf16+f32 outputs.
__global__ void k_pool(const float* __restrict__ f14, bf16* __restrict__ f7b,
                       float* __restrict__ f7f)
{
  int idx = blockIdx.x * 256 + threadIdx.x;   // 128*49*512 = 3211264 exact
  int c = idx & 511;
  int pp = idx >> 9;
  int n = pp / 49, p7 = pp - n * 49;
  int y = p7 / 7, x = p7 - 7 * (p7 / 7);
  int y0 = 2 * y - 1, x0 = 2 * x - 1;
  float mx = -3.4e38f;
  #pragma unroll
  for (int dy = 0; dy < 3; ++dy) {
    int iy = y0 + dy; if ((unsigned)iy >= 14u) continue;
    #pragma unroll
    for (int dx = 0; dx < 3; ++dx) {
      int ix = x0 + dx; if ((unsigned)ix >= 14u) continue;
      mx = fmaxf(mx, f14[(size_t)(n * 196 + iy * 14 + ix) * 512 + c]);
    }
  }
  f7f[idx] = mx;
  f7b[idx] = (bf16)mx;
}

// K5: group attention. grid (49 pixels, 16 groups). 8x8 scores, softmax, PV.
__global__ __launch_bounds__(256)
void k_attn(const bf16* __restrict__ q, const bf16* __restrict__ k,
            const bf16* __restrict__ v, const float* __restrict__ rois,
            float* __restrict__ virt)
{
  const int p = blockIdx.x, g = blockIdx.y, t = threadIdx.x;
  __shared__ float sS[8][9];
  __shared__ float sP[8][9];
  __shared__ __attribute__((aligned(16))) bf16 sV[8][512];
  // stage V rows for the group
  {
    int u = t;
    #pragma unroll
    for (int rep = 0; rep < 2; ++rep, u += 256) {
      int j = u >> 6, ch = u & 63;
      *(v8bf*)&sV[j][ch * 8] = *(const v8bf*)(v + ((size_t)(g * 8 + j) * 49 + p) * 512 + ch * 8);
    }
  }
  // 64 dots, 4 lanes each
  int pi = t >> 2, ls = t & 3;
  int i = pi >> 3, j = pi & 7;
  const bf16* qi = q + ((size_t)(g * 8 + i) * 49 + p) * 512;
  const bf16* kj = k + ((size_t)(g * 8 + j) * 49 + p) * 512;
  float s = 0.f;
  for (int ch = ls * 16; ch < ls * 16 + 16; ++ch) {
    v8bf a = *(const v8bf*)(qi + ch * 8);
    v8bf b = *(const v8bf*)(kj + ch * 8);
    #pragma unroll
    for (int e = 0; e < 8; ++e) s += (float)a[e] * (float)b[e];
  }
  s += __shfl_xor(s, 1);
  s += __shfl_xor(s, 2);
  if (ls == 0) sS[i][j] = s * 0.04419417382415922f;   // 1/sqrt(512)
  __syncthreads();
  if (t < 8) {
    float gi = rois[(g * 8 + t) * 5];
    float pv[8]; float mx = -3.4e38f;
    #pragma unroll
    for (int jj = 0; jj < 8; ++jj) {
      float gj = rois[(g * 8 + jj) * 5];
      float sv = (gi == gj) ? sS[t][jj] : -1e30f;
      pv[jj] = sv; mx = fmaxf(mx, sv);
    }
    float sum = 0.f;
    #pragma unroll
    for (int jj = 0; jj < 8; ++jj) { float e = expf(pv[jj] - mx); pv[jj] = e; sum += e; }
    float inv = 1.f / sum;
    #pragma unroll
    for (int jj = 0; jj < 8; ++jj) sP[t][jj] = pv[jj] * inv;
  }
  __syncthreads();
  int i2 = t >> 5, c0 = (t & 31) * 16;
  float o[16];
  #pragma unroll
  for (int e = 0; e < 16; ++e) o[e] = 0.f;
  #pragma unroll
  for (int jj = 0; jj < 8; ++jj) {
    float ww = sP[i2][jj];
    v8bf v0 = *(const v8bf*)&sV[jj][c0];
    v8bf v1 = *(const v8bf*)&sV[jj][c0 + 8];
    #pragma unroll
    for (int e = 0; e < 8; ++e) { o[e] += ww * (float)v0[e]; o[8 + e] += ww * (float)v1[e]; }
  }
  float* dst = virt + ((size_t)(g * 8 + i2) * 49 + p) * 512 + c0;
  #pragma unroll
  for (int e = 0; e < 16; ++e) dst[e] = o[e];
}

// K6: per-sample LN stats over 49*512 elems
__global__ __launch_bounds__(256)
void k_lnstats(const float* __restrict__ virt, float* __restrict__ stats)
{
  int n = blockIdx.x, t = threadIdx.x;
  const float* p = virt + (size_t)n * 25088;
  float s1 = 0.f, s2 = 0.f;
  for (int idx = t; idx < 25088; idx += 256) { float x = p[idx]; s1 += x; s2 += x * x; }
  __shared__ float r1[256], r2[256];
  r1[t] = s1; r2[t] = s2; __syncthreads();
  for (int off = 128; off; off >>= 1) {
    if (t < off) { r1[t] += r1[t + off]; r2[t] += r2[t + off]; }
    __syncthreads();
  }
  if (t == 0) {
    float mu = r1[0] * (1.f / 25088.f);
    float var = r2[0] * (1.f / 25088.f) - mu * mu;
    stats[2 * n] = mu;
    stats[2 * n + 1] = rsqrtf(var + 1e-5f);
  }
}

// K7: LN apply + gamma/beta + ReLU -> bf16
__global__ void k_lnapply(const float* __restrict__ virt, const float* __restrict__ stats,
                          const float* __restrict__ gamma, const float* __restrict__ beta,
                          bf16* __restrict__ virtn)
{
  int idx = blockIdx.x * 256 + threadIdx.x;   // 3211264 exact
  int c = idx & 511;
  int n = (idx >> 9) / 49;
  float mu = stats[2 * n], rstd = stats[2 * n + 1];
  float y = (virt[idx] - mu) * rstd * gamma[c] + beta[c];
  virtn[idx] = (bf16)fmaxf(y, 0.f);
}

// K9: ho = mean over 49 pixels of (f7 + virt2) -> out[:, 0:512]
__global__ void k_ho(const float* __restrict__ f7f, const float* __restrict__ virt2,
                     float* __restrict__ out)
{
  int n = blockIdx.x, t = threadIdx.x;
  for (int c = t; c < 512; c += 256) {
    const float* a = f7f + (size_t)n * 25088 + c;
    const float* b = virt2 + (size_t)n * 25088 + c;
    float s = 0.f;
    for (int pp = 0; pp < 49; ++pp) s += a[pp * 512] + b[pp * 512];
    out[n * 1024 + c] = s * (1.f / 49.f);
  }
}

// K10a: obm = mean bbox_feat over 196
__global__ void k_obm(const float* __restrict__ bbox, float* __restrict__ obm)
{
  int n = blockIdx.x, t = threadIdx.x;
  for (int cb = t; cb < 1024; cb += 256) {
    const float4* p4 = (const float4*)(bbox + (size_t)(n * 1024 + cb) * 196);
    float s = 0.f;
    for (int e = 0; e < 49; ++e) { float4 w = p4[e]; s += w.x + w.y + w.z + w.w; }
    obm[n * 1024 + cb] = s * (1.f / 196.f);
  }
}

// K10b: fc + relu -> out[:, 512:1024]
__global__ __launch_bounds__(256)
void k_fc(const float* __restrict__ obm, const float* __restrict__ wfc,
          float* __restrict__ out)
{
  int n = blockIdx.x, t = threadIdx.x;
  __shared__ float sO[1024];
  for (int u = t; u < 1024; u += 256) sO[u] = obm[n * 1024 + u];
  __syncthreads();
  for (int jj = t; jj < 512; jj += 256) {
    const float4* wp = (const float4*)(wfc + (size_t)jj * 1024);
    float s = 0.f;
    for (int c4 = 0; c4 < 256; ++c4) {
      float4 w = wp[c4];
      s += w.x * sO[c4 * 4] + w.y * sO[c4 * 4 + 1] + w.z * sO[c4 * 4 + 2] + w.w * sO[c4 * 4 + 3];
    }
    out[n * 1024 + 512 + jj] = fmaxf(s, 0.f);
  }
}

// ---------------------------------------------------------------------------
extern "C" void kernel_launch(void* const* d_in, const int* in_sizes, int n_in,
                              void* d_out, int out_size, void* d_ws, size_t ws_size,
                              hipStream_t stream) {
  const float* rois     = (const float*)d_in[0];
  const float* interact = (const float*)d_in[1];
  const float* bbox     = (const float*)d_in[2];
  const float* w_reduce = (const float*)d_in[3];
  const float* w_rsize  = (const float*)d_in[4];
  const float* wq       = (const float*)d_in[5];
  const float* wk       = (const float*)d_in[6];
  const float* wv       = (const float*)d_in[7];
  const float* w1       = (const float*)d_in[8];
  const float* gamma    = (const float*)d_in[9];
  const float* beta     = (const float*)d_in[10];
  const float* wfc      = (const float*)d_in[11];
  float* out = (float*)d_out;
  char* ws = (char*)d_ws;

  // workspace layout (time-aliased regions; total ~150 MB)
  size_t o = 0;
  auto take = [&](size_t sz) { size_t r = o; o += (sz + 255) & ~(size_t)255; return r; };
  char*  R1    = ws + take(51380224);  // A1 chunk (37.7MB) -> f14 (51.4MB) -> virt2 (12.8MB)
  char*  R2    = ws + take(33554432);  // f1 (33.6MB) -> q,k,v (3x6.4MB)
  bf16*  wrb   = (bf16*)(ws + take(2359296));
  bf16*  wt    = (bf16*)(ws + take(23592960));  // [5][9][512][512] bf16
  bf16*  f7b   = (bf16*)(ws + take(6422528));
  float* f7f   = (float*)(ws + take(12845056));
  float* virt  = (float*)(ws + take(12845056));
  float* stats = (float*)(ws + take(1024));
  bf16*  virtn = (bf16*)(ws + take(6422528));
  float* obm   = (float*)(ws + take(524288));
  bf16*  zp    = (bf16*)(ws + take(256));

  bf16*  A1    = (bf16*)R1;
  float* f14   = (float*)R1;
  float* virt2 = (float*)R1;
  bf16*  f1    = (bf16*)R2;
  bf16*  qb    = (bf16*)R2;
  bf16*  kb    = (bf16*)(R2 + 6422528);
  bf16*  vb    = (bf16*)(R2 + 12845056);

  hipMemsetAsync(zp, 0, 256, stream);

  // weight prep
  k_castw<<<1152, 256, 0, stream>>>(w_reduce, wrb, 1179648);
  k_wtrans<<<dim3(1024, 5), 256, 0, stream>>>(w_rsize, wq, wk, wv, w1, wt);

  // reduce conv in 4 chunks of 32 images (A1 buffer reuse is stream-ordered)
  for (int ch = 0; ch < 4; ++ch) {
    k_tin<<<dim3(72, 8, 32), 256, 0, stream>>>(interact, A1, ch * 32);
    k_gemm_reduce<<<dim3(64, 4), 256, 0, stream>>>(A1, wrb, f1, ch * 8192);
  }

  // rsize conv (valid) + pool
  k_conv_rsize<<<dim3(196, 4), 256, 0, stream>>>(f1, wt, f14);
  k_pool<<<12544, 256, 0, stream>>>(f14, f7b, f7f);

  // q/k/v convs (pad=1)
  k_conv_pad<bf16><<<dim3(49, 4), 256, 0, stream>>>(f7b, wt + (size_t)1 * 2359296, qb, zp);
  k_conv_pad<bf16><<<dim3(49, 4), 256, 0, stream>>>(f7b, wt + (size_t)2 * 2359296, kb, zp);
  k_conv_pad<bf16><<<dim3(49, 4), 256, 0, stream>>>(f7b, wt + (size_t)3 * 2359296, vb, zp);

  // group attention -> virt
  k_attn<<<dim3(49, 16), 256, 0, stream>>>(qb, kb, vb, rois, virt);

  // layernorm + relu
  k_lnstats<<<128, 256, 0, stream>>>(virt, stats);
  k_lnapply<<<12544, 256, 0, stream>>>(virt, stats, gamma, beta, virtn);

  // w1 conv (pad=1) -> virt2 (f32)
  k_conv_pad<float><<<dim3(49, 4), 256, 0, stream>>>(virtn, wt + (size_t)4 * 2359296, virt2, zp);

  // heads
  k_ho<<<128, 256, 0, stream>>>(f7f, virt2, out);
  k_obm<<<128, 256, 0, stream>>>(bbox, obm);
  k_fc<<<128, 256, 0, stream>>>(obm, wfc, out);
}

// Round 2
// 839.162 us; speedup vs baseline: 1.1338x; 1.1338x over previous
//
#include <hip/hip_runtime.h>
#include <hip/hip_bf16.h>
#include <math.h>

typedef __bf16 bf16;
typedef __bf16 v8bf __attribute__((ext_vector_type(8)));
typedef float f32x4 __attribute__((ext_vector_type(4)));

// async global->LDS, 16B per lane. LDS dest is wave-uniform base + lane*16.
#define GLDS16(g, l) __builtin_amdgcn_global_load_lds( \
    (const __attribute__((address_space(1))) void*)(g), \
    (__attribute__((address_space(3))) void*)(l), 16, 0, 0)

// bijective XCD-chunk swizzle (m204 variant, works for any nwg)
__device__ __forceinline__ int xcd_swz(int bid, int nwg) {
  int xcd = bid & 7, off = bid >> 3;
  int q = nwg >> 3, r = nwg & 7;
  return (xcd < r ? xcd * (q + 1) : r * (q + 1) + (xcd - r) * q) + off;
}

// ---------------------------------------------------------------------------
// Shared MFMA core: 128x128 tile, BK=64, 4 waves (2x2 of 64x64).
// LDS [128 rows][128 B], XOR swizzle: phys colbyte = logical ^ ((row&7)<<4).
// gload_lds fills linearly: thread t, issue i -> LDS off i*4096 + t*16 =
// row (i*32 + (t>>3)), phys colbyte (t&7)*16. Source global column must be
// the inverse-swizzled cphys = ((t&7)<<4) ^ (((t>>3)&7)<<4).
// MFMA C/D: col=lane&15, row=4*(lane>>4)+reg.
// ---------------------------------------------------------------------------
__device__ __forceinline__ void tile_compute(const char* ldsA, const char* ldsB,
                                             f32x4 (&acc)[4][4], int wr, int wc, int lane) {
  const int l15 = lane & 15;
  const int colb = (lane >> 4) << 4;
  #pragma unroll
  for (int kk = 0; kk < 2; ++kk) {
    v8bf a[4], b[4];
    #pragma unroll
    for (int i = 0; i < 4; ++i) {
      int ra = wr * 64 + i * 16 + l15;
      int ca = ((kk << 6) | colb) ^ ((ra & 7) << 4);
      a[i] = *(const v8bf*)(ldsA + ra * 128 + ca);
    }
    #pragma unroll
    for (int j = 0; j < 4; ++j) {
      int rb = wc * 64 + j * 16 + l15;
      int cb = ((kk << 6) | colb) ^ ((rb & 7) << 4);
      b[j] = *(const v8bf*)(ldsB + rb * 128 + cb);
    }
    #pragma unroll
    for (int i = 0; i < 4; ++i)
      #pragma unroll
      for (int j = 0; j < 4; ++j)
        acc[i][j] = __builtin_amdgcn_mfma_f32_16x16x32_bf16(a[i], b[j], acc[i][j], 0, 0, 0);
  }
}

template<typename OutT, bool RELU>
__device__ __forceinline__ void store_tile(OutT* __restrict__ C, int m0, int c0,
                                           f32x4 (&acc)[4][4], int lane) {
  const int rbase = (lane >> 4) << 2;
  const int cl = lane & 15;
  #pragma unroll
  for (int i = 0; i < 4; ++i)
    #pragma unroll
    for (int j = 0; j < 4; ++j)
      #pragma unroll
      for (int r = 0; r < 4; ++r) {
        float v = acc[i][j][r];
        if (RELU) v = fmaxf(v, 0.f);
        C[(size_t)(m0 + i * 16 + rbase + r) * 512 + (c0 + j * 16 + cl)] = (OutT)v;
      }
}

// ---------------------------------------------------------------------------
// G1: 1x1 reduce conv + ReLU. A = interact^T bf16 [m][2304], B = wrb [512][2304].
// ---------------------------------------------------------------------------
__global__ __launch_bounds__(256)
void k_gemm_reduce(const bf16* __restrict__ A, const bf16* __restrict__ B,
                   bf16* __restrict__ f1, int mbase)
{
  __shared__ __attribute__((aligned(16))) char lds[32768];
  const int gx = gridDim.x, nwg = gx * gridDim.y;
  const int s = xcd_swz(blockIdx.x + gx * blockIdx.y, nwg);
  const int bx = s % gx, by = s / gx;
  const int t = threadIdx.x, lane = t & 63, w = t >> 6, wr = w >> 1, wc = w & 1;
  const int tr = t >> 3;
  const int cphys = ((t & 7) << 4) ^ ((tr & 7) << 4);
  const char* pa[4]; const char* pb[4];
  #pragma unroll
  for (int i = 0; i < 4; ++i) {
    int r = i * 32 + tr;
    pa[i] = (const char*)A + (size_t)(bx * 128 + r) * 4608 + cphys;
    pb[i] = (const char*)B + (size_t)(by * 128 + r) * 4608 + cphys;
  }
  char* la = lds + t * 16;
  char* lb = lds + 16384 + t * 16;
  f32x4 acc[4][4] = {};
  for (int ks = 0; ks < 36; ++ks) {
    __syncthreads();
    #pragma unroll
    for (int i = 0; i < 4; ++i) GLDS16(pa[i] + ks * 128, la + i * 4096);
    #pragma unroll
    for (int i = 0; i < 4; ++i) GLDS16(pb[i] + ks * 128, lb + i * 4096);
    __syncthreads();
    tile_compute(lds, lds + 16384, acc, wr, wc, lane);
  }
  store_tile<bf16, true>(f1, mbase + bx * 128 + wr * 64, by * 128 + wc * 64, acc, lane);
}

// ---------------------------------------------------------------------------
// G2: 3x3 VALID conv (16x16 -> 14x14). f1 NHWC bf16 -> f14 NHWC bf16.
// ---------------------------------------------------------------------------
__global__ __launch_bounds__(256)
void k_conv_rsize(const bf16* __restrict__ f1, const bf16* __restrict__ wt,
                  bf16* __restrict__ f14)
{
  __shared__ __attribute__((aligned(16))) char lds[32768];
  const int nwg = gridDim.x * gridDim.y;
  const int s = xcd_swz(blockIdx.x + gridDim.x * blockIdx.y, nwg);
  const int bx = s % 196, by = s / 196;
  const int t = threadIdx.x, lane = t & 63, w = t >> 6, wr = w >> 1, wc = w & 1;
  const int tr = t >> 3;
  const int cphys = ((t & 7) << 4) ^ ((tr & 7) << 4);
  int abase[4]; const char* pb[4];
  #pragma unroll
  for (int i = 0; i < 4; ++i) {
    int r = i * 32 + tr;
    int m = bx * 128 + r;
    int n = m / 196, rem = m - n * 196;
    int y = rem / 14, x = rem - 14 * (rem / 14);
    abase[i] = n * 256 + y * 16 + x;
    pb[i] = (const char*)wt + (size_t)(by * 128 + r) * 1024 + cphys;
  }
  const char* f1c = (const char*)f1 + cphys;
  char* la = lds + t * 16;
  char* lb = lds + 16384 + t * 16;
  f32x4 acc[4][4] = {};
  for (int ks = 0; ks < 72; ++ks) {
    int tap = ks >> 3, ko = (ks & 7) << 7;
    int dy = (tap * 11) >> 5, dx = tap - dy * 3;
    int doff = dy * 16 + dx;
    __syncthreads();
    #pragma unroll
    for (int i = 0; i < 4; ++i)
      GLDS16(f1c + ((size_t)(abase[i] + doff) << 10) + ko, la + i * 4096);
    #pragma unroll
    for (int i = 0; i < 4; ++i)
      GLDS16(pb[i] + (size_t)tap * 524288 + ko, lb + i * 4096);
    __syncthreads();
    tile_compute(lds, lds + 16384, acc, wr, wc, lane);
  }
  store_tile<bf16, false>(f14, bx * 128 + wr * 64, by * 128 + wc * 64, acc, lane);
}

// ---------------------------------------------------------------------------
// G4: merged q/k/v 3x3 SAME conv on 7x7 (tensor = swizzled y / 4).
// ---------------------------------------------------------------------------
__global__ __launch_bounds__(256)
void k_conv_qkv(const bf16* __restrict__ fin, const bf16* __restrict__ wt,
                bf16* __restrict__ qkv, const bf16* __restrict__ zp)
{
  __shared__ __attribute__((aligned(16))) char lds[32768];
  const int nwg = gridDim.x * gridDim.y;
  const int s = xcd_swz(blockIdx.x + gridDim.x * blockIdx.y, nwg);
  const int bx = s % 49;
  const int q12 = s / 49;
  const int tensor = q12 >> 2, by = q12 & 3;
  const char* wtc = (const char*)wt + (size_t)tensor * 4718592;
  bf16* outp = qkv + (size_t)tensor * 3211264;
  const int t = threadIdx.x, lane = t & 63, w = t >> 6, wr = w >> 1, wc = w & 1;
  const int tr = t >> 3;
  const int cphys = ((t & 7) << 4) ^ ((tr & 7) << 4);
  int nb[4], py[4], px[4]; const char* pb[4];
  #pragma unroll
  for (int i = 0; i < 4; ++i) {
    int r = i * 32 + tr;
    int m = bx * 128 + r;
    int n = m / 49, rem = m - n * 49;
    nb[i] = n * 49;
    py[i] = rem / 7 - 1;
    px[i] = rem - 7 * (rem / 7) - 1;
    pb[i] = wtc + (size_t)(by * 128 + r) * 1024 + cphys;
  }
  const char* finc = (const char*)fin + cphys;
  const char* zpc = (const char*)zp;
  char* la = lds + t * 16;
  char* lb = lds + 16384 + t * 16;
  f32x4 acc[4][4] = {};
  for (int ks = 0; ks < 72; ++ks) {
    int tap = ks >> 3, ko = (ks & 7) << 7;
    int dy = (tap * 11) >> 5, dx = tap - dy * 3;
    __syncthreads();
    #pragma unroll
    for (int i = 0; i < 4; ++i) {
      int iy = py[i] + dy, ix = px[i] + dx;
      const char* src = ((unsigned)iy < 7u && (unsigned)ix < 7u)
          ? finc + ((size_t)(nb[i] + iy * 7 + ix) << 10) + ko : zpc;
      GLDS16(src, la + i * 4096);
    }
    #pragma unroll
    for (int i = 0; i < 4; ++i)
      GLDS16(pb[i] + (size_t)tap * 524288 + ko, lb + i * 4096);
    __syncthreads();
    tile_compute(lds, lds + 16384, acc, wr, wc, lane);
  }
  store_tile<bf16, false>(outp, bx * 128 + wr * 64, by * 128 + wc * 64, acc, lane);
}

// ---------------------------------------------------------------------------
// G6: tiny GEMM replacing w1-conv + ho-mean: out[:, :512] = A_s @ w1r^T + f7m.
// A_s [128][4608] bf16 (windowed sums /49), w1r [512][4608] bf16.
// ---------------------------------------------------------------------------
__global__ __launch_bounds__(256)
void k_gemm_s(const bf16* __restrict__ A_s, const bf16* __restrict__ w1r,
              const float* __restrict__ f7m, float* __restrict__ out)
{
  __shared__ __attribute__((aligned(16))) char lds[32768];
  const int by = blockIdx.x;
  const int t = threadIdx.x, lane = t & 63, w = t >> 6, wr = w >> 1, wc = w & 1;
  const int tr = t >> 3;
  const int cphys = ((t & 7) << 4) ^ ((tr & 7) << 4);
  const char* pa[4]; const char* pb[4];
  #pragma unroll
  for (int i = 0; i < 4; ++i) {
    int r = i * 32 + tr;
    pa[i] = (const char*)A_s + (size_t)r * 9216 + cphys;
    pb[i] = (const char*)w1r + (size_t)(by * 128 + r) * 9216 + cphys;
  }
  char* la = lds + t * 16;
  char* lb = lds + 16384 + t * 16;
  f32x4 acc[4][4] = {};
  for (int ks = 0; ks < 72; ++ks) {
    __syncthreads();
    #pragma unroll
    for (int i = 0; i < 4; ++i) GLDS16(pa[i] + ks * 128, la + i * 4096);
    #pragma unroll
    for (int i = 0; i < 4; ++i) GLDS16(pb[i] + ks * 128, lb + i * 4096);
    __syncthreads();
    tile_compute(lds, lds + 16384, acc, wr, wc, lane);
  }
  const int rb = (lane >> 4) << 2, cl = lane & 15;
  #pragma unroll
  for (int i = 0; i < 4; ++i)
    #pragma unroll
    for (int j = 0; j < 4; ++j)
      #pragma unroll
      for (int r = 0; r < 4; ++r) {
        int row = wr * 64 + i * 16 + rb + r;
        int col = by * 128 + wc * 64 + j * 16 + cl;
        out[(size_t)row * 1024 + col] = acc[i][j][r] + f7m[row * 512 + col];
      }
}

// ---------------------------------------------------------------------------
// P0: transpose+cast interact (n,2304,256) f32 -> A1 bf16 [(nl*256+p)][2304]
// ---------------------------------------------------------------------------
__global__ void k_tin(const float* __restrict__ in, bf16* __restrict__ A1, int n0)
{
  __shared__ float tile[32][33];
  const int k0 = blockIdx.x * 32, p0 = blockIdx.y * 32, nl = blockIdx.z;
  const int n = n0 + nl;
  const int r = threadIdx.x >> 5, c = threadIdx.x & 31;
  const float* src = in + (size_t)n * 2304 * 256;
  #pragma unroll
  for (int rr = r; rr < 32; rr += 8) tile[rr][c] = src[(size_t)(k0 + rr) * 256 + p0 + c];
  __syncthreads();
  bf16* dst = A1 + (size_t)nl * 256 * 2304;
  #pragma unroll
  for (int rr = r; rr < 32; rr += 8) dst[(size_t)(p0 + rr) * 2304 + k0 + c] = (bf16)tile[c][rr];
}

// P1: cast w_reduce f32 -> bf16
__global__ void k_castw(const float* __restrict__ wsrc, bf16* __restrict__ wb, int nelem)
{
  int idx = (blockIdx.x * 256 + threadIdx.x) * 4;
  if (idx >= nelem) return;
  float4 v = *(const float4*)(wsrc + idx);
  bf16 o0 = (bf16)v.x, o1 = (bf16)v.y, o2 = (bf16)v.z, o3 = (bf16)v.w;
  bf16* d = wb + idx;
  d[0] = o0; d[1] = o1; d[2] = o2; d[3] = o3;
}

// P2: (co,ci,3,3) f32 -> wt [tensor<4][tap][co][ci] bf16; w1 -> w1r [co][tap][ci]
__global__ void k_wtrans(const float* __restrict__ s0, const float* __restrict__ s1,
                         const float* __restrict__ s2, const float* __restrict__ s3,
                         const float* __restrict__ s4, bf16* __restrict__ wt,
                         bf16* __restrict__ w1r)
{
  const float* src;
  switch (blockIdx.y) {
    case 0: src = s0; break; case 1: src = s1; break; case 2: src = s2; break;
    case 3: src = s3; break; default: src = s4; break;
  }
  int q = blockIdx.x * 256 + threadIdx.x;   // co*512+ci
  const float* sp = src + (size_t)q * 9;
  float tmp[9];
  #pragma unroll
  for (int e = 0; e < 9; ++e) tmp[e] = sp[e];
  if (blockIdx.y < 4) {
    bf16* dst = wt + (size_t)blockIdx.y * 2359296;
    #pragma unroll
    for (int e = 0; e < 9; ++e) dst[(size_t)e * 262144 + q] = (bf16)tmp[e];
  } else {
    int co = q >> 9, ci = q & 511;
    #pragma unroll
    for (int e = 0; e < 9; ++e) w1r[(size_t)(co * 9 + e) * 512 + ci] = (bf16)tmp[e];
  }
}

// K3: maxpool 3x3 s2 p1, 14x14 -> 7x7, bf16, 2 channels/thread
__global__ void k_pool(const bf16* __restrict__ f14, bf16* __restrict__ f7b)
{
  int idx = blockIdx.x * 256 + threadIdx.x;   // 128*49*256
  int c2 = idx & 255;
  int pp = idx >> 8;
  int n = pp / 49, p7 = pp - n * 49;
  int y = p7 / 7, x = p7 - 7 * (p7 / 7);
  int y0 = 2 * y - 1, x0 = 2 * x - 1;
  const unsigned* f14u = (const unsigned*)f14;
  float m0 = -3.4e38f, m1 = -3.4e38f;
  #pragma unroll
  for (int dy = 0; dy < 3; ++dy) {
    int iy = y0 + dy; if ((unsigned)iy >= 14u) continue;
    #pragma unroll
    for (int dx = 0; dx < 3; ++dx) {
      int ix = x0 + dx; if ((unsigned)ix >= 14u) continue;
      unsigned vv = f14u[(size_t)(n * 196 + iy * 14 + ix) * 256 + c2];
      m0 = fmaxf(m0, __builtin_bit_cast(float, vv << 16));
      m1 = fmaxf(m1, __builtin_bit_cast(float, vv & 0xffff0000u));
    }
  }
  bf16 b0 = (bf16)m0, b1 = (bf16)m1;
  unsigned pk = (unsigned)__builtin_bit_cast(unsigned short, b0)
              | ((unsigned)__builtin_bit_cast(unsigned short, b1) << 16);
  ((unsigned*)f7b)[idx] = pk;
}

// K5: group attention (8x8 within group, mask from rois)
__global__ __launch_bounds__(256)
void k_attn(const bf16* __restrict__ q, const bf16* __restrict__ k,
            const bf16* __restrict__ v, const float* __restrict__ rois,
            float* __restrict__ virt)
{
  const int p = blockIdx.x, g = blockIdx.y, t = threadIdx.x;
  __shared__ float sS[8][9];
  __shared__ float sP[8][9];
  __shared__ __attribute__((aligned(16))) bf16 sV[8][512];
  {
    int u = t;
    #pragma unroll
    for (int rep = 0; rep < 2; ++rep, u += 256) {
      int j = u >> 6, ch = u & 63;
      *(v8bf*)&sV[j][ch * 8] = *(const v8bf*)(v + ((size_t)(g * 8 + j) * 49 + p) * 512 + ch * 8);
    }
  }
  int pi = t >> 2, ls = t & 3;
  int i = pi >> 3, j = pi & 7;
  const bf16* qi = q + ((size_t)(g * 8 + i) * 49 + p) * 512;
  const bf16* kj = k + ((size_t)(g * 8 + j) * 49 + p) * 512;
  float s = 0.f;
  for (int ch = ls * 16; ch < ls * 16 + 16; ++ch) {
    v8bf a = *(const v8bf*)(qi + ch * 8);
    v8bf b = *(const v8bf*)(kj + ch * 8);
    #pragma unroll
    for (int e = 0; e < 8; ++e) s += (float)a[e] * (float)b[e];
  }
  s += __shfl_xor(s, 1);
  s += __shfl_xor(s, 2);
  if (ls == 0) sS[i][j] = s * 0.04419417382415922f;
  __syncthreads();
  if (t < 8) {
    float gi = rois[(g * 8 + t) * 5];
    float pv[8]; float mx = -3.4e38f;
    #pragma unroll
    for (int jj = 0; jj < 8; ++jj) {
      float gj = rois[(g * 8 + jj) * 5];
      float sv = (gi == gj) ? sS[t][jj] : -1e30f;
      pv[jj] = sv; mx = fmaxf(mx, sv);
    }
    float sum = 0.f;
    #pragma unroll
    for (int jj = 0; jj < 8; ++jj) { float e = expf(pv[jj] - mx); pv[jj] = e; sum += e; }
    float inv = 1.f / sum;
    #pragma unroll
    for (int jj = 0; jj < 8; ++jj) sP[t][jj] = pv[jj] * inv;
  }
  __syncthreads();
  int i2 = t >> 5, c0 = (t & 31) * 16;
  float o[16];
  #pragma unroll
  for (int e = 0; e < 16; ++e) o[e] = 0.f;
  #pragma unroll
  for (int jj = 0; jj < 8; ++jj) {
    float ww = sP[i2][jj];
    v8bf v0 = *(const v8bf*)&sV[jj][c0];
    v8bf v1 = *(const v8bf*)&sV[jj][c0 + 8];
    #pragma unroll
    for (int e = 0; e < 8; ++e) { o[e] += ww * (float)v0[e]; o[8 + e] += ww * (float)v1[e]; }
  }
  float* dst = virt + ((size_t)(g * 8 + i2) * 49 + p) * 512 + c0;
  #pragma unroll
  for (int e = 0; e < 16; ++e) dst[e] = o[e];
}

// K6: per-sample LN stats
__global__ __launch_bounds__(256)
void k_lnstats(const float* __restrict__ virt, float* __restrict__ stats)
{
  int n = blockIdx.x, t = threadIdx.x;
  const float* p = virt + (size_t)n * 25088;
  float s1 = 0.f, s2 = 0.f;
  for (int idx = t; idx < 25088; idx += 256) { float x = p[idx]; s1 += x; s2 += x * x; }
  __shared__ float r1[256], r2[256];
  r1[t] = s1; r2[t] = s2; __syncthreads();
  for (int off = 128; off; off >>= 1) {
    if (t < off) { r1[t] += r1[t + off]; r2[t] += r2[t + off]; }
    __syncthreads();
  }
  if (t == 0) {
    float mu = r1[0] * (1.f / 25088.f);
    float var = r2[0] * (1.f / 25088.f) - mu * mu;
    stats[2 * n] = mu;
    stats[2 * n + 1] = rsqrtf(var + 1e-5f);
  }
}

// K7: LN apply + gamma/beta + ReLU -> bf16
__global__ void k_lnapply(const float* __restrict__ virt, const float* __restrict__ stats,
                          const float* __restrict__ gamma, const float* __restrict__ beta,
                          bf16* __restrict__ virtn)
{
  int idx = blockIdx.x * 256 + threadIdx.x;
  int c = idx & 511;
  int n = (idx >> 9) / 49;
  float mu = stats[2 * n], rstd = stats[2 * n + 1];
  float y = (virt[idx] - mu) * rstd * gamma[c] + beta[c];
  virtn[idx] = (bf16)fmaxf(y, 0.f);
}

// K8: windowed sums for the mean-of-conv trick + f7 mean. block=n, 2 ci/thread.
__global__ __launch_bounds__(256)
void k_sums(const bf16* __restrict__ virtn, const bf16* __restrict__ f7b,
            bf16* __restrict__ A_s, float* __restrict__ f7m)
{
  const int n = blockIdx.x, t = threadIdx.x;
  const unsigned* vp = (const unsigned*)virtn + (size_t)n * 49 * 256 + t;
  const unsigned* fp = (const unsigned*)f7b + (size_t)n * 49 * 256 + t;
  float T0=0,T1=0,R0a=0,R0b=0,R6a=0,R6b=0,C0a=0,C0b=0,C6a=0,C6b=0;
  float X00a=0,X00b=0,X06a=0,X06b=0,X60a=0,X60b=0,X66a=0,X66b=0;
  float F0=0,F1=0;
  int u = 0, v = 0;
  for (int p = 0; p < 49; ++p) {
    unsigned av = vp[(size_t)p * 256], fv = fp[(size_t)p * 256];
    float a0 = __builtin_bit_cast(float, av << 16);
    float a1 = __builtin_bit_cast(float, av & 0xffff0000u);
    float b0 = __builtin_bit_cast(float, fv << 16);
    float b1 = __builtin_bit_cast(float, fv & 0xffff0000u);
    T0 += a0; T1 += a1; F0 += b0; F1 += b1;
    if (u == 0) { R0a += a0; R0b += a1; }
    if (u == 6) { R6a += a0; R6b += a1; }
    if (v == 0) { C0a += a0; C0b += a1; }
    if (v == 6) { C6a += a0; C6b += a1; }
    if (p == 0)  { X00a = a0; X00b = a1; }
    if (p == 6)  { X06a = a0; X06b = a1; }
    if (p == 42) { X60a = a0; X60b = a1; }
    if (p == 48) { X66a = a0; X66b = a1; }
    if (++v == 7) { v = 0; ++u; }
  }
  // S[tap]: dy excludes row {6,-,0}, dx excludes col {6,-,0}
  float s0[9] = { T0-R6a-C6a+X66a, T0-R6a, T0-R6a-C0a+X60a,
                  T0-C6a,          T0,     T0-C0a,
                  T0-R0a-C6a+X06a, T0-R0a, T0-R0a-C0a+X00a };
  float s1[9] = { T1-R6b-C6b+X66b, T1-R6b, T1-R6b-C0b+X60b,
                  T1-C6b,          T1,     T1-C0b,
                  T1-R0b-C6b+X06b, T1-R0b, T1-R0b-C0b+X00b };
  unsigned* Ap = (unsigned*)A_s + (size_t)n * 2304 + t;
  #pragma unroll
  for (int tap = 0; tap < 9; ++tap) {
    bf16 lo = (bf16)(s0[tap] * (1.f / 49.f));
    bf16 hi = (bf16)(s1[tap] * (1.f / 49.f));
    unsigned pk = (unsigned)__builtin_bit_cast(unsigned short, lo)
                | ((unsigned)__builtin_bit_cast(unsigned short, hi) << 16);
    Ap[tap * 256] = pk;
  }
  f7m[n * 512 + 2 * t]     = F0 * (1.f / 49.f);
  f7m[n * 512 + 2 * t + 1] = F1 * (1.f / 49.f);
}

// K10a: obm = mean bbox over 196; 4 lanes per channel, coalesced float4
__global__ __launch_bounds__(256)
void k_obm(const float* __restrict__ bbox, float* __restrict__ obm)
{
  int n = blockIdx.x;
  int c = blockIdx.y * 64 + (threadIdx.x >> 2);
  int seg = threadIdx.x & 3;
  const float4* p4 = (const float4*)(bbox + ((size_t)n * 1024 + c) * 196);
  float s = 0.f;
  for (int k = seg; k < 49; k += 4) { float4 w = p4[k]; s += w.x + w.y + w.z + w.w; }
  s += __shfl_xor(s, 1);
  s += __shfl_xor(s, 2);
  if (seg == 0) obm[n * 1024 + c] = s * (1.f / 196.f);
}

// K10b: fc + relu -> out[:, 512:1024]
__global__ __launch_bounds__(256)
void k_fc(const float* __restrict__ obm, const float* __restrict__ wfc,
          float* __restrict__ out)
{
  int n = blockIdx.x, t = threadIdx.x;
  __shared__ float sO[1024];
  for (int u = t; u < 1024; u += 256) sO[u] = obm[n * 1024 + u];
  __syncthreads();
  for (int jj = t; jj < 512; jj += 256) {
    const float4* wp = (const float4*)(wfc + (size_t)jj * 1024);
    float s = 0.f;
    for (int c4 = 0; c4 < 256; ++c4) {
      float4 w = wp[c4];
      s += w.x * sO[c4 * 4] + w.y * sO[c4 * 4 + 1] + w.z * sO[c4 * 4 + 2] + w.w * sO[c4 * 4 + 3];
    }
    out[n * 1024 + 512 + jj] = fmaxf(s, 0.f);
  }
}

// ---------------------------------------------------------------------------
extern "C" void kernel_launch(void* const* d_in, const int* in_sizes, int n_in,
                              void* d_out, int out_size, void* d_ws, size_t ws_size,
                              hipStream_t stream) {
  const float* rois     = (const float*)d_in[0];
  const float* interact = (const float*)d_in[1];
  const float* bbox     = (const float*)d_in[2];
  const float* w_reduce = (const float*)d_in[3];
  const float* w_rsize  = (const float*)d_in[4];
  const float* wq       = (const float*)d_in[5];
  const float* wk       = (const float*)d_in[6];
  const float* wv       = (const float*)d_in[7];
  const float* w1       = (const float*)d_in[8];
  const float* gamma    = (const float*)d_in[9];
  const float* beta     = (const float*)d_in[10];
  const float* wfc      = (const float*)d_in[11];
  float* out = (float*)d_out;
  char* ws = (char*)d_ws;

  size_t o = 0;
  auto take = [&](size_t sz) { size_t r = o; o += (sz + 255) & ~(size_t)255; return r; };
  bf16*  wrb   = (bf16*)(ws + take(2359296));
  bf16*  wt    = (bf16*)(ws + take(18874368));   // [4][9][512][512] bf16 (rsize,q,k,v)
  bf16*  w1r   = (bf16*)(ws + take(4718592));    // [512 co][9 tap][512 ci] bf16
  char*  Rf1   = ws + take(33554432);            // f1 (33.6MB) -> later q,k,v (19.3MB)
  bf16*  f7b   = (bf16*)(ws + take(6422528));
  float* virt  = (float*)(ws + take(12845056));
  bf16*  virtn = (bf16*)(ws + take(6422528));
  bf16*  A_s   = (bf16*)(ws + take(1179648));
  float* f7m   = (float*)(ws + take(262144));
  float* stats = (float*)(ws + take(1024));
  float* obm   = (float*)(ws + take(524288));
  bf16*  zp    = (bf16*)(ws + take(256));
  size_t fixedEnd = o;
  // A1 region last; f14 (bf16, 25.7MB) aliases it after the reduce GEMM is done
  const size_t A1_FULL = 150994944, A1_CHUNK = 37748736;
  bool full = (ws_size >= fixedEnd + A1_FULL);
  bf16* A1  = (bf16*)(ws + fixedEnd);
  bf16* f14 = (bf16*)(ws + fixedEnd);

  bf16* f1 = (bf16*)Rf1;
  bf16* qb = (bf16*)Rf1;
  bf16* kb = qb + 3211264;
  bf16* vb = kb + 3211264;
  (void)A1_CHUNK;

  hipMemsetAsync(zp, 0, 256, stream);

  k_castw<<<1152, 256, 0, stream>>>(w_reduce, wrb, 1179648);
  k_wtrans<<<dim3(1024, 5), 256, 0, stream>>>(w_rsize, wq, wk, wv, w1, wt, w1r);

  if (full) {
    k_tin<<<dim3(72, 8, 128), 256, 0, stream>>>(interact, A1, 0);
    k_gemm_reduce<<<dim3(256, 4), 256, 0, stream>>>(A1, wrb, f1, 0);
  } else {
    for (int ch = 0; ch < 4; ++ch) {
      k_tin<<<dim3(72, 8, 32), 256, 0, stream>>>(interact, A1, ch * 32);
      k_gemm_reduce<<<dim3(64, 4), 256, 0, stream>>>(A1, wrb, f1, ch * 8192);
    }
  }

  k_conv_rsize<<<dim3(196, 4), 256, 0, stream>>>(f1, wt, f14);
  k_pool<<<6272, 256, 0, stream>>>(f14, f7b);

  k_conv_qkv<<<dim3(49, 12), 256, 0, stream>>>(f7b, wt + (size_t)1 * 2359296, qb, zp);

  k_attn<<<dim3(49, 16), 256, 0, stream>>>(qb, kb, vb, rois, virt);

  k_lnstats<<<128, 256, 0, stream>>>(virt, stats);
  k_lnapply<<<12544, 256, 0, stream>>>(virt, stats, gamma, beta, virtn);

  k_sums<<<128, 256, 0, stream>>>(virtn, f7b, A_s, f7m);
  k_gemm_s<<<4, 256, 0, stream>>>(A_s, w1r, f7m, out);

  k_obm<<<dim3(128, 16), 256, 0, stream>>>(bbox, obm);
  k_fc<<<128, 256, 0, stream>>>(obm, wfc, out);
}

// Round 3
// 764.923 us; speedup vs baseline: 1.2438x; 1.0971x over previous
//
#include <hip/hip_runtime.h>
#include <hip/hip_bf16.h>
#include <math.h>

typedef __bf16 bf16;
typedef __bf16 v8bf __attribute__((ext_vector_type(8)));
typedef float f32x4 __attribute__((ext_vector_type(4)));

// async global->LDS, 16B per lane. LDS dest ends up wave-uniform base + lane*16
// because our per-thread offset is exactly t*16 (lane-linear within a wave).
#define GLDS16(g, l) __builtin_amdgcn_global_load_lds( \
    (const __attribute__((address_space(1))) void*)(g), \
    (__attribute__((address_space(3))) void*)(l), 16, 0, 0)

// bijective XCD-chunk swizzle (m204 variant, works for any nwg):
// consecutive returned s values land on the same XCD.
__device__ __forceinline__ int xcd_swz(int bid, int nwg) {
  int xcd = bid & 7, off = bid >> 3;
  int q = nwg >> 3, r = nwg & 7;
  return (xcd < r ? xcd * (q + 1) : r * (q + 1) + (xcd - r) * q) + off;
}

// ---------------------------------------------------------------------------
// Shared MFMA core: 128x128 tile, BK=64, 4 waves (2x2 of 64x64), double-
// buffered LDS (2 x 32KB). LDS tile [128 rows][128 B], XOR swizzle:
// phys colbyte = logical ^ ((row&7)<<4). gload_lds fills linearly:
// thread t, issue i -> row (i*32 + (t>>3)), phys colbyte (t&7)*16, so the
// global source column is pre-inverse-swizzled: cphys = ((t&7)<<4) ^ (((t>>3)&7)<<4).
// MFMA C/D: col=lane&15, row=4*(lane>>4)+reg.
// ---------------------------------------------------------------------------
__device__ __forceinline__ void tile_compute(const char* ldsA, const char* ldsB,
                                             f32x4 (&acc)[4][4], int wr, int wc, int lane) {
  const int l15 = lane & 15;
  const int colb = (lane >> 4) << 4;
  #pragma unroll
  for (int kk = 0; kk < 2; ++kk) {
    v8bf a[4], b[4];
    #pragma unroll
    for (int i = 0; i < 4; ++i) {
      int ra = wr * 64 + i * 16 + l15;
      int ca = ((kk << 6) | colb) ^ ((ra & 7) << 4);
      a[i] = *(const v8bf*)(ldsA + ra * 128 + ca);
    }
    #pragma unroll
    for (int j = 0; j < 4; ++j) {
      int rb = wc * 64 + j * 16 + l15;
      int cb = ((kk << 6) | colb) ^ ((rb & 7) << 4);
      b[j] = *(const v8bf*)(ldsB + rb * 128 + cb);
    }
    #pragma unroll
    for (int i = 0; i < 4; ++i)
      #pragma unroll
      for (int j = 0; j < 4; ++j)
        acc[i][j] = __builtin_amdgcn_mfma_f32_16x16x32_bf16(a[i], b[j], acc[i][j], 0, 0, 0);
  }
}

template<typename OutT, bool RELU>
__device__ __forceinline__ void store_tile(OutT* __restrict__ C, int m0, int c0,
                                           f32x4 (&acc)[4][4], int lane) {
  const int rbase = (lane >> 4) << 2;
  const int cl = lane & 15;
  #pragma unroll
  for (int i = 0; i < 4; ++i)
    #pragma unroll
    for (int j = 0; j < 4; ++j)
      #pragma unroll
      for (int r = 0; r < 4; ++r) {
        float v = acc[i][j][r];
        if (RELU) v = fmaxf(v, 0.f);
        C[(size_t)(m0 + i * 16 + rbase + r) * 512 + (c0 + j * 16 + cl)] = (OutT)v;
      }
}

// ---------------------------------------------------------------------------
// G1: 1x1 reduce conv + ReLU. A = interact^T bf16 [m][2304], B = wrb [512][2304].
// 1-D grid; by (N-tile) is the fast swizzle dim for A-tile L2 reuse.
// ---------------------------------------------------------------------------
__global__ __launch_bounds__(256)
void k_gemm_reduce(const bf16* __restrict__ A, const bf16* __restrict__ B,
                   bf16* __restrict__ f1, int mbase)
{
  __shared__ __attribute__((aligned(16))) char lds[65536];
  const int s = xcd_swz(blockIdx.x, gridDim.x);
  const int by = s & 3, bx = s >> 2;
  const int t = threadIdx.x, lane = t & 63, w = t >> 6, wr = w >> 1, wc = w & 1;
  const int tr = t >> 3;
  const int cphys = ((t & 7) << 4) ^ ((tr & 7) << 4);
  const char* pa[4]; const char* pb[4];
  #pragma unroll
  for (int i = 0; i < 4; ++i) {
    int r = i * 32 + tr;
    pa[i] = (const char*)A + (size_t)(bx * 128 + r) * 4608 + cphys;
    pb[i] = (const char*)B + (size_t)(by * 128 + r) * 4608 + cphys;
  }
  const int lo = t * 16;
  auto stage = [&](int ks, char* base) {
    #pragma unroll
    for (int i = 0; i < 4; ++i) GLDS16(pa[i] + ks * 128, base + lo + i * 4096);
    #pragma unroll
    for (int i = 0; i < 4; ++i) GLDS16(pb[i] + ks * 128, base + 16384 + lo + i * 4096);
  };
  f32x4 acc[4][4] = {};
  stage(0, lds);
  __syncthreads();
  int cur = 0;
  for (int ks = 0; ks < 36; ++ks) {
    if (ks + 1 < 36) stage(ks + 1, lds + (cur ^ 1) * 32768);
    tile_compute(lds + cur * 32768, lds + cur * 32768 + 16384, acc, wr, wc, lane);
    __syncthreads();
    cur ^= 1;
  }
  store_tile<bf16, true>(f1, mbase + bx * 128 + wr * 64, by * 128 + wc * 64, acc, lane);
}

// ---------------------------------------------------------------------------
// G2: 3x3 VALID conv (16x16 -> 14x14). f1 NHWC bf16 -> f14 NHWC bf16.
// ---------------------------------------------------------------------------
__global__ __launch_bounds__(256)
void k_conv_rsize(const bf16* __restrict__ f1, const bf16* __restrict__ wt,
                  bf16* __restrict__ f14)
{
  __shared__ __attribute__((aligned(16))) char lds[65536];
  const int s = xcd_swz(blockIdx.x, gridDim.x);
  const int by = s & 3, bx = s >> 2;
  const int t = threadIdx.x, lane = t & 63, w = t >> 6, wr = w >> 1, wc = w & 1;
  const int tr = t >> 3;
  const int cphys = ((t & 7) << 4) ^ ((tr & 7) << 4);
  int abase[4]; const char* pb[4];
  #pragma unroll
  for (int i = 0; i < 4; ++i) {
    int r = i * 32 + tr;
    int m = bx * 128 + r;
    int n = m / 196, rem = m - n * 196;
    int y = rem / 14, x = rem - 14 * (rem / 14);
    abase[i] = n * 256 + y * 16 + x;
    pb[i] = (const char*)wt + (size_t)(by * 128 + r) * 1024 + cphys;
  }
  const char* f1c = (const char*)f1 + cphys;
  const int lo = t * 16;
  auto stage = [&](int ks, char* base) {
    int tap = ks >> 3, ko = (ks & 7) << 7;
    int dy = (tap * 11) >> 5, dx = tap - dy * 3;
    int doff = dy * 16 + dx;
    #pragma unroll
    for (int i = 0; i < 4; ++i)
      GLDS16(f1c + ((size_t)(abase[i] + doff) << 10) + ko, base + lo + i * 4096);
    #pragma unroll
    for (int i = 0; i < 4; ++i)
      GLDS16(pb[i] + (size_t)tap * 524288 + ko, base + 16384 + lo + i * 4096);
  };
  f32x4 acc[4][4] = {};
  stage(0, lds);
  __syncthreads();
  int cur = 0;
  for (int ks = 0; ks < 72; ++ks) {
    if (ks + 1 < 72) stage(ks + 1, lds + (cur ^ 1) * 32768);
    tile_compute(lds + cur * 32768, lds + cur * 32768 + 16384, acc, wr, wc, lane);
    __syncthreads();
    cur ^= 1;
  }
  store_tile<bf16, false>(f14, bx * 128 + wr * 64, by * 128 + wc * 64, acc, lane);
}

// ---------------------------------------------------------------------------
// G4: merged q/k/v 3x3 SAME conv on 7x7. (tensor,by) is the fast swizzle dim
// so 12 consecutive blocks share one A-tile via L2.
// ---------------------------------------------------------------------------
__global__ __launch_bounds__(256)
void k_conv_qkv(const bf16* __restrict__ fin, const bf16* __restrict__ wt,
                bf16* __restrict__ qkv, const bf16* __restrict__ zp)
{
  __shared__ __attribute__((aligned(16))) char lds[65536];
  const int s = xcd_swz(blockIdx.x, gridDim.x);
  const int q12 = s % 12, bx = s / 12;
  const int tensor = q12 >> 2, by = q12 & 3;
  const char* wtc = (const char*)wt + (size_t)tensor * 4718592;
  bf16* outp = qkv + (size_t)tensor * 3211264;
  const int t = threadIdx.x, lane = t & 63, w = t >> 6, wr = w >> 1, wc = w & 1;
  const int tr = t >> 3;
  const int cphys = ((t & 7) << 4) ^ ((tr & 7) << 4);
  int nb[4], py[4], px[4]; const char* pb[4];
  #pragma unroll
  for (int i = 0; i < 4; ++i) {
    int r = i * 32 + tr;
    int m = bx * 128 + r;
    int n = m / 49, rem = m - n * 49;
    nb[i] = n * 49;
    py[i] = rem / 7 - 1;
    px[i] = rem - 7 * (rem / 7) - 1;
    pb[i] = wtc + (size_t)(by * 128 + r) * 1024 + cphys;
  }
  const char* finc = (const char*)fin + cphys;
  const char* zpc = (const char*)zp;
  const int lo = t * 16;
  auto stage = [&](int ks, char* base) {
    int tap = ks >> 3, ko = (ks & 7) << 7;
    int dy = (tap * 11) >> 5, dx = tap - dy * 3;
    #pragma unroll
    for (int i = 0; i < 4; ++i) {
      int iy = py[i] + dy, ix = px[i] + dx;
      const char* src = ((unsigned)iy < 7u && (unsigned)ix < 7u)
          ? finc + ((size_t)(nb[i] + iy * 7 + ix) << 10) + ko : zpc;
      GLDS16(src, base + lo + i * 4096);
    }
    #pragma unroll
    for (int i = 0; i < 4; ++i)
      GLDS16(pb[i] + (size_t)tap * 524288 + ko, base + 16384 + lo + i * 4096);
  };
  f32x4 acc[4][4] = {};
  stage(0, lds);
  __syncthreads();
  int cur = 0;
  for (int ks = 0; ks < 72; ++ks) {
    if (ks + 1 < 72) stage(ks + 1, lds + (cur ^ 1) * 32768);
    tile_compute(lds + cur * 32768, lds + cur * 32768 + 16384, acc, wr, wc, lane);
    __syncthreads();
    cur ^= 1;
  }
  store_tile<bf16, false>(outp, bx * 128 + wr * 64, by * 128 + wc * 64, acc, lane);
}

// ---------------------------------------------------------------------------
// G6: tiny GEMM replacing w1-conv + ho-mean: out[:, :512] = A_s @ w1r^T + f7m.
// ---------------------------------------------------------------------------
__global__ __launch_bounds__(256)
void k_gemm_s(const bf16* __restrict__ A_s, const bf16* __restrict__ w1r,
              const float* __restrict__ f7m, float* __restrict__ out)
{
  __shared__ __attribute__((aligned(16))) char lds[65536];
  const int by = blockIdx.x;
  const int t = threadIdx.x, lane = t & 63, w = t >> 6, wr = w >> 1, wc = w & 1;
  const int tr = t >> 3;
  const int cphys = ((t & 7) << 4) ^ ((tr & 7) << 4);
  const char* pa[4]; const char* pb[4];
  #pragma unroll
  for (int i = 0; i < 4; ++i) {
    int r = i * 32 + tr;
    pa[i] = (const char*)A_s + (size_t)r * 9216 + cphys;
    pb[i] = (const char*)w1r + (size_t)(by * 128 + r) * 9216 + cphys;
  }
  const int lo = t * 16;
  auto stage = [&](int ks, char* base) {
    #pragma unroll
    for (int i = 0; i < 4; ++i) GLDS16(pa[i] + ks * 128, base + lo + i * 4096);
    #pragma unroll
    for (int i = 0; i < 4; ++i) GLDS16(pb[i] + ks * 128, base + 16384 + lo + i * 4096);
  };
  f32x4 acc[4][4] = {};
  stage(0, lds);
  __syncthreads();
  int cur = 0;
  for (int ks = 0; ks < 72; ++ks) {
    if (ks + 1 < 72) stage(ks + 1, lds + (cur ^ 1) * 32768);
    tile_compute(lds + cur * 32768, lds + cur * 32768 + 16384, acc, wr, wc, lane);
    __syncthreads();
    cur ^= 1;
  }
  const int rb = (lane >> 4) << 2, cl = lane & 15;
  #pragma unroll
  for (int i = 0; i < 4; ++i)
    #pragma unroll
    for (int j = 0; j < 4; ++j)
      #pragma unroll
      for (int r = 0; r < 4; ++r) {
        int row = wr * 64 + i * 16 + rb + r;
        int col = by * 128 + wc * 64 + j * 16 + cl;
        out[(size_t)row * 1024 + col] = acc[i][j][r] + f7m[row * 512 + col];
      }
}

// ---------------------------------------------------------------------------
// P0: transpose+cast interact (n,2304,256) f32 -> A1 bf16 [(nl*256+p)][2304]
// ---------------------------------------------------------------------------
__global__ void k_tin(const float* __restrict__ in, bf16* __restrict__ A1, int n0)
{
  __shared__ float tile[32][33];
  const int k0 = blockIdx.x * 32, p0 = blockIdx.y * 32, nl = blockIdx.z;
  const int n = n0 + nl;
  const int r = threadIdx.x >> 5, c = threadIdx.x & 31;
  const float* src = in + (size_t)n * 2304 * 256;
  #pragma unroll
  for (int rr = r; rr < 32; rr += 8) tile[rr][c] = src[(size_t)(k0 + rr) * 256 + p0 + c];
  __syncthreads();
  bf16* dst = A1 + (size_t)nl * 256 * 2304;
  #pragma unroll
  for (int rr = r; rr < 32; rr += 8) dst[(size_t)(p0 + rr) * 2304 + k0 + c] = (bf16)tile[c][rr];
}

// P1: cast w_reduce f32 -> bf16
__global__ void k_castw(const float* __restrict__ wsrc, bf16* __restrict__ wb, int nelem)
{
  int idx = (blockIdx.x * 256 + threadIdx.x) * 4;
  if (idx >= nelem) return;
  float4 v = *(const float4*)(wsrc + idx);
  bf16 o0 = (bf16)v.x, o1 = (bf16)v.y, o2 = (bf16)v.z, o3 = (bf16)v.w;
  bf16* d = wb + idx;
  d[0] = o0; d[1] = o1; d[2] = o2; d[3] = o3;
}

// P2: (co,ci,3,3) f32 -> wt [tensor<4][tap][co][ci] bf16; w1 -> w1r [co][tap][ci]
__global__ void k_wtrans(const float* __restrict__ s0, const float* __restrict__ s1,
                         const float* __restrict__ s2, const float* __restrict__ s3,
                         const float* __restrict__ s4, bf16* __restrict__ wt,
                         bf16* __restrict__ w1r)
{
  const float* src;
  switch (blockIdx.y) {
    case 0: src = s0; break; case 1: src = s1; break; case 2: src = s2; break;
    case 3: src = s3; break; default: src = s4; break;
  }
  int q = blockIdx.x * 256 + threadIdx.x;   // co*512+ci
  const float* sp = src + (size_t)q * 9;
  float tmp[9];
  #pragma unroll
  for (int e = 0; e < 9; ++e) tmp[e] = sp[e];
  if (blockIdx.y < 4) {
    bf16* dst = wt + (size_t)blockIdx.y * 2359296;
    #pragma unroll
    for (int e = 0; e < 9; ++e) dst[(size_t)e * 262144 + q] = (bf16)tmp[e];
  } else {
    int co = q >> 9, ci = q & 511;
    #pragma unroll
    for (int e = 0; e < 9; ++e) w1r[(size_t)(co * 9 + e) * 512 + ci] = (bf16)tmp[e];
  }
}

// K3: maxpool 3x3 s2 p1, 14x14 -> 7x7, bf16, 2 channels/thread
__global__ void k_pool(const bf16* __restrict__ f14, bf16* __restrict__ f7b)
{
  int idx = blockIdx.x * 256 + threadIdx.x;   // 128*49*256
  int c2 = idx & 255;
  int pp = idx >> 8;
  int n = pp / 49, p7 = pp - n * 49;
  int y = p7 / 7, x = p7 - 7 * (p7 / 7);
  int y0 = 2 * y - 1, x0 = 2 * x - 1;
  const unsigned* f14u = (const unsigned*)f14;
  float m0 = -3.4e38f, m1 = -3.4e38f;
  #pragma unroll
  for (int dy = 0; dy < 3; ++dy) {
    int iy = y0 + dy; if ((unsigned)iy >= 14u) continue;
    #pragma unroll
    for (int dx = 0; dx < 3; ++dx) {
      int ix = x0 + dx; if ((unsigned)ix >= 14u) continue;
      unsigned vv = f14u[(size_t)(n * 196 + iy * 14 + ix) * 256 + c2];
      m0 = fmaxf(m0, __builtin_bit_cast(float, vv << 16));
      m1 = fmaxf(m1, __builtin_bit_cast(float, vv & 0xffff0000u));
    }
  }
  bf16 b0 = (bf16)m0, b1 = (bf16)m1;
  unsigned pk = (unsigned)__builtin_bit_cast(unsigned short, b0)
              | ((unsigned)__builtin_bit_cast(unsigned short, b1) << 16);
  ((unsigned*)f7b)[idx] = pk;
}

// K5: group attention (8x8 within group, mask from rois)
__global__ __launch_bounds__(256)
void k_attn(const bf16* __restrict__ q, const bf16* __restrict__ k,
            const bf16* __restrict__ v, const float* __restrict__ rois,
            float* __restrict__ virt)
{
  const int p = blockIdx.x, g = blockIdx.y, t = threadIdx.x;
  __shared__ float sS[8][9];
  __shared__ float sP[8][9];
  __shared__ __attribute__((aligned(16))) bf16 sV[8][512];
  {
    int u = t;
    #pragma unroll
    for (int rep = 0; rep < 2; ++rep, u += 256) {
      int j = u >> 6, ch = u & 63;
      *(v8bf*)&sV[j][ch * 8] = *(const v8bf*)(v + ((size_t)(g * 8 + j) * 49 + p) * 512 + ch * 8);
    }
  }
  int pi = t >> 2, ls = t & 3;
  int i = pi >> 3, j = pi & 7;
  const bf16* qi = q + ((size_t)(g * 8 + i) * 49 + p) * 512;
  const bf16* kj = k + ((size_t)(g * 8 + j) * 49 + p) * 512;
  float s = 0.f;
  for (int ch = ls * 16; ch < ls * 16 + 16; ++ch) {
    v8bf a = *(const v8bf*)(qi + ch * 8);
    v8bf b = *(const v8bf*)(kj + ch * 8);
    #pragma unroll
    for (int e = 0; e < 8; ++e) s += (float)a[e] * (float)b[e];
  }
  s += __shfl_xor(s, 1);
  s += __shfl_xor(s, 2);
  if (ls == 0) sS[i][j] = s * 0.04419417382415922f;
  __syncthreads();
  if (t < 8) {
    float gi = rois[(g * 8 + t) * 5];
    float pv[8]; float mx = -3.4e38f;
    #pragma unroll
    for (int jj = 0; jj < 8; ++jj) {
      float gj = rois[(g * 8 + jj) * 5];
      float sv = (gi == gj) ? sS[t][jj] : -1e30f;
      pv[jj] = sv; mx = fmaxf(mx, sv);
    }
    float sum = 0.f;
    #pragma unroll
    for (int jj = 0; jj < 8; ++jj) { float e = expf(pv[jj] - mx); pv[jj] = e; sum += e; }
    float inv = 1.f / sum;
    #pragma unroll
    for (int jj = 0; jj < 8; ++jj) sP[t][jj] = pv[jj] * inv;
  }
  __syncthreads();
  int i2 = t >> 5, c0 = (t & 31) * 16;
  float o[16];
  #pragma unroll
  for (int e = 0; e < 16; ++e) o[e] = 0.f;
  #pragma unroll
  for (int jj = 0; jj < 8; ++jj) {
    float ww = sP[i2][jj];
    v8bf v0 = *(const v8bf*)&sV[jj][c0];
    v8bf v1 = *(const v8bf*)&sV[jj][c0 + 8];
    #pragma unroll
    for (int e = 0; e < 8; ++e) { o[e] += ww * (float)v0[e]; o[8 + e] += ww * (float)v1[e]; }
  }
  float* dst = virt + ((size_t)(g * 8 + i2) * 49 + p) * 512 + c0;
  #pragma unroll
  for (int e = 0; e < 16; ++e) dst[e] = o[e];
}

// K6: per-sample LN stats
__global__ __launch_bounds__(256)
void k_lnstats(const float* __restrict__ virt, float* __restrict__ stats)
{
  int n = blockIdx.x, t = threadIdx.x;
  const float* p = virt + (size_t)n * 25088;
  float s1 = 0.f, s2 = 0.f;
  for (int idx = t; idx < 25088; idx += 256) { float x = p[idx]; s1 += x; s2 += x * x; }
  __shared__ float r1[256], r2[256];
  r1[t] = s1; r2[t] = s2; __syncthreads();
  for (int off = 128; off; off >>= 1) {
    if (t < off) { r1[t] += r1[t + off]; r2[t] += r2[t + off]; }
    __syncthreads();
  }
  if (t == 0) {
    float mu = r1[0] * (1.f / 25088.f);
    float var = r2[0] * (1.f / 25088.f) - mu * mu;
    stats[2 * n] = mu;
    stats[2 * n + 1] = rsqrtf(var + 1e-5f);
  }
}

// K7: LN apply + gamma/beta + ReLU -> bf16
__global__ void k_lnapply(const float* __restrict__ virt, const float* __restrict__ stats,
                          const float* __restrict__ gamma, const float* __restrict__ beta,
                          bf16* __restrict__ virtn)
{
  int idx = blockIdx.x * 256 + threadIdx.x;
  int c = idx & 511;
  int n = (idx >> 9) / 49;
  float mu = stats[2 * n], rstd = stats[2 * n + 1];
  float y = (virt[idx] - mu) * rstd * gamma[c] + beta[c];
  virtn[idx] = (bf16)fmaxf(y, 0.f);
}

// K8: windowed sums for the mean-of-conv trick + f7 mean. block=n, 2 ci/thread.
__global__ __launch_bounds__(256)
void k_sums(const bf16* __restrict__ virtn, const bf16* __restrict__ f7b,
            bf16* __restrict__ A_s, float* __restrict__ f7m)
{
  const int n = blockIdx.x, t = threadIdx.x;
  const unsigned* vp = (const unsigned*)virtn + (size_t)n * 49 * 256 + t;
  const unsigned* fp = (const unsigned*)f7b + (size_t)n * 49 * 256 + t;
  float T0=0,T1=0,R0a=0,R0b=0,R6a=0,R6b=0,C0a=0,C0b=0,C6a=0,C6b=0;
  float X00a=0,X00b=0,X06a=0,X06b=0,X60a=0,X60b=0,X66a=0,X66b=0;
  float F0=0,F1=0;
  int u = 0, v = 0;
  for (int p = 0; p < 49; ++p) {
    unsigned av = vp[(size_t)p * 256], fv = fp[(size_t)p * 256];
    float a0 = __builtin_bit_cast(float, av << 16);
    float a1 = __builtin_bit_cast(float, av & 0xffff0000u);
    float b0 = __builtin_bit_cast(float, fv << 16);
    float b1 = __builtin_bit_cast(float, fv & 0xffff0000u);
    T0 += a0; T1 += a1; F0 += b0; F1 += b1;
    if (u == 0) { R0a += a0; R0b += a1; }
    if (u == 6) { R6a += a0; R6b += a1; }
    if (v == 0) { C0a += a0; C0b += a1; }
    if (v == 6) { C6a += a0; C6b += a1; }
    if (p == 0)  { X00a = a0; X00b = a1; }
    if (p == 6)  { X06a = a0; X06b = a1; }
    if (p == 42) { X60a = a0; X60b = a1; }
    if (p == 48) { X66a = a0; X66b = a1; }
    if (++v == 7) { v = 0; ++u; }
  }
  float s0[9] = { T0-R6a-C6a+X66a, T0-R6a, T0-R6a-C0a+X60a,
                  T0-C6a,          T0,     T0-C0a,
                  T0-R0a-C6a+X06a, T0-R0a, T0-R0a-C0a+X00a };
  float s1[9] = { T1-R6b-C6b+X66b, T1-R6b, T1-R6b-C0b+X60b,
                  T1-C6b,          T1,     T1-C0b,
                  T1-R0b-C6b+X06b, T1-R0b, T1-R0b-C0b+X00b };
  unsigned* Ap = (unsigned*)A_s + (size_t)n * 2304 + t;
  #pragma unroll
  for (int tap = 0; tap < 9; ++tap) {
    bf16 lo = (bf16)(s0[tap] * (1.f / 49.f));
    bf16 hi = (bf16)(s1[tap] * (1.f / 49.f));
    unsigned pk = (unsigned)__builtin_bit_cast(unsigned short, lo)
                | ((unsigned)__builtin_bit_cast(unsigned short, hi) << 16);
    Ap[tap * 256] = pk;
  }
  f7m[n * 512 + 2 * t]     = F0 * (1.f / 49.f);
  f7m[n * 512 + 2 * t + 1] = F1 * (1.f / 49.f);
}

// K10a: obm = mean bbox over 196; 4 lanes per channel, coalesced float4
__global__ __launch_bounds__(256)
void k_obm(const float* __restrict__ bbox, float* __restrict__ obm)
{
  int n = blockIdx.x;
  int c = blockIdx.y * 64 + (threadIdx.x >> 2);
  int seg = threadIdx.x & 3;
  const float4* p4 = (const float4*)(bbox + ((size_t)n * 1024 + c) * 196);
  float s = 0.f;
  for (int k = seg; k < 49; k += 4) { float4 w = p4[k]; s += w.x + w.y + w.z + w.w; }
  s += __shfl_xor(s, 1);
  s += __shfl_xor(s, 2);
  if (seg == 0) obm[n * 1024 + c] = s * (1.f / 196.f);
}

// K10b: fc + relu -> out[:, 512:1024]
__global__ __launch_bounds__(256)
void k_fc(const float* __restrict__ obm, const float* __restrict__ wfc,
          float* __restrict__ out)
{
  int n = blockIdx.x, t = threadIdx.x;
  __shared__ float sO[1024];
  for (int u = t; u < 1024; u += 256) sO[u] = obm[n * 1024 + u];
  __syncthreads();
  for (int jj = t; jj < 512; jj += 256) {
    const float4* wp = (const float4*)(wfc + (size_t)jj * 1024);
    float s = 0.f;
    for (int c4 = 0; c4 < 256; ++c4) {
      float4 w = wp[c4];
      s += w.x * sO[c4 * 4] + w.y * sO[c4 * 4 + 1] + w.z * sO[c4 * 4 + 2] + w.w * sO[c4 * 4 + 3];
    }
    out[n * 1024 + 512 + jj] = fmaxf(s, 0.f);
  }
}

// ---------------------------------------------------------------------------
extern "C" void kernel_launch(void* const* d_in, const int* in_sizes, int n_in,
                              void* d_out, int out_size, void* d_ws, size_t ws_size,
                              hipStream_t stream) {
  const float* rois     = (const float*)d_in[0];
  const float* interact = (const float*)d_in[1];
  const float* bbox     = (const float*)d_in[2];
  const float* w_reduce = (const float*)d_in[3];
  const float* w_rsize  = (const float*)d_in[4];
  const float* wq       = (const float*)d_in[5];
  const float* wk       = (const float*)d_in[6];
  const float* wv       = (const float*)d_in[7];
  const float* w1       = (const float*)d_in[8];
  const float* gamma    = (const float*)d_in[9];
  const float* beta     = (const float*)d_in[10];
  const float* wfc      = (const float*)d_in[11];
  float* out = (float*)d_out;
  char* ws = (char*)d_ws;

  size_t o = 0;
  auto take = [&](size_t sz) { size_t r = o; o += (sz + 255) & ~(size_t)255; return r; };
  bf16*  wrb   = (bf16*)(ws + take(2359296));
  bf16*  wt    = (bf16*)(ws + take(18874368));   // [4][9][512][512] bf16 (rsize,q,k,v)
  bf16*  w1r   = (bf16*)(ws + take(4718592));    // [512 co][9 tap][512 ci] bf16
  char*  Rf1   = ws + take(33554432);            // f1 (33.6MB) -> later q,k,v (19.3MB)
  bf16*  f7b   = (bf16*)(ws + take(6422528));
  float* virt  = (float*)(ws + take(12845056));
  bf16*  virtn = (bf16*)(ws + take(6422528));
  bf16*  A_s   = (bf16*)(ws + take(1179648));
  float* f7m   = (float*)(ws + take(262144));
  float* stats = (float*)(ws + take(1024));
  float* obm   = (float*)(ws + take(524288));
  bf16*  zp    = (bf16*)(ws + take(256));
  size_t fixedEnd = o;
  const size_t A1_FULL = 150994944;
  bool full = (ws_size >= fixedEnd + A1_FULL);
  bf16* A1  = (bf16*)(ws + fixedEnd);
  bf16* f14 = (bf16*)(ws + fixedEnd);

  bf16* f1 = (bf16*)Rf1;
  bf16* qb = (bf16*)Rf1;
  bf16* kb = qb + 3211264;
  bf16* vb = kb + 3211264;

  hipMemsetAsync(zp, 0, 256, stream);

  k_castw<<<1152, 256, 0, stream>>>(w_reduce, wrb, 1179648);
  k_wtrans<<<dim3(1024, 5), 256, 0, stream>>>(w_rsize, wq, wk, wv, w1, wt, w1r);

  if (full) {
    k_tin<<<dim3(72, 8, 128), 256, 0, stream>>>(interact, A1, 0);
    k_gemm_reduce<<<1024, 256, 0, stream>>>(A1, wrb, f1, 0);
  } else {
    for (int ch = 0; ch < 4; ++ch) {
      k_tin<<<dim3(72, 8, 32), 256, 0, stream>>>(interact, A1, ch * 32);
      k_gemm_reduce<<<256, 256, 0, stream>>>(A1, wrb, f1, ch * 8192);
    }
  }

  k_conv_rsize<<<784, 256, 0, stream>>>(f1, wt, f14);
  k_pool<<<6272, 256, 0, stream>>>(f14, f7b);

  k_conv_qkv<<<588, 256, 0, stream>>>(f7b, wt + (size_t)1 * 2359296, qb, zp);

  k_attn<<<dim3(49, 16), 256, 0, stream>>>(qb, kb, vb, rois, virt);

  k_lnstats<<<128, 256, 0, stream>>>(virt, stats);
  k_lnapply<<<12544, 256, 0, stream>>>(virt, stats, gamma, beta, virtn);

  k_sums<<<128, 256, 0, stream>>>(virtn, f7b, A_s, f7m);
  k_gemm_s<<<4, 256, 0, stream>>>(A_s, w1r, f7m, out);

  k_obm<<<dim3(128, 16), 256, 0, stream>>>(bbox, obm);
  k_fc<<<128, 256, 0, stream>>>(obm, wfc, out);
}

// Round 4
// 701.216 us; speedup vs baseline: 1.3568x; 1.0909x over previous
//
#include <hip/hip_runtime.h>
#include <hip/hip_bf16.h>
#include <math.h>

typedef __bf16 bf16;
typedef __bf16 v8bf __attribute__((ext_vector_type(8)));
typedef float f32x4 __attribute__((ext_vector_type(4)));

// async global->LDS, 16B per lane. LDS dest ends up wave-uniform base + lane*16
// because our per-thread offset is exactly t*16 (lane-linear within a wave).
#define GLDS16(g, l) __builtin_amdgcn_global_load_lds( \
    (const __attribute__((address_space(1))) void*)(g), \
    (__attribute__((address_space(3))) void*)(l), 16, 0, 0)

// bijective XCD-chunk swizzle (m204 variant, works for any nwg):
// consecutive returned s values land on the same XCD.
__device__ __forceinline__ int xcd_swz(int bid, int nwg) {
  int xcd = bid & 7, off = bid >> 3;
  int q = nwg >> 3, r = nwg & 7;
  return (xcd < r ? xcd * (q + 1) : r * (q + 1) + (xcd - r) * q) + off;
}

// ---------------------------------------------------------------------------
// Shared MFMA core: 128x128 tile, BK=64, 4 waves (2x2 of 64x64), double-
// buffered LDS (2 x 32KB) with counted-vmcnt pipeline (T3/T4):
//   per iter: vmcnt(8); barrier; compute(cur); barrier; stage(ks+2 -> cur)
// Each stage = exactly 8 global_load_lds, so vmcnt(8) waits for stage(ks)
// while stage(ks+1)'s 8 loads stay in flight across the barriers. vmcnt(0)
// only before the final tile. Barrier-after-vmcnt makes cross-wave staging
// visible (every wave's stage(ks) landed before anyone passes barrier 1).
// LDS tile [128 rows][128 B], XOR swizzle: phys colbyte = logical ^ ((row&7)<<4).
// gload_lds fills linearly (thread t, issue i -> row i*32+(t>>3), colbyte
// (t&7)*16), so the global source column is pre-inverse-swizzled:
// cphys = ((t&7)<<4) ^ (((t>>3)&7)<<4).  MFMA C/D: col=lane&15, row=4*(lane>>4)+reg.
// ---------------------------------------------------------------------------
__device__ __forceinline__ void tile_compute(const char* ldsA, const char* ldsB,
                                             f32x4 (&acc)[4][4], int wr, int wc, int lane) {
  const int l15 = lane & 15;
  const int colb = (lane >> 4) << 4;
  #pragma unroll
  for (int kk = 0; kk < 2; ++kk) {
    v8bf a[4], b[4];
    #pragma unroll
    for (int i = 0; i < 4; ++i) {
      int ra = wr * 64 + i * 16 + l15;
      int ca = ((kk << 6) | colb) ^ ((ra & 7) << 4);
      a[i] = *(const v8bf*)(ldsA + ra * 128 + ca);
    }
    #pragma unroll
    for (int j = 0; j < 4; ++j) {
      int rb = wc * 64 + j * 16 + l15;
      int cb = ((kk << 6) | colb) ^ ((rb & 7) << 4);
      b[j] = *(const v8bf*)(ldsB + rb * 128 + cb);
    }
    #pragma unroll
    for (int i = 0; i < 4; ++i)
      #pragma unroll
      for (int j = 0; j < 4; ++j)
        acc[i][j] = __builtin_amdgcn_mfma_f32_16x16x32_bf16(a[i], b[j], acc[i][j], 0, 0, 0);
  }
}

// The counted-vmcnt pipelined K-loop. `stage(ks, base)` must issue exactly
// 8 global_load_lds. Never drains vmcnt to 0 except before the last tile.
#define PIPELINE_LOOP(NK)                                                   \
  stage(0, lds);                                                            \
  stage(1, lds + 32768);                                                    \
  int cur = 0;                                                              \
  for (int ks = 0; ks < (NK) - 1; ++ks) {                                   \
    asm volatile("s_waitcnt vmcnt(8)" ::: "memory");                        \
    __builtin_amdgcn_s_barrier();                                           \
    __builtin_amdgcn_sched_barrier(0);                                      \
    tile_compute(lds + cur * 32768, lds + cur * 32768 + 16384, acc, wr, wc, lane); \
    __builtin_amdgcn_sched_barrier(0);                                      \
    __builtin_amdgcn_s_barrier();                                           \
    __builtin_amdgcn_sched_barrier(0);                                      \
    if (ks + 2 < (NK)) stage(ks + 2, lds + cur * 32768);                    \
    cur ^= 1;                                                               \
  }                                                                         \
  asm volatile("s_waitcnt vmcnt(0)" ::: "memory");                          \
  __builtin_amdgcn_s_barrier();                                             \
  __builtin_amdgcn_sched_barrier(0);                                        \
  tile_compute(lds + cur * 32768, lds + cur * 32768 + 16384, acc, wr, wc, lane);

template<typename OutT, bool RELU>
__device__ __forceinline__ void store_tile(OutT* __restrict__ C, int m0, int c0,
                                           f32x4 (&acc)[4][4], int lane) {
  const int rbase = (lane >> 4) << 2;
  const int cl = lane & 15;
  #pragma unroll
  for (int i = 0; i < 4; ++i)
    #pragma unroll
    for (int j = 0; j < 4; ++j)
      #pragma unroll
      for (int r = 0; r < 4; ++r) {
        float v = acc[i][j][r];
        if (RELU) v = fmaxf(v, 0.f);
        C[(size_t)(m0 + i * 16 + rbase + r) * 512 + (c0 + j * 16 + cl)] = (OutT)v;
      }
}

// ---------------------------------------------------------------------------
// G1: 1x1 reduce conv + ReLU. A = interact^T bf16 [m][2304], B = wrb [512][2304].
// by (N-tile) is the fast swizzle dim for A-tile L2 reuse.
// ---------------------------------------------------------------------------
__global__ __launch_bounds__(256)
void k_gemm_reduce(const bf16* __restrict__ A, const bf16* __restrict__ B,
                   bf16* __restrict__ f1, int mbase)
{
  __shared__ __attribute__((aligned(16))) char lds[65536];
  const int s = xcd_swz(blockIdx.x, gridDim.x);
  const int by = s & 3, bx = s >> 2;
  const int t = threadIdx.x, lane = t & 63, w = t >> 6, wr = w >> 1, wc = w & 1;
  const int tr = t >> 3;
  const int cphys = ((t & 7) << 4) ^ ((tr & 7) << 4);
  const char* pa[4]; const char* pb[4];
  #pragma unroll
  for (int i = 0; i < 4; ++i) {
    int r = i * 32 + tr;
    pa[i] = (const char*)A + (size_t)(bx * 128 + r) * 4608 + cphys;
    pb[i] = (const char*)B + (size_t)(by * 128 + r) * 4608 + cphys;
  }
  const int lo = t * 16;
  auto stage = [&](int ks, char* base) {
    #pragma unroll
    for (int i = 0; i < 4; ++i) GLDS16(pa[i] + ks * 128, base + lo + i * 4096);
    #pragma unroll
    for (int i = 0; i < 4; ++i) GLDS16(pb[i] + ks * 128, base + 16384 + lo + i * 4096);
  };
  f32x4 acc[4][4] = {};
  PIPELINE_LOOP(36)
  store_tile<bf16, true>(f1, mbase + bx * 128 + wr * 64, by * 128 + wc * 64, acc, lane);
}

// ---------------------------------------------------------------------------
// G2: 3x3 VALID conv (16x16 -> 14x14). f1 NHWC bf16 -> f14 NHWC bf16.
// ---------------------------------------------------------------------------
__global__ __launch_bounds__(256)
void k_conv_rsize(const bf16* __restrict__ f1, const bf16* __restrict__ wt,
                  bf16* __restrict__ f14)
{
  __shared__ __attribute__((aligned(16))) char lds[65536];
  const int s = xcd_swz(blockIdx.x, gridDim.x);
  const int by = s & 3, bx = s >> 2;
  const int t = threadIdx.x, lane = t & 63, w = t >> 6, wr = w >> 1, wc = w & 1;
  const int tr = t >> 3;
  const int cphys = ((t & 7) << 4) ^ ((tr & 7) << 4);
  int abase[4]; const char* pb[4];
  #pragma unroll
  for (int i = 0; i < 4; ++i) {
    int r = i * 32 + tr;
    int m = bx * 128 + r;
    int n = m / 196, rem = m - n * 196;
    int y = rem / 14, x = rem - 14 * (rem / 14);
    abase[i] = n * 256 + y * 16 + x;
    pb[i] = (const char*)wt + (size_t)(by * 128 + r) * 1024 + cphys;
  }
  const char* f1c = (const char*)f1 + cphys;
  const int lo = t * 16;
  auto stage = [&](int ks, char* base) {
    int tap = ks >> 3, ko = (ks & 7) << 7;
    int dy = (tap * 11) >> 5, dx = tap - dy * 3;
    int doff = dy * 16 + dx;
    #pragma unroll
    for (int i = 0; i < 4; ++i)
      GLDS16(f1c + ((size_t)(abase[i] + doff) << 10) + ko, base + lo + i * 4096);
    #pragma unroll
    for (int i = 0; i < 4; ++i)
      GLDS16(pb[i] + (size_t)tap * 524288 + ko, base + 16384 + lo + i * 4096);
  };
  f32x4 acc[4][4] = {};
  PIPELINE_LOOP(72)
  store_tile<bf16, false>(f14, bx * 128 + wr * 64, by * 128 + wc * 64, acc, lane);
}

// ---------------------------------------------------------------------------
// G4: merged q/k/v 3x3 SAME conv on 7x7. (tensor,by) is the fast swizzle dim
// so 12 consecutive blocks share one A-tile via L2.
// ---------------------------------------------------------------------------
__global__ __launch_bounds__(256)
void k_conv_qkv(const bf16* __restrict__ fin, const bf16* __restrict__ wt,
                bf16* __restrict__ qkv, const bf16* __restrict__ zp)
{
  __shared__ __attribute__((aligned(16))) char lds[65536];
  const int s = xcd_swz(blockIdx.x, gridDim.x);
  const int q12 = s % 12, bx = s / 12;
  const int tensor = q12 >> 2, by = q12 & 3;
  const char* wtc = (const char*)wt + (size_t)tensor * 4718592;
  bf16* outp = qkv + (size_t)tensor * 3211264;
  const int t = threadIdx.x, lane = t & 63, w = t >> 6, wr = w >> 1, wc = w & 1;
  const int tr = t >> 3;
  const int cphys = ((t & 7) << 4) ^ ((tr & 7) << 4);
  int nb[4], py[4], px[4]; const char* pb[4];
  #pragma unroll
  for (int i = 0; i < 4; ++i) {
    int r = i * 32 + tr;
    int m = bx * 128 + r;
    int n = m / 49, rem = m - n * 49;
    nb[i] = n * 49;
    py[i] = rem / 7 - 1;
    px[i] = rem - 7 * (rem / 7) - 1;
    pb[i] = wtc + (size_t)(by * 128 + r) * 1024 + cphys;
  }
  const char* finc = (const char*)fin + cphys;
  const char* zpc = (const char*)zp;
  const int lo = t * 16;
  auto stage = [&](int ks, char* base) {
    int tap = ks >> 3, ko = (ks & 7) << 7;
    int dy = (tap * 11) >> 5, dx = tap - dy * 3;
    #pragma unroll
    for (int i = 0; i < 4; ++i) {
      int iy = py[i] + dy, ix = px[i] + dx;
      const char* src = ((unsigned)iy < 7u && (unsigned)ix < 7u)
          ? finc + ((size_t)(nb[i] + iy * 7 + ix) << 10) + ko : zpc;
      GLDS16(src, base + lo + i * 4096);
    }
    #pragma unroll
    for (int i = 0; i < 4; ++i)
      GLDS16(pb[i] + (size_t)tap * 524288 + ko, base + 16384 + lo + i * 4096);
  };
  f32x4 acc[4][4] = {};
  PIPELINE_LOOP(72)
  store_tile<bf16, false>(outp, bx * 128 + wr * 64, by * 128 + wc * 64, acc, lane);
}

// ---------------------------------------------------------------------------
// G6: tiny GEMM replacing w1-conv + ho-mean: out[:, :512] = A_s @ w1r^T + f7m.
// ---------------------------------------------------------------------------
__global__ __launch_bounds__(256)
void k_gemm_s(const bf16* __restrict__ A_s, const bf16* __restrict__ w1r,
              const float* __restrict__ f7m, float* __restrict__ out)
{
  __shared__ __attribute__((aligned(16))) char lds[65536];
  const int by = blockIdx.x;
  const int t = threadIdx.x, lane = t & 63, w = t >> 6, wr = w >> 1, wc = w & 1;
  const int tr = t >> 3;
  const int cphys = ((t & 7) << 4) ^ ((tr & 7) << 4);
  const char* pa[4]; const char* pb[4];
  #pragma unroll
  for (int i = 0; i < 4; ++i) {
    int r = i * 32 + tr;
    pa[i] = (const char*)A_s + (size_t)r * 9216 + cphys;
    pb[i] = (const char*)w1r + (size_t)(by * 128 + r) * 9216 + cphys;
  }
  const int lo = t * 16;
  auto stage = [&](int ks, char* base) {
    #pragma unroll
    for (int i = 0; i < 4; ++i) GLDS16(pa[i] + ks * 128, base + lo + i * 4096);
    #pragma unroll
    for (int i = 0; i < 4; ++i) GLDS16(pb[i] + ks * 128, base + 16384 + lo + i * 4096);
  };
  f32x4 acc[4][4] = {};
  PIPELINE_LOOP(72)
  const int rb = (lane >> 4) << 2, cl = lane & 15;
  #pragma unroll
  for (int i = 0; i < 4; ++i)
    #pragma unroll
    for (int j = 0; j < 4; ++j)
      #pragma unroll
      for (int r = 0; r < 4; ++r) {
        int row = wr * 64 + i * 16 + rb + r;
        int col = by * 128 + wc * 64 + j * 16 + cl;
        out[(size_t)row * 1024 + col] = acc[i][j][r] + f7m[row * 512 + col];
      }
}

// ---------------------------------------------------------------------------
// P0: transpose+cast interact (n,2304,256) f32 -> A1 bf16 [(nl*256+p)][2304].
// 64k x 32p tiles; float4 global loads, 16 B packed v8bf stores.
// ---------------------------------------------------------------------------
__global__ void k_tin(const float* __restrict__ in, bf16* __restrict__ A1, int n0)
{
  __shared__ float tile[64][36];
  const int k0 = blockIdx.x * 64, p0 = blockIdx.y * 32, nl = blockIdx.z;
  const int n = n0 + nl;
  const int t = threadIdx.x;
  const float* src = in + (size_t)n * 2304 * 256;
  #pragma unroll
  for (int rep = 0; rep < 2; ++rep) {
    int idx = t + rep * 256;          // 0..511 -> (row, c4)
    int row = idx >> 3, c4 = (idx & 7) * 4;
    float4 v = *(const float4*)(src + (size_t)(k0 + row) * 256 + p0 + c4);
    tile[row][c4] = v.x; tile[row][c4 + 1] = v.y;
    tile[row][c4 + 2] = v.z; tile[row][c4 + 3] = v.w;
  }
  __syncthreads();
  const int pl = t >> 3, ke = (t & 7) * 8;
  v8bf o;
  #pragma unroll
  for (int e = 0; e < 8; ++e) o[e] = (bf16)tile[ke + e][pl];
  bf16* dst = A1 + (size_t)nl * 256 * 2304;
  *(v8bf*)(dst + (size_t)(p0 + pl) * 2304 + k0 + ke) = o;
}

// P1: cast w_reduce f32 -> bf16
__global__ void k_castw(const float* __restrict__ wsrc, bf16* __restrict__ wb, int nelem)
{
  int idx = (blockIdx.x * 256 + threadIdx.x) * 4;
  if (idx >= nelem) return;
  float4 v = *(const float4*)(wsrc + idx);
  bf16 o0 = (bf16)v.x, o1 = (bf16)v.y, o2 = (bf16)v.z, o3 = (bf16)v.w;
  bf16* d = wb + idx;
  d[0] = o0; d[1] = o1; d[2] = o2; d[3] = o3;
}

// P2: (co,ci,3,3) f32 -> wt [tensor<4][tap][co][ci] bf16; w1 -> w1r [co][tap][ci]
__global__ void k_wtrans(const float* __restrict__ s0, const float* __restrict__ s1,
                         const float* __restrict__ s2, const float* __restrict__ s3,
                         const float* __restrict__ s4, bf16* __restrict__ wt,
                         bf16* __restrict__ w1r)
{
  const float* src;
  switch (blockIdx.y) {
    case 0: src = s0; break; case 1: src = s1; break; case 2: src = s2; break;
    case 3: src = s3; break; default: src = s4; break;
  }
  int q = blockIdx.x * 256 + threadIdx.x;   // co*512+ci
  const float* sp = src + (size_t)q * 9;
  float tmp[9];
  #pragma unroll
  for (int e = 0; e < 9; ++e) tmp[e] = sp[e];
  if (blockIdx.y < 4) {
    bf16* dst = wt + (size_t)blockIdx.y * 2359296;
    #pragma unroll
    for (int e = 0; e < 9; ++e) dst[(size_t)e * 262144 + q] = (bf16)tmp[e];
  } else {
    int co = q >> 9, ci = q & 511;
    #pragma unroll
    for (int e = 0; e < 9; ++e) w1r[(size_t)(co * 9 + e) * 512 + ci] = (bf16)tmp[e];
  }
}

// K3: maxpool 3x3 s2 p1, 14x14 -> 7x7, bf16, 2 channels/thread
__global__ void k_pool(const bf16* __restrict__ f14, bf16* __restrict__ f7b)
{
  int idx = blockIdx.x * 256 + threadIdx.x;   // 128*49*256
  int c2 = idx & 255;
  int pp = idx >> 8;
  int n = pp / 49, p7 = pp - n * 49;
  int y = p7 / 7, x = p7 - 7 * (p7 / 7);
  int y0 = 2 * y - 1, x0 = 2 * x - 1;
  const unsigned* f14u = (const unsigned*)f14;
  float m0 = -3.4e38f, m1 = -3.4e38f;
  #pragma unroll
  for (int dy = 0; dy < 3; ++dy) {
    int iy = y0 + dy; if ((unsigned)iy >= 14u) continue;
    #pragma unroll
    for (int dx = 0; dx < 3; ++dx) {
      int ix = x0 + dx; if ((unsigned)ix >= 14u) continue;
      unsigned vv = f14u[(size_t)(n * 196 + iy * 14 + ix) * 256 + c2];
      m0 = fmaxf(m0, __builtin_bit_cast(float, vv << 16));
      m1 = fmaxf(m1, __builtin_bit_cast(float, vv & 0xffff0000u));
    }
  }
  bf16 b0 = (bf16)m0, b1 = (bf16)m1;
  unsigned pk = (unsigned)__builtin_bit_cast(unsigned short, b0)
              | ((unsigned)__builtin_bit_cast(unsigned short, b1) << 16);
  ((unsigned*)f7b)[idx] = pk;
}

// K5: group attention (8x8 within group, mask from rois)
__global__ __launch_bounds__(256)
void k_attn(const bf16* __restrict__ q, const bf16* __restrict__ k,
            const bf16* __restrict__ v, const float* __restrict__ rois,
            float* __restrict__ virt)
{
  const int p = blockIdx.x, g = blockIdx.y, t = threadIdx.x;
  __shared__ float sS[8][9];
  __shared__ float sP[8][9];
  __shared__ __attribute__((aligned(16))) bf16 sV[8][512];
  {
    int u = t;
    #pragma unroll
    for (int rep = 0; rep < 2; ++rep, u += 256) {
      int j = u >> 6, ch = u & 63;
      *(v8bf*)&sV[j][ch * 8] = *(const v8bf*)(v + ((size_t)(g * 8 + j) * 49 + p) * 512 + ch * 8);
    }
  }
  int pi = t >> 2, ls = t & 3;
  int i = pi >> 3, j = pi & 7;
  const bf16* qi = q + ((size_t)(g * 8 + i) * 49 + p) * 512;
  const bf16* kj = k + ((size_t)(g * 8 + j) * 49 + p) * 512;
  float s = 0.f;
  for (int ch = ls * 16; ch < ls * 16 + 16; ++ch) {
    v8bf a = *(const v8bf*)(qi + ch * 8);
    v8bf b = *(const v8bf*)(kj + ch * 8);
    #pragma unroll
    for (int e = 0; e < 8; ++e) s += (float)a[e] * (float)b[e];
  }
  s += __shfl_xor(s, 1);
  s += __shfl_xor(s, 2);
  if (ls == 0) sS[i][j] = s * 0.04419417382415922f;
  __syncthreads();
  if (t < 8) {
    float gi = rois[(g * 8 + t) * 5];
    float pv[8]; float mx = -3.4e38f;
    #pragma unroll
    for (int jj = 0; jj < 8; ++jj) {
      float gj = rois[(g * 8 + jj) * 5];
      float sv = (gi == gj) ? sS[t][jj] : -1e30f;
      pv[jj] = sv; mx = fmaxf(mx, sv);
    }
    float sum = 0.f;
    #pragma unroll
    for (int jj = 0; jj < 8; ++jj) { float e = expf(pv[jj] - mx); pv[jj] = e; sum += e; }
    float inv = 1.f / sum;
    #pragma unroll
    for (int jj = 0; jj < 8; ++jj) sP[t][jj] = pv[jj] * inv;
  }
  __syncthreads();
  int i2 = t >> 5, c0 = (t & 31) * 16;
  float o[16];
  #pragma unroll
  for (int e = 0; e < 16; ++e) o[e] = 0.f;
  #pragma unroll
  for (int jj = 0; jj < 8; ++jj) {
    float ww = sP[i2][jj];
    v8bf v0 = *(const v8bf*)&sV[jj][c0];
    v8bf v1 = *(const v8bf*)&sV[jj][c0 + 8];
    #pragma unroll
    for (int e = 0; e < 8; ++e) { o[e] += ww * (float)v0[e]; o[8 + e] += ww * (float)v1[e]; }
  }
  float* dst = virt + ((size_t)(g * 8 + i2) * 49 + p) * 512 + c0;
  #pragma unroll
  for (int e = 0; e < 16; ++e) dst[e] = o[e];
}

// K6: per-sample LN stats
__global__ __launch_bounds__(256)
void k_lnstats(const float* __restrict__ virt, float* __restrict__ stats)
{
  int n = blockIdx.x, t = threadIdx.x;
  const float* p = virt + (size_t)n * 25088;
  float s1 = 0.f, s2 = 0.f;
  for (int idx = t; idx < 25088; idx += 256) { float x = p[idx]; s1 += x; s2 += x * x; }
  __shared__ float r1[256], r2[256];
  r1[t] = s1; r2[t] = s2; __syncthreads();
  for (int off = 128; off; off >>= 1) {
    if (t < off) { r1[t] += r1[t + off]; r2[t] += r2[t + off]; }
    __syncthreads();
  }
  if (t == 0) {
    float mu = r1[0] * (1.f / 25088.f);
    float var = r2[0] * (1.f / 25088.f) - mu * mu;
    stats[2 * n] = mu;
    stats[2 * n + 1] = rsqrtf(var + 1e-5f);
  }
}

// K7: LN apply + gamma/beta + ReLU -> bf16
__global__ void k_lnapply(const float* __restrict__ virt, const float* __restrict__ stats,
                          const float* __restrict__ gamma, const float* __restrict__ beta,
                          bf16* __restrict__ virtn)
{
  int idx = blockIdx.x * 256 + threadIdx.x;
  int c = idx & 511;
  int n = (idx >> 9) / 49;
  float mu = stats[2 * n], rstd = stats[2 * n + 1];
  float y = (virt[idx] - mu) * rstd * gamma[c] + beta[c];
  virtn[idx] = (bf16)fmaxf(y, 0.f);
}

// K8: windowed sums for the mean-of-conv trick + f7 mean. block=n, 2 ci/thread.
__global__ __launch_bounds__(256)
void k_sums(const bf16* __restrict__ virtn, const bf16* __restrict__ f7b,
            bf16* __restrict__ A_s, float* __restrict__ f7m)
{
  const int n = blockIdx.x, t = threadIdx.x;
  const unsigned* vp = (const unsigned*)virtn + (size_t)n * 49 * 256 + t;
  const unsigned* fp = (const unsigned*)f7b + (size_t)n * 49 * 256 + t;
  float T0=0,T1=0,R0a=0,R0b=0,R6a=0,R6b=0,C0a=0,C0b=0,C6a=0,C6b=0;
  float X00a=0,X00b=0,X06a=0,X06b=0,X60a=0,X60b=0,X66a=0,X66b=0;
  float F0=0,F1=0;
  int u = 0, v = 0;
  for (int p = 0; p < 49; ++p) {
    unsigned av = vp[(size_t)p * 256], fv = fp[(size_t)p * 256];
    float a0 = __builtin_bit_cast(float, av << 16);
    float a1 = __builtin_bit_cast(float, av & 0xffff0000u);
    float b0 = __builtin_bit_cast(float, fv << 16);
    float b1 = __builtin_bit_cast(float, fv & 0xffff0000u);
    T0 += a0; T1 += a1; F0 += b0; F1 += b1;
    if (u == 0) { R0a += a0; R0b += a1; }
    if (u == 6) { R6a += a0; R6b += a1; }
    if (v == 0) { C0a += a0; C0b += a1; }
    if (v == 6) { C6a += a0; C6b += a1; }
    if (p == 0)  { X00a = a0; X00b = a1; }
    if (p == 6)  { X06a = a0; X06b = a1; }
    if (p == 42) { X60a = a0; X60b = a1; }
    if (p == 48) { X66a = a0; X66b = a1; }
    if (++v == 7) { v = 0; ++u; }
  }
  float s0[9] = { T0-R6a-C6a+X66a, T0-R6a, T0-R6a-C0a+X60a,
                  T0-C6a,          T0,     T0-C0a,
                  T0-R0a-C6a+X06a, T0-R0a, T0-R0a-C0a+X00a };
  float s1[9] = { T1-R6b-C6b+X66b, T1-R6b, T1-R6b-C0b+X60b,
                  T1-C6b,          T1,     T1-C0b,
                  T1-R0b-C6b+X06b, T1-R0b, T1-R0b-C0b+X00b };
  unsigned* Ap = (unsigned*)A_s + (size_t)n * 2304 + t;
  #pragma unroll
  for (int tap = 0; tap < 9; ++tap) {
    bf16 lo = (bf16)(s0[tap] * (1.f / 49.f));
    bf16 hi = (bf16)(s1[tap] * (1.f / 49.f));
    unsigned pk = (unsigned)__builtin_bit_cast(unsigned short, lo)
                | ((unsigned)__builtin_bit_cast(unsigned short, hi) << 16);
    Ap[tap * 256] = pk;
  }
  f7m[n * 512 + 2 * t]     = F0 * (1.f / 49.f);
  f7m[n * 512 + 2 * t + 1] = F1 * (1.f / 49.f);
}

// K10a: obm = mean bbox over 196; 4 lanes per channel, coalesced float4
__global__ __launch_bounds__(256)
void k_obm(const float* __restrict__ bbox, float* __restrict__ obm)
{
  int n = blockIdx.x;
  int c = blockIdx.y * 64 + (threadIdx.x >> 2);
  int seg = threadIdx.x & 3;
  const float4* p4 = (const float4*)(bbox + ((size_t)n * 1024 + c) * 196);
  float s = 0.f;
  for (int k = seg; k < 49; k += 4) { float4 w = p4[k]; s += w.x + w.y + w.z + w.w; }
  s += __shfl_xor(s, 1);
  s += __shfl_xor(s, 2);
  if (seg == 0) obm[n * 1024 + c] = s * (1.f / 196.f);
}

// K10b: fc + relu -> out[:, 512:1024]
__global__ __launch_bounds__(256)
void k_fc(const float* __restrict__ obm, const float* __restrict__ wfc,
          float* __restrict__ out)
{
  int n = blockIdx.x, t = threadIdx.x;
  __shared__ float sO[1024];
  for (int u = t; u < 1024; u += 256) sO[u] = obm[n * 1024 + u];
  __syncthreads();
  for (int jj = t; jj < 512; jj += 256) {
    const float4* wp = (const float4*)(wfc + (size_t)jj * 1024);
    float s = 0.f;
    for (int c4 = 0; c4 < 256; ++c4) {
      float4 w = wp[c4];
      s += w.x * sO[c4 * 4] + w.y * sO[c4 * 4 + 1] + w.z * sO[c4 * 4 + 2] + w.w * sO[c4 * 4 + 3];
    }
    out[n * 1024 + 512 + jj] = fmaxf(s, 0.f);
  }
}

// ---------------------------------------------------------------------------
extern "C" void kernel_launch(void* const* d_in, const int* in_sizes, int n_in,
                              void* d_out, int out_size, void* d_ws, size_t ws_size,
                              hipStream_t stream) {
  const float* rois     = (const float*)d_in[0];
  const float* interact = (const float*)d_in[1];
  const float* bbox     = (const float*)d_in[2];
  const float* w_reduce = (const float*)d_in[3];
  const float* w_rsize  = (const float*)d_in[4];
  const float* wq       = (const float*)d_in[5];
  const float* wk       = (const float*)d_in[6];
  const float* wv       = (const float*)d_in[7];
  const float* w1       = (const float*)d_in[8];
  const float* gamma    = (const float*)d_in[9];
  const float* beta     = (const float*)d_in[10];
  const float* wfc      = (const float*)d_in[11];
  float* out = (float*)d_out;
  char* ws = (char*)d_ws;

  size_t o = 0;
  auto take = [&](size_t sz) { size_t r = o; o += (sz + 255) & ~(size_t)255; return r; };
  bf16*  wrb   = (bf16*)(ws + take(2359296));
  bf16*  wt    = (bf16*)(ws + take(18874368));   // [4][9][512][512] bf16 (rsize,q,k,v)
  bf16*  w1r   = (bf16*)(ws + take(4718592));    // [512 co][9 tap][512 ci] bf16
  char*  Rf1   = ws + take(33554432);            // f1 (33.6MB) -> later q,k,v (19.3MB)
  bf16*  f7b   = (bf16*)(ws + take(6422528));
  float* virt  = (float*)(ws + take(12845056));
  bf16*  virtn = (bf16*)(ws + take(6422528));
  bf16*  A_s   = (bf16*)(ws + take(1179648));
  float* f7m   = (float*)(ws + take(262144));
  float* stats = (float*)(ws + take(1024));
  float* obm   = (float*)(ws + take(524288));
  bf16*  zp    = (bf16*)(ws + take(256));
  size_t fixedEnd = o;
  const size_t A1_FULL = 150994944;
  bool full = (ws_size >= fixedEnd + A1_FULL);
  bf16* A1  = (bf16*)(ws + fixedEnd);
  bf16* f14 = (bf16*)(ws + fixedEnd);

  bf16* f1 = (bf16*)Rf1;
  bf16* qb = (bf16*)Rf1;
  bf16* kb = qb + 3211264;
  bf16* vb = kb + 3211264;

  hipMemsetAsync(zp, 0, 256, stream);

  k_castw<<<1152, 256, 0, stream>>>(w_reduce, wrb, 1179648);
  k_wtrans<<<dim3(1024, 5), 256, 0, stream>>>(w_rsize, wq, wk, wv, w1, wt, w1r);

  if (full) {
    k_tin<<<dim3(36, 8, 128), 256, 0, stream>>>(interact, A1, 0);
    k_gemm_reduce<<<1024, 256, 0, stream>>>(A1, wrb, f1, 0);
  } else {
    for (int ch = 0; ch < 4; ++ch) {
      k_tin<<<dim3(36, 8, 32), 256, 0, stream>>>(interact, A1, ch * 32);
      k_gemm_reduce<<<256, 256, 0, stream>>>(A1, wrb, f1, ch * 8192);
    }
  }

  k_conv_rsize<<<784, 256, 0, stream>>>(f1, wt, f14);
  k_pool<<<6272, 256, 0, stream>>>(f14, f7b);

  k_conv_qkv<<<588, 256, 0, stream>>>(f7b, wt + (size_t)1 * 2359296, qb, zp);

  k_attn<<<dim3(49, 16), 256, 0, stream>>>(qb, kb, vb, rois, virt);

  k_lnstats<<<128, 256, 0, stream>>>(virt, stats);
  k_lnapply<<<12544, 256, 0, stream>>>(virt, stats, gamma, beta, virtn);

  k_sums<<<128, 256, 0, stream>>>(virtn, f7b, A_s, f7m);
  k_gemm_s<<<4, 256, 0, stream>>>(A_s, w1r, f7m, out);

  k_obm<<<dim3(128, 16), 256, 0, stream>>>(bbox, obm);
  k_fc<<<128, 256, 0, stream>>>(obm, wfc, out);
}

// Round 5
// 552.056 us; speedup vs baseline: 1.7234x; 1.2702x over previous
//
#include <hip/hip_runtime.h>
#include <hip/hip_bf16.h>
#include <math.h>

typedef __bf16 bf16;
typedef __bf16 v8bf __attribute__((ext_vector_type(8)));
typedef float f32x4 __attribute__((ext_vector_type(4)));

// async global->LDS, 16B per lane. LDS dest ends up wave-uniform base + lane*16
// because our per-thread offset is exactly t*16 (lane-linear within a wave).
#define GLDS16(g, l) __builtin_amdgcn_global_load_lds( \
    (const __attribute__((address_space(1))) void*)(g), \
    (__attribute__((address_space(3))) void*)(l), 16, 0, 0)

// bijective XCD-chunk swizzle (m204 variant, works for any nwg):
// consecutive returned s values land on the same XCD.
__device__ __forceinline__ int xcd_swz(int bid, int nwg) {
  int xcd = bid & 7, off = bid >> 3;
  int q = nwg >> 3, r = nwg & 7;
  return (xcd < r ? xcd * (q + 1) : r * (q + 1) + (xcd - r) * q) + off;
}

// ---------------------------------------------------------------------------
// Shared MFMA core: 128x128 tile, BK=64, 4 waves (2x2 of 64x64), double-
// buffered LDS (2 x 32KB) with counted-vmcnt pipeline (T3/T4):
//   per iter: vmcnt(8); barrier; compute(cur); barrier; stage(ks+2 -> cur)
// vmcnt(0) only before the final tile. T5 setprio wraps each MFMA cluster.
// LDS tile [128 rows][128 B], XOR swizzle: phys colbyte = logical ^ ((row&7)<<4).
// gload_lds fills linearly (thread t, issue i -> row i*32+(t>>3), colbyte
// (t&7)*16), so the global source column is pre-inverse-swizzled:
// cphys = ((t&7)<<4) ^ (((t>>3)&7)<<4).  MFMA C/D: col=lane&15, row=4*(lane>>4)+reg.
// ---------------------------------------------------------------------------
__device__ __forceinline__ void tile_compute(const char* ldsA, const char* ldsB,
                                             f32x4 (&acc)[4][4], int wr, int wc, int lane) {
  const int l15 = lane & 15;
  const int colb = (lane >> 4) << 4;
  #pragma unroll
  for (int kk = 0; kk < 2; ++kk) {
    v8bf a[4], b[4];
    #pragma unroll
    for (int i = 0; i < 4; ++i) {
      int ra = wr * 64 + i * 16 + l15;
      int ca = ((kk << 6) | colb) ^ ((ra & 7) << 4);
      a[i] = *(const v8bf*)(ldsA + ra * 128 + ca);
    }
    #pragma unroll
    for (int j = 0; j < 4; ++j) {
      int rb = wc * 64 + j * 16 + l15;
      int cb = ((kk << 6) | colb) ^ ((rb & 7) << 4);
      b[j] = *(const v8bf*)(ldsB + rb * 128 + cb);
    }
    __builtin_amdgcn_s_setprio(1);
    #pragma unroll
    for (int i = 0; i < 4; ++i)
      #pragma unroll
      for (int j = 0; j < 4; ++j)
        acc[i][j] = __builtin_amdgcn_mfma_f32_16x16x32_bf16(a[i], b[j], acc[i][j], 0, 0, 0);
    __builtin_amdgcn_s_setprio(0);
  }
}

// The counted-vmcnt pipelined K-loop. `stage(ks, base)` must issue exactly
// 8 global_load_lds. Never drains vmcnt to 0 except before the last tile.
#define PIPELINE_LOOP(NK)                                                   \
  stage(0, lds);                                                            \
  stage(1, lds + 32768);                                                    \
  int cur = 0;                                                              \
  for (int ks = 0; ks < (NK) - 1; ++ks) {                                   \
    asm volatile("s_waitcnt vmcnt(8)" ::: "memory");                        \
    __builtin_amdgcn_s_barrier();                                           \
    __builtin_amdgcn_sched_barrier(0);                                      \
    tile_compute(lds + cur * 32768, lds + cur * 32768 + 16384, acc, wr, wc, lane); \
    __builtin_amdgcn_sched_barrier(0);                                      \
    __builtin_amdgcn_s_barrier();                                           \
    __builtin_amdgcn_sched_barrier(0);                                      \
    if (ks + 2 < (NK)) stage(ks + 2, lds + cur * 32768);                    \
    cur ^= 1;                                                               \
  }                                                                         \
  asm volatile("s_waitcnt vmcnt(0)" ::: "memory");                          \
  __builtin_amdgcn_s_barrier();                                             \
  __builtin_amdgcn_sched_barrier(0);                                        \
  tile_compute(lds + cur * 32768, lds + cur * 32768 + 16384, acc, wr, wc, lane);

template<typename OutT, bool RELU>
__device__ __forceinline__ void store_tile(OutT* __restrict__ C, int m0, int c0,
                                           f32x4 (&acc)[4][4], int lane) {
  const int rbase = (lane >> 4) << 2;
  const int cl = lane & 15;
  #pragma unroll
  for (int i = 0; i < 4; ++i)
    #pragma unroll
    for (int j = 0; j < 4; ++j)
      #pragma unroll
      for (int r = 0; r < 4; ++r) {
        float v = acc[i][j][r];
        if (RELU) v = fmaxf(v, 0.f);
        C[(size_t)(m0 + i * 16 + rbase + r) * 512 + (c0 + j * 16 + cl)] = (OutT)v;
      }
}

// ---------------------------------------------------------------------------
// G1: 1x1 reduce conv + ReLU. A = interact^T bf16 [m][2304], B = wrb [512][2304].
// by (N-tile) is the fast swizzle dim for A-tile L2 reuse.
// ---------------------------------------------------------------------------
__global__ __launch_bounds__(256)
void k_gemm_reduce(const bf16* __restrict__ A, const bf16* __restrict__ B,
                   bf16* __restrict__ f1, int mbase)
{
  __shared__ __attribute__((aligned(16))) char lds[65536];
  const int s = xcd_swz(blockIdx.x, gridDim.x);
  const int by = s & 3, bx = s >> 2;
  const int t = threadIdx.x, lane = t & 63, w = t >> 6, wr = w >> 1, wc = w & 1;
  const int tr = t >> 3;
  const int cphys = ((t & 7) << 4) ^ ((tr & 7) << 4);
  const char* pa[4]; const char* pb[4];
  #pragma unroll
  for (int i = 0; i < 4; ++i) {
    int r = i * 32 + tr;
    pa[i] = (const char*)A + (size_t)(bx * 128 + r) * 4608 + cphys;
    pb[i] = (const char*)B + (size_t)(by * 128 + r) * 4608 + cphys;
  }
  const int lo = t * 16;
  auto stage = [&](int ks, char* base) {
    #pragma unroll
    for (int i = 0; i < 4; ++i) GLDS16(pa[i] + ks * 128, base + lo + i * 4096);
    #pragma unroll
    for (int i = 0; i < 4; ++i) GLDS16(pb[i] + ks * 128, base + 16384 + lo + i * 4096);
  };
  f32x4 acc[4][4] = {};
  PIPELINE_LOOP(36)
  store_tile<bf16, true>(f1, mbase + bx * 128 + wr * 64, by * 128 + wc * 64, acc, lane);
}

// ---------------------------------------------------------------------------
// G2: 3x3 VALID conv (16x16 -> 14x14). f1 NHWC bf16 -> f14 NHWC bf16.
// ---------------------------------------------------------------------------
__global__ __launch_bounds__(256)
void k_conv_rsize(const bf16* __restrict__ f1, const bf16* __restrict__ wt,
                  bf16* __restrict__ f14)
{
  __shared__ __attribute__((aligned(16))) char lds[65536];
  const int s = xcd_swz(blockIdx.x, gridDim.x);
  const int by = s & 3, bx = s >> 2;
  const int t = threadIdx.x, lane = t & 63, w = t >> 6, wr = w >> 1, wc = w & 1;
  const int tr = t >> 3;
  const int cphys = ((t & 7) << 4) ^ ((tr & 7) << 4);
  int abase[4]; const char* pb[4];
  #pragma unroll
  for (int i = 0; i < 4; ++i) {
    int r = i * 32 + tr;
    int m = bx * 128 + r;
    int n = m / 196, rem = m - n * 196;
    int y = rem / 14, x = rem - 14 * (rem / 14);
    abase[i] = n * 256 + y * 16 + x;
    pb[i] = (const char*)wt + (size_t)(by * 128 + r) * 1024 + cphys;
  }
  const char* f1c = (const char*)f1 + cphys;
  const int lo = t * 16;
  auto stage = [&](int ks, char* base) {
    int tap = ks >> 3, ko = (ks & 7) << 7;
    int dy = (tap * 11) >> 5, dx = tap - dy * 3;
    int doff = dy * 16 + dx;
    #pragma unroll
    for (int i = 0; i < 4; ++i)
      GLDS16(f1c + ((size_t)(abase[i] + doff) << 10) + ko, base + lo + i * 4096);
    #pragma unroll
    for (int i = 0; i < 4; ++i)
      GLDS16(pb[i] + (size_t)tap * 524288 + ko, base + 16384 + lo + i * 4096);
  };
  f32x4 acc[4][4] = {};
  PIPELINE_LOOP(72)
  store_tile<bf16, false>(f14, bx * 128 + wr * 64, by * 128 + wc * 64, acc, lane);
}

// ---------------------------------------------------------------------------
// G4: merged q/k/v 3x3 SAME conv on 7x7 (blocks 0..587) + obm mean (blocks
// 588..2635, overlapping bbox HBM reads with qkv compute).
// ---------------------------------------------------------------------------
__global__ __launch_bounds__(256)
void k_conv_qkv(const bf16* __restrict__ fin, const bf16* __restrict__ wt,
                bf16* __restrict__ qkv, const bf16* __restrict__ zp,
                const float* __restrict__ bbox, float* __restrict__ obm)
{
  __shared__ __attribute__((aligned(16))) char lds[65536];
  const int t = threadIdx.x;
  if (blockIdx.x >= 588) {
    // obm: mean of bbox over 196; 4 lanes per channel, coalesced float4
    int bid = blockIdx.x - 588;
    int n = bid >> 4;
    int c = (bid & 15) * 64 + (t >> 2);
    int seg = t & 3;
    const float4* p4 = (const float4*)(bbox + ((size_t)n * 1024 + c) * 196);
    float s = 0.f;
    for (int k = seg; k < 49; k += 4) { float4 w = p4[k]; s += w.x + w.y + w.z + w.w; }
    s += __shfl_xor(s, 1);
    s += __shfl_xor(s, 2);
    if (seg == 0) obm[n * 1024 + c] = s * (1.f / 196.f);
    return;
  }
  const int s = xcd_swz(blockIdx.x, 588);
  const int q12 = s % 12, bx = s / 12;
  const int tensor = q12 >> 2, by = q12 & 3;
  const char* wtc = (const char*)wt + (size_t)tensor * 4718592;
  bf16* outp = qkv + (size_t)tensor * 3211264;
  const int lane = t & 63, w = t >> 6, wr = w >> 1, wc = w & 1;
  const int tr = t >> 3;
  const int cphys = ((t & 7) << 4) ^ ((tr & 7) << 4);
  int nb[4], py[4], px[4]; const char* pb[4];
  #pragma unroll
  for (int i = 0; i < 4; ++i) {
    int r = i * 32 + tr;
    int m = bx * 128 + r;
    int n = m / 49, rem = m - n * 49;
    nb[i] = n * 49;
    py[i] = rem / 7 - 1;
    px[i] = rem - 7 * (rem / 7) - 1;
    pb[i] = wtc + (size_t)(by * 128 + r) * 1024 + cphys;
  }
  const char* finc = (const char*)fin + cphys;
  const char* zpc = (const char*)zp;
  const int lo = t * 16;
  auto stage = [&](int ks, char* base) {
    int tap = ks >> 3, ko = (ks & 7) << 7;
    int dy = (tap * 11) >> 5, dx = tap - dy * 3;
    #pragma unroll
    for (int i = 0; i < 4; ++i) {
      int iy = py[i] + dy, ix = px[i] + dx;
      const char* src = ((unsigned)iy < 7u && (unsigned)ix < 7u)
          ? finc + ((size_t)(nb[i] + iy * 7 + ix) << 10) + ko : zpc;
      GLDS16(src, base + lo + i * 4096);
    }
    #pragma unroll
    for (int i = 0; i < 4; ++i)
      GLDS16(pb[i] + (size_t)tap * 524288 + ko, base + 16384 + lo + i * 4096);
  };
  f32x4 acc[4][4] = {};
  PIPELINE_LOOP(72)
  store_tile<bf16, false>(outp, bx * 128 + wr * 64, by * 128 + wc * 64, acc, lane);
}

// ---------------------------------------------------------------------------
// G6: w1-conv+ho-mean GEMM, K-split: part[ks] = A_s[:,ksK] @ w1r[:,ksK]^T.
// grid (4 by, 4 ks), 18 K-steps each.
// ---------------------------------------------------------------------------
__global__ __launch_bounds__(256)
void k_gemm_s(const bf16* __restrict__ A_s, const bf16* __restrict__ w1r,
              float* __restrict__ part)
{
  __shared__ __attribute__((aligned(16))) char lds[65536];
  const int by = blockIdx.x, kspl = blockIdx.y;
  const int t = threadIdx.x, lane = t & 63, w = t >> 6, wr = w >> 1, wc = w & 1;
  const int tr = t >> 3;
  const int cphys = ((t & 7) << 4) ^ ((tr & 7) << 4);
  const char* pa[4]; const char* pb[4];
  #pragma unroll
  for (int i = 0; i < 4; ++i) {
    int r = i * 32 + tr;
    pa[i] = (const char*)A_s + (size_t)r * 9216 + kspl * 2304 + cphys;
    pb[i] = (const char*)w1r + (size_t)(by * 128 + r) * 9216 + kspl * 2304 + cphys;
  }
  const int lo = t * 16;
  auto stage = [&](int ks, char* base) {
    #pragma unroll
    for (int i = 0; i < 4; ++i) GLDS16(pa[i] + ks * 128, base + lo + i * 4096);
    #pragma unroll
    for (int i = 0; i < 4; ++i) GLDS16(pb[i] + ks * 128, base + 16384 + lo + i * 4096);
  };
  f32x4 acc[4][4] = {};
  PIPELINE_LOOP(18)
  const int rb = (lane >> 4) << 2, cl = lane & 15;
  #pragma unroll
  for (int i = 0; i < 4; ++i)
    #pragma unroll
    for (int j = 0; j < 4; ++j)
      #pragma unroll
      for (int r = 0; r < 4; ++r) {
        int row = wr * 64 + i * 16 + rb + r;
        int col = by * 128 + wc * 64 + j * 16 + cl;
        part[(size_t)kspl * 65536 + row * 512 + col] = acc[i][j][r];
      }
}

// K-split reduce + f7m add -> out[:, :512]
__global__ __launch_bounds__(512)
void k_red(const float* __restrict__ part, const float* __restrict__ f7m,
           float* __restrict__ out)
{
  int idx = blockIdx.x * 512 + threadIdx.x;   // 65536
  float s = part[idx] + part[65536 + idx] + part[131072 + idx] + part[196608 + idx];
  int row = idx >> 9, col = idx & 511;
  out[row * 1024 + col] = s + f7m[idx];
}

// ---------------------------------------------------------------------------
// P0: transpose+cast interact (n,2304,256) f32 -> A1 bf16 [(nl*256+p)][2304].
// ---------------------------------------------------------------------------
__global__ void k_tin(const float* __restrict__ in, bf16* __restrict__ A1, int n0)
{
  __shared__ float tile[64][36];
  const int k0 = blockIdx.x * 64, p0 = blockIdx.y * 32, nl = blockIdx.z;
  const int n = n0 + nl;
  const int t = threadIdx.x;
  const float* src = in + (size_t)n * 2304 * 256;
  #pragma unroll
  for (int rep = 0; rep < 2; ++rep) {
    int idx = t + rep * 256;          // 0..511 -> (row, c4)
    int row = idx >> 3, c4 = (idx & 7) * 4;
    float4 v = *(const float4*)(src + (size_t)(k0 + row) * 256 + p0 + c4);
    tile[row][c4] = v.x; tile[row][c4 + 1] = v.y;
    tile[row][c4 + 2] = v.z; tile[row][c4 + 3] = v.w;
  }
  __syncthreads();
  const int pl = t >> 3, ke = (t & 7) * 8;
  v8bf o;
  #pragma unroll
  for (int e = 0; e < 8; ++e) o[e] = (bf16)tile[ke + e][pl];
  bf16* dst = A1 + (size_t)nl * 256 * 2304;
  *(v8bf*)(dst + (size_t)(p0 + pl) * 2304 + k0 + ke) = o;
}

// P1: cast w_reduce f32 -> bf16
__global__ void k_castw(const float* __restrict__ wsrc, bf16* __restrict__ wb, int nelem)
{
  int idx = (blockIdx.x * 256 + threadIdx.x) * 4;
  if (idx >= nelem) return;
  float4 v = *(const float4*)(wsrc + idx);
  bf16 o0 = (bf16)v.x, o1 = (bf16)v.y, o2 = (bf16)v.z, o3 = (bf16)v.w;
  bf16* d = wb + idx;
  d[0] = o0; d[1] = o1; d[2] = o2; d[3] = o3;
}

// P2: (co,ci,3,3) f32 -> wt [tensor<4][tap][co][ci] bf16; w1 -> w1r [co][tap][ci]
__global__ void k_wtrans(const float* __restrict__ s0, const float* __restrict__ s1,
                         const float* __restrict__ s2, const float* __restrict__ s3,
                         const float* __restrict__ s4, bf16* __restrict__ wt,
                         bf16* __restrict__ w1r)
{
  const float* src;
  switch (blockIdx.y) {
    case 0: src = s0; break; case 1: src = s1; break; case 2: src = s2; break;
    case 3: src = s3; break; default: src = s4; break;
  }
  int q = blockIdx.x * 256 + threadIdx.x;   // co*512+ci
  const float* sp = src + (size_t)q * 9;
  float tmp[9];
  #pragma unroll
  for (int e = 0; e < 9; ++e) tmp[e] = sp[e];
  if (blockIdx.y < 4) {
    bf16* dst = wt + (size_t)blockIdx.y * 2359296;
    #pragma unroll
    for (int e = 0; e < 9; ++e) dst[(size_t)e * 262144 + q] = (bf16)tmp[e];
  } else {
    int co = q >> 9, ci = q & 511;
    #pragma unroll
    for (int e = 0; e < 9; ++e) w1r[(size_t)(co * 9 + e) * 512 + ci] = (bf16)tmp[e];
  }
}

// K3: maxpool 3x3 s2 p1, 14x14 -> 7x7, bf16, 2 channels/thread
__global__ void k_pool(const bf16* __restrict__ f14, bf16* __restrict__ f7b)
{
  int idx = blockIdx.x * 256 + threadIdx.x;   // 128*49*256
  int c2 = idx & 255;
  int pp = idx >> 8;
  int n = pp / 49, p7 = pp - n * 49;
  int y = p7 / 7, x = p7 - 7 * (p7 / 7);
  int y0 = 2 * y - 1, x0 = 2 * x - 1;
  const unsigned* f14u = (const unsigned*)f14;
  float m0 = -3.4e38f, m1 = -3.4e38f;
  #pragma unroll
  for (int dy = 0; dy < 3; ++dy) {
    int iy = y0 + dy; if ((unsigned)iy >= 14u) continue;
    #pragma unroll
    for (int dx = 0; dx < 3; ++dx) {
      int ix = x0 + dx; if ((unsigned)ix >= 14u) continue;
      unsigned vv = f14u[(size_t)(n * 196 + iy * 14 + ix) * 256 + c2];
      m0 = fmaxf(m0, __builtin_bit_cast(float, vv << 16));
      m1 = fmaxf(m1, __builtin_bit_cast(float, vv & 0xffff0000u));
    }
  }
  bf16 b0 = (bf16)m0, b1 = (bf16)m1;
  unsigned pk = (unsigned)__builtin_bit_cast(unsigned short, b0)
              | ((unsigned)__builtin_bit_cast(unsigned short, b1) << 16);
  ((unsigned*)f7b)[idx] = pk;
}

// K5: group attention (8x8 within group, mask from rois)
__global__ __launch_bounds__(256)
void k_attn(const bf16* __restrict__ q, const bf16* __restrict__ k,
            const bf16* __restrict__ v, const float* __restrict__ rois,
            float* __restrict__ virt)
{
  const int p = blockIdx.x, g = blockIdx.y, t = threadIdx.x;
  __shared__ float sS[8][9];
  __shared__ float sP[8][9];
  __shared__ __attribute__((aligned(16))) bf16 sV[8][512];
  {
    int u = t;
    #pragma unroll
    for (int rep = 0; rep < 2; ++rep, u += 256) {
      int j = u >> 6, ch = u & 63;
      *(v8bf*)&sV[j][ch * 8] = *(const v8bf*)(v + ((size_t)(g * 8 + j) * 49 + p) * 512 + ch * 8);
    }
  }
  int pi = t >> 2, ls = t & 3;
  int i = pi >> 3, j = pi & 7;
  const bf16* qi = q + ((size_t)(g * 8 + i) * 49 + p) * 512;
  const bf16* kj = k + ((size_t)(g * 8 + j) * 49 + p) * 512;
  float s = 0.f;
  for (int ch = ls * 16; ch < ls * 16 + 16; ++ch) {
    v8bf a = *(const v8bf*)(qi + ch * 8);
    v8bf b = *(const v8bf*)(kj + ch * 8);
    #pragma unroll
    for (int e = 0; e < 8; ++e) s += (float)a[e] * (float)b[e];
  }
  s += __shfl_xor(s, 1);
  s += __shfl_xor(s, 2);
  if (ls == 0) sS[i][j] = s * 0.04419417382415922f;
  __syncthreads();
  if (t < 8) {
    float gi = rois[(g * 8 + t) * 5];
    float pv[8]; float mx = -3.4e38f;
    #pragma unroll
    for (int jj = 0; jj < 8; ++jj) {
      float gj = rois[(g * 8 + jj) * 5];
      float sv = (gi == gj) ? sS[t][jj] : -1e30f;
      pv[jj] = sv; mx = fmaxf(mx, sv);
    }
    float sum = 0.f;
    #pragma unroll
    for (int jj = 0; jj < 8; ++jj) { float e = expf(pv[jj] - mx); pv[jj] = e; sum += e; }
    float inv = 1.f / sum;
    #pragma unroll
    for (int jj = 0; jj < 8; ++jj) sP[t][jj] = pv[jj] * inv;
  }
  __syncthreads();
  int i2 = t >> 5, c0 = (t & 31) * 16;
  float o[16];
  #pragma unroll
  for (int e = 0; e < 16; ++e) o[e] = 0.f;
  #pragma unroll
  for (int jj = 0; jj < 8; ++jj) {
    float ww = sP[i2][jj];
    v8bf v0 = *(const v8bf*)&sV[jj][c0];
    v8bf v1 = *(const v8bf*)&sV[jj][c0 + 8];
    #pragma unroll
    for (int e = 0; e < 8; ++e) { o[e] += ww * (float)v0[e]; o[8 + e] += ww * (float)v1[e]; }
  }
  float* dst = virt + ((size_t)(g * 8 + i2) * 49 + p) * 512 + c0;
  #pragma unroll
  for (int e = 0; e < 16; ++e) dst[e] = o[e];
}

// ---------------------------------------------------------------------------
// K6: fused LN(stats+apply)+windowed-sums (blocks 0..127, one n each, thread=
// channel, 49 values in regs; virtn never materialized) and fc (blocks
// 128..255, thread=output col).
// ---------------------------------------------------------------------------
__global__ __launch_bounds__(512)
void k_ln_fc(const float* __restrict__ virt, const float* __restrict__ gamma,
             const float* __restrict__ beta, const bf16* __restrict__ f7b,
             bf16* __restrict__ A_s, float* __restrict__ f7m,
             const float* __restrict__ obm, const float* __restrict__ wfc,
             float* __restrict__ out)
{
  const int t = threadIdx.x;
  if (blockIdx.x >= 128) {
    // fc + relu -> out[:, 512:1024]
    __shared__ float sO[1024];
    int n = blockIdx.x - 128;
    for (int u = t; u < 1024; u += 512) sO[u] = obm[n * 1024 + u];
    __syncthreads();
    const float4* wp = (const float4*)(wfc + (size_t)t * 1024);
    float s = 0.f;
    for (int c4 = 0; c4 < 256; ++c4) {
      float4 w = wp[c4];
      s += w.x * sO[c4 * 4] + w.y * sO[c4 * 4 + 1] + w.z * sO[c4 * 4 + 2] + w.w * sO[c4 * 4 + 3];
    }
    out[n * 1024 + 512 + t] = fmaxf(s, 0.f);
    return;
  }
  const int n = blockIdx.x;
  const float* p = virt + (size_t)n * 25088 + t;   // channel t, stride 512
  float xv[49];
  float s1 = 0.f, s2 = 0.f;
  #pragma unroll
  for (int pp = 0; pp < 49; ++pp) {
    float x = p[pp * 512];
    xv[pp] = x; s1 += x; s2 += x * x;
  }
  __shared__ float r1[512], r2[512];
  r1[t] = s1; r2[t] = s2; __syncthreads();
  for (int off = 256; off; off >>= 1) {
    if (t < off) { r1[t] += r1[t + off]; r2[t] += r2[t + off]; }
    __syncthreads();
  }
  float mu = r1[0] * (1.f / 25088.f);
  float var = r2[0] * (1.f / 25088.f) - mu * mu;
  float rstd = rsqrtf(var + 1e-5f);
  float g = gamma[t], be = beta[t];
  const bf16* fp = f7b + (size_t)n * 25088 + t;
  float T = 0, R0 = 0, R6 = 0, C0 = 0, C6 = 0;
  float X00 = 0, X06 = 0, X60 = 0, X66 = 0, F = 0;
  #pragma unroll
  for (int pp = 0; pp < 49; ++pp) {
    const int u = pp / 7, v = pp - 7 * (pp / 7);
    float y = fmaxf((xv[pp] - mu) * rstd * g + be, 0.f);
    T += y;
    if (u == 0) R0 += y;
    if (u == 6) R6 += y;
    if (v == 0) C0 += y;
    if (v == 6) C6 += y;
    if (pp == 0)  X00 = y;
    if (pp == 6)  X06 = y;
    if (pp == 42) X60 = y;
    if (pp == 48) X66 = y;
    F += (float)fp[pp * 512];
  }
  float sv[9] = { T-R6-C6+X66, T-R6, T-R6-C0+X60,
                  T-C6,        T,    T-C0,
                  T-R0-C6+X06, T-R0, T-R0-C0+X00 };
  bf16* Ap = A_s + (size_t)n * 4608 + t;
  #pragma unroll
  for (int tap = 0; tap < 9; ++tap)
    Ap[tap * 512] = (bf16)(sv[tap] * (1.f / 49.f));
  f7m[n * 512 + t] = F * (1.f / 49.f);
}

// ---------------------------------------------------------------------------
extern "C" void kernel_launch(void* const* d_in, const int* in_sizes, int n_in,
                              void* d_out, int out_size, void* d_ws, size_t ws_size,
                              hipStream_t stream) {
  const float* rois     = (const float*)d_in[0];
  const float* interact = (const float*)d_in[1];
  const float* bbox     = (const float*)d_in[2];
  const float* w_reduce = (const float*)d_in[3];
  const float* w_rsize  = (const float*)d_in[4];
  const float* wq       = (const float*)d_in[5];
  const float* wk       = (const float*)d_in[6];
  const float* wv       = (const float*)d_in[7];
  const float* w1       = (const float*)d_in[8];
  const float* gamma    = (const float*)d_in[9];
  const float* beta     = (const float*)d_in[10];
  const float* wfc      = (const float*)d_in[11];
  float* out = (float*)d_out;
  char* ws = (char*)d_ws;

  size_t o = 0;
  auto take = [&](size_t sz) { size_t r = o; o += (sz + 255) & ~(size_t)255; return r; };
  bf16*  wrb   = (bf16*)(ws + take(2359296));
  bf16*  wt    = (bf16*)(ws + take(18874368));   // [4][9][512][512] bf16 (rsize,q,k,v)
  bf16*  w1r   = (bf16*)(ws + take(4718592));    // [512 co][9 tap][512 ci] bf16
  char*  Rf1   = ws + take(33554432);            // f1 (33.6MB) -> later q,k,v (19.3MB)
  bf16*  f7b   = (bf16*)(ws + take(6422528));
  float* virt  = (float*)(ws + take(12845056));
  bf16*  A_s   = (bf16*)(ws + take(1179648));
  float* f7m   = (float*)(ws + take(262144));
  float* part  = (float*)(ws + take(1048576));   // [4 ks][128][512] f32
  float* obm   = (float*)(ws + take(524288));
  bf16*  zp    = (bf16*)(ws + take(256));
  size_t fixedEnd = o;
  const size_t A1_FULL = 150994944;
  bool full = (ws_size >= fixedEnd + A1_FULL);
  bf16* A1  = (bf16*)(ws + fixedEnd);
  bf16* f14 = (bf16*)(ws + fixedEnd);

  bf16* f1 = (bf16*)Rf1;
  bf16* qb = (bf16*)Rf1;
  bf16* kb = qb + 3211264;
  bf16* vb = kb + 3211264;

  hipMemsetAsync(zp, 0, 256, stream);

  k_castw<<<1152, 256, 0, stream>>>(w_reduce, wrb, 1179648);
  k_wtrans<<<dim3(1024, 5), 256, 0, stream>>>(w_rsize, wq, wk, wv, w1, wt, w1r);

  if (full) {
    k_tin<<<dim3(36, 8, 128), 256, 0, stream>>>(interact, A1, 0);
    k_gemm_reduce<<<1024, 256, 0, stream>>>(A1, wrb, f1, 0);
  } else {
    for (int ch = 0; ch < 4; ++ch) {
      k_tin<<<dim3(36, 8, 32), 256, 0, stream>>>(interact, A1, ch * 32);
      k_gemm_reduce<<<256, 256, 0, stream>>>(A1, wrb, f1, ch * 8192);
    }
  }

  k_conv_rsize<<<784, 256, 0, stream>>>(f1, wt, f14);
  k_pool<<<6272, 256, 0, stream>>>(f14, f7b);

  // qkv convs + obm (grid union; obm blocks overlap qkv compute)
  k_conv_qkv<<<2636, 256, 0, stream>>>(f7b, wt + (size_t)1 * 2359296, qb, zp, bbox, obm);

  k_attn<<<dim3(49, 16), 256, 0, stream>>>(qb, kb, vb, rois, virt);

  // fused LN + windowed sums + f7 mean (blocks 0-127) and fc head (128-255)
  k_ln_fc<<<256, 512, 0, stream>>>(virt, gamma, beta, f7b, A_s, f7m, obm, wfc, out);

  k_gemm_s<<<dim3(4, 4), 256, 0, stream>>>(A_s, w1r, part);
  k_red<<<128, 512, 0, stream>>>(part, f7m, out);
}

// Round 6
// 551.366 us; speedup vs baseline: 1.7256x; 1.0013x over previous
//
#include <hip/hip_runtime.h>
#include <hip/hip_bf16.h>
#include <math.h>

typedef __bf16 bf16;
typedef __bf16 v8bf __attribute__((ext_vector_type(8)));
typedef float f32x4 __attribute__((ext_vector_type(4)));

// async global->LDS, 16B per lane (per-thread LDS offset is t*16, lane-linear).
#define GLDS16(g, l) __builtin_amdgcn_global_load_lds( \
    (const __attribute__((address_space(1))) void*)(g), \
    (__attribute__((address_space(3))) void*)(l), 16, 0, 0)

// bijective XCD-chunk swizzle (m204 variant, works for any nwg)
__device__ __forceinline__ int xcd_swz(int bid, int nwg) {
  int xcd = bid & 7, off = bid >> 3;
  int q = nwg >> 3, r = nwg & 7;
  return (xcd < r ? xcd * (q + 1) : r * (q + 1) + (xcd - r) * q) + off;
}

// ===========================================================================
// 256x256 MFMA core, BK=32, 4-slot LDS ring (4 x 32KB), 512 thr = 8 waves
// (2M x 4N; per-wave output 128x64). Each ring slot: [A 16KB][B 16KB], each
// tile stored as [128 lds-rows][128 B] where row r packs global rows (r, r+128)
// side by side (64 B each); XOR swizzle: phys col = logical ^ ((row&7)<<4).
// Staging (gload_lds linear): thread t, issue j -> lds row j*64+(t>>3), phys
// slot (t&7)*16; global source logical col lb = ((t&7)<<4) ^ (((t>>3)&7)<<4);
// hi = lb>>6 selects the +128 row half, kb = lb&63 the k-byte.
// Pipeline: group g computes K-tile g from ring[g&3] in 2 phases (ih=0/1,
// 16 MFMA each), staging tile g+3 into ring[(g+3)&3] (2 issues/phase).
// vmcnt(8) once per group (tail: 4, then 0) -> ~2 groups of load flight.
// MFMA C/D: col=lane&15, row=4*(lane>>4)+reg.
// ===========================================================================
#define LDA256(ih) do { \
  _Pragma("unroll") for (int _i = 0; _i < 4; ++_i) { \
    int _r = (ih) * 64 + _i * 16 + l15; \
    int _c = (wm * 64 + colb) ^ ((l15 & 7) << 4); \
    af[_i] = *(const v8bf*)(ringp + _r * 128 + _c); } } while (0)

#define LDB256() do { \
  _Pragma("unroll") for (int _j = 0; _j < 4; ++_j) { \
    int _r = (wn & 1) * 64 + _j * 16 + l15; \
    int _c = ((wn >> 1) * 64 + colb) ^ ((l15 & 7) << 4); \
    bfr[_j] = *(const v8bf*)(ringp + 16384 + _r * 128 + _c); } } while (0)

#define MMA256(ih) do { \
  __builtin_amdgcn_s_setprio(1); \
  _Pragma("unroll") for (int _i = 0; _i < 4; ++_i) \
  _Pragma("unroll") for (int _j = 0; _j < 4; ++_j) \
    acc[(ih)*4+_i][_j] = __builtin_amdgcn_mfma_f32_16x16x32_bf16(af[_i], bfr[_j], acc[(ih)*4+_i][_j], 0, 0, 0); \
  __builtin_amdgcn_s_setprio(0); } while (0)

#define GROUP256(g, NT, STAGEA, STAGEB) do { \
  const char* ringp = lds + ((g) & 3) * 32768; \
  char* srng = lds + (((g) + 3) & 3) * 32768; \
  (void)srng; \
  const bool _st = ((g) + 3 < (NT)); \
  LDA256(0); LDB256(); \
  if (_st) { STAGEA; } \
  __builtin_amdgcn_s_barrier(); \
  __builtin_amdgcn_sched_barrier(0); \
  MMA256(0); \
  __builtin_amdgcn_sched_barrier(0); \
  __builtin_amdgcn_s_barrier(); \
  LDA256(1); \
  if (_st) { STAGEB; } \
  if (_st)                       asm volatile("s_waitcnt vmcnt(8)" ::: "memory"); \
  else if ((g) + 3 == (NT))      asm volatile("s_waitcnt vmcnt(4)" ::: "memory"); \
  else if ((g) + 3 == (NT) + 1)  asm volatile("s_waitcnt vmcnt(0)" ::: "memory"); \
  __builtin_amdgcn_s_barrier(); \
  __builtin_amdgcn_sched_barrier(0); \
  MMA256(1); \
  __builtin_amdgcn_sched_barrier(0); \
  __builtin_amdgcn_s_barrier(); } while (0)

// ---------------------------------------------------------------------------
// G1: 1x1 reduce conv + ReLU. A = interact^T bf16 [m][2304], B = wrb [512][2304].
// Grid: nbx*2 blocks (by fast for A L2 reuse). K-tiles: 72.
// ---------------------------------------------------------------------------
__global__ __launch_bounds__(512, 2)
void k_gemm_reduce(const bf16* __restrict__ A, const bf16* __restrict__ B,
                   bf16* __restrict__ f1, int mbase)
{
  __shared__ __attribute__((aligned(16))) char lds[131072];
  const int s = xcd_swz(blockIdx.x, gridDim.x);
  const int by = s & 1, bx = s >> 1;
  const int t = threadIdx.x, lane = t & 63, w = t >> 6;
  const int wm = w >> 2, wn = w & 3;
  const int l15 = lane & 15, colb = (lane >> 4) << 4;
  const int tr = t >> 3;
  const int lb = ((t & 7) << 4) ^ ((tr & 7) << 4);
  const int hi = lb >> 6, kb = lb & 63;
  const int t16 = t * 16;
  const char* pa[2]; const char* pb[2];
  #pragma unroll
  for (int j = 0; j < 2; ++j) {
    pa[j] = (const char*)A + (size_t)(bx * 256 + j * 64 + tr + hi * 128) * 4608 + kb;
    pb[j] = (const char*)B + (size_t)(by * 256 + j * 64 + tr + hi * 128) * 4608 + kb;
  }
  #define SA_GR(kt, ring) do { GLDS16(pa[0]+(size_t)(kt)*64, (ring)+t16); \
                               GLDS16(pa[1]+(size_t)(kt)*64, (ring)+8192+t16); } while (0)
  #define SB_GR(kt, ring) do { GLDS16(pb[0]+(size_t)(kt)*64, (ring)+16384+t16); \
                               GLDS16(pb[1]+(size_t)(kt)*64, (ring)+24576+t16); } while (0)
  f32x4 acc[8][4] = {};
  v8bf af[4], bfr[4];
  SA_GR(0, lds);         SB_GR(0, lds);
  SA_GR(1, lds + 32768); SB_GR(1, lds + 32768);
  SA_GR(2, lds + 65536); SB_GR(2, lds + 65536);
  asm volatile("s_waitcnt vmcnt(8)" ::: "memory");
  __builtin_amdgcn_s_barrier();
  for (int g = 0; g < 72; ++g) {
    GROUP256(g, 72, SA_GR(g + 3, srng), SB_GR(g + 3, srng));
  }
  const int rbase = (lane >> 4) << 2, cl = lane & 15;
  #pragma unroll
  for (int i = 0; i < 8; ++i)
    #pragma unroll
    for (int j = 0; j < 4; ++j)
      #pragma unroll
      for (int r = 0; r < 4; ++r) {
        int row = mbase + bx * 256 + wm * 128 + i * 16 + rbase + r;
        int col = by * 256 + wn * 64 + j * 16 + cl;
        f1[(size_t)row * 512 + col] = (bf16)fmaxf(acc[i][j][r], 0.f);
      }
}

// ---------------------------------------------------------------------------
// G2: 3x3 VALID conv (16x16 -> 14x14). f1 NHWC bf16 -> f14 NHWC bf16.
// M=25088 (98 bx) x N=512 (2 by) = 196 blocks. K-tiles: 144 (9 taps x 16).
// ---------------------------------------------------------------------------
__global__ __launch_bounds__(512, 2)
void k_conv_rsize(const bf16* __restrict__ f1, const bf16* __restrict__ wt,
                  bf16* __restrict__ f14)
{
  __shared__ __attribute__((aligned(16))) char lds[131072];
  const int s = xcd_swz(blockIdx.x, gridDim.x);
  const int by = s & 1, bx = s >> 1;
  const int t = threadIdx.x, lane = t & 63, w = t >> 6;
  const int wm = w >> 2, wn = w & 3;
  const int l15 = lane & 15, colb = (lane >> 4) << 4;
  const int tr = t >> 3;
  const int lb = ((t & 7) << 4) ^ ((tr & 7) << 4);
  const int hi = lb >> 6, kb = lb & 63;
  const int t16 = t * 16;
  int abase[2]; const char* pb[2];
  #pragma unroll
  for (int j = 0; j < 2; ++j) {
    int m = bx * 256 + j * 64 + tr + hi * 128;
    int n = m / 196, rem = m - n * 196;
    int y = rem / 14, x = rem - 14 * (rem / 14);
    abase[j] = n * 256 + y * 16 + x;
    pb[j] = (const char*)wt + (size_t)(by * 256 + j * 64 + tr + hi * 128) * 1024 + kb;
  }
  const char* f1c = (const char*)f1 + kb;
  #define SA_CR(kt, ring) do { int _tap = (kt) >> 4, _ko = ((kt) & 15) << 6; \
    int _dy = (_tap * 11) >> 5, _dx = _tap - _dy * 3; int _df = _dy * 16 + _dx; \
    GLDS16(f1c + (size_t)(abase[0] + _df) * 1024 + _ko, (ring)+t16); \
    GLDS16(f1c + (size_t)(abase[1] + _df) * 1024 + _ko, (ring)+8192+t16); } while (0)
  #define SB_CR(kt, ring) do { int _tap = (kt) >> 4, _ko = ((kt) & 15) << 6; \
    GLDS16(pb[0] + (size_t)_tap * 524288 + _ko, (ring)+16384+t16); \
    GLDS16(pb[1] + (size_t)_tap * 524288 + _ko, (ring)+24576+t16); } while (0)
  f32x4 acc[8][4] = {};
  v8bf af[4], bfr[4];
  SA_CR(0, lds);         SB_CR(0, lds);
  SA_CR(1, lds + 32768); SB_CR(1, lds + 32768);
  SA_CR(2, lds + 65536); SB_CR(2, lds + 65536);
  asm volatile("s_waitcnt vmcnt(8)" ::: "memory");
  __builtin_amdgcn_s_barrier();
  for (int g = 0; g < 144; ++g) {
    GROUP256(g, 144, SA_CR(g + 3, srng), SB_CR(g + 3, srng));
  }
  const int rbase = (lane >> 4) << 2, cl = lane & 15;
  #pragma unroll
  for (int i = 0; i < 8; ++i)
    #pragma unroll
    for (int j = 0; j < 4; ++j)
      #pragma unroll
      for (int r = 0; r < 4; ++r) {
        int row = bx * 256 + wm * 128 + i * 16 + rbase + r;
        int col = by * 256 + wn * 64 + j * 16 + cl;
        f14[(size_t)row * 512 + col] = (bf16)acc[i][j][r];
      }
}

// ---------------------------------------------------------------------------
// G4: fused q/k/v 3x3 SAME conv on 7x7, N=1536 (3 tensors x 512), M=6272
// (25 bx, masked tail). Blocks 0..149 conv; 150..1173 = obm mean (overlaps
// bbox HBM reads with qkv compute). K-tiles: 144.
// ---------------------------------------------------------------------------
__global__ __launch_bounds__(512, 2)
void k_conv_qkv(const bf16* __restrict__ fin, const bf16* __restrict__ wt,
                bf16* __restrict__ qkv, const bf16* __restrict__ zp,
                const float* __restrict__ bbox, float* __restrict__ obm)
{
  __shared__ __attribute__((aligned(16))) char lds[131072];
  const int t = threadIdx.x;
  if (blockIdx.x >= 150) {
    int bid = blockIdx.x - 150;           // 1024 blocks: 128 n x 8 cgroups
    int n = bid >> 3;
    int c = (bid & 7) * 128 + (t >> 2);
    int seg = t & 3;
    const float4* p4 = (const float4*)(bbox + ((size_t)n * 1024 + c) * 196);
    float sum = 0.f;
    for (int k = seg; k < 49; k += 4) { float4 ww = p4[k]; sum += ww.x + ww.y + ww.z + ww.w; }
    sum += __shfl_xor(sum, 1);
    sum += __shfl_xor(sum, 2);
    if (seg == 0) obm[n * 1024 + c] = sum * (1.f / 196.f);
    return;
  }
  const int s = xcd_swz(blockIdx.x, 150);
  const int q6 = s % 6, bx = s / 6;
  const int tensor = q6 >> 1, byl = q6 & 1;
  const char* wtc = (const char*)wt + (size_t)tensor * 4718592;
  bf16* outp = qkv + (size_t)tensor * 3211264;
  const int lane = t & 63, w = t >> 6;
  const int wm = w >> 2, wn = w & 3;
  const int l15 = lane & 15, colb = (lane >> 4) << 4;
  const int tr = t >> 3;
  const int lb = ((t & 7) << 4) ^ ((tr & 7) << 4);
  const int hi = lb >> 6, kb = lb & 63;
  const int t16 = t * 16;
  int nb[2], py[2], px[2]; const char* pb[2];
  #pragma unroll
  for (int j = 0; j < 2; ++j) {
    int m = bx * 256 + j * 64 + tr + hi * 128;
    if (m > 6271) m = 6271;
    int n = m / 49, rem = m - n * 49;
    nb[j] = n * 49;
    py[j] = rem / 7 - 1;
    px[j] = rem - 7 * (rem / 7) - 1;
    pb[j] = wtc + (size_t)(byl * 256 + j * 64 + tr + hi * 128) * 1024 + kb;
  }
  const char* finc = (const char*)fin + kb;
  const char* zpc = (const char*)zp;
  #define SA_QK(kt, ring) do { int _tap = (kt) >> 4, _ko = ((kt) & 15) << 6; \
    int _dy = (_tap * 11) >> 5, _dx = _tap - _dy * 3; \
    _Pragma("unroll") for (int _j = 0; _j < 2; ++_j) { \
      int _iy = py[_j] + _dy, _ix = px[_j] + _dx; \
      const char* _sp = ((unsigned)_iy < 7u && (unsigned)_ix < 7u) \
          ? finc + (size_t)(nb[_j] + _iy * 7 + _ix) * 1024 + _ko : zpc; \
      GLDS16(_sp, (ring) + _j * 8192 + t16); } } while (0)
  #define SB_QK(kt, ring) do { int _tap = (kt) >> 4, _ko = ((kt) & 15) << 6; \
    GLDS16(pb[0] + (size_t)_tap * 524288 + _ko, (ring)+16384+t16); \
    GLDS16(pb[1] + (size_t)_tap * 524288 + _ko, (ring)+24576+t16); } while (0)
  f32x4 acc[8][4] = {};
  v8bf af[4], bfr[4];
  SA_QK(0, lds);         SB_QK(0, lds);
  SA_QK(1, lds + 32768); SB_QK(1, lds + 32768);
  SA_QK(2, lds + 65536); SB_QK(2, lds + 65536);
  asm volatile("s_waitcnt vmcnt(8)" ::: "memory");
  __builtin_amdgcn_s_barrier();
  for (int g = 0; g < 144; ++g) {
    GROUP256(g, 144, SA_QK(g + 3, srng), SB_QK(g + 3, srng));
  }
  const int rbase = (lane >> 4) << 2, cl = lane & 15;
  #pragma unroll
  for (int i = 0; i < 8; ++i)
    #pragma unroll
    for (int j = 0; j < 4; ++j)
      #pragma unroll
      for (int r = 0; r < 4; ++r) {
        int row = bx * 256 + wm * 128 + i * 16 + rbase + r;
        if (row < 6272) {
          int col = byl * 256 + wn * 64 + j * 16 + cl;
          outp[(size_t)row * 512 + col] = (bf16)acc[i][j][r];
        }
      }
}

// ===========================================================================
// Old 128x128 core (kept for the tiny gemm_s)
// ===========================================================================
__device__ __forceinline__ void tile_compute(const char* ldsA, const char* ldsB,
                                             f32x4 (&acc)[4][4], int wr, int wc, int lane) {
  const int l15 = lane & 15;
  const int colb = (lane >> 4) << 4;
  #pragma unroll
  for (int kk = 0; kk < 2; ++kk) {
    v8bf a[4], b[4];
    #pragma unroll
    for (int i = 0; i < 4; ++i) {
      int ra = wr * 64 + i * 16 + l15;
      int ca = ((kk << 6) | colb) ^ ((ra & 7) << 4);
      a[i] = *(const v8bf*)(ldsA + ra * 128 + ca);
    }
    #pragma unroll
    for (int j = 0; j < 4; ++j) {
      int rb = wc * 64 + j * 16 + l15;
      int cb = ((kk << 6) | colb) ^ ((rb & 7) << 4);
      b[j] = *(const v8bf*)(ldsB + rb * 128 + cb);
    }
    __builtin_amdgcn_s_setprio(1);
    #pragma unroll
    for (int i = 0; i < 4; ++i)
      #pragma unroll
      for (int j = 0; j < 4; ++j)
        acc[i][j] = __builtin_amdgcn_mfma_f32_16x16x32_bf16(a[i], b[j], acc[i][j], 0, 0, 0);
    __builtin_amdgcn_s_setprio(0);
  }
}

#define PIPELINE_LOOP(NK)                                                   \
  stage(0, lds);                                                            \
  stage(1, lds + 32768);                                                    \
  int cur = 0;                                                              \
  for (int ks = 0; ks < (NK) - 1; ++ks) {                                   \
    asm volatile("s_waitcnt vmcnt(8)" ::: "memory");                        \
    __builtin_amdgcn_s_barrier();                                           \
    __builtin_amdgcn_sched_barrier(0);                                      \
    tile_compute(lds + cur * 32768, lds + cur * 32768 + 16384, acc, wr, wc, lane); \
    __builtin_amdgcn_sched_barrier(0);                                      \
    __builtin_amdgcn_s_barrier();                                           \
    __builtin_amdgcn_sched_barrier(0);                                      \
    if (ks + 2 < (NK)) stage(ks + 2, lds + cur * 32768);                    \
    cur ^= 1;                                                               \
  }                                                                         \
  asm volatile("s_waitcnt vmcnt(0)" ::: "memory");                          \
  __builtin_amdgcn_s_barrier();                                             \
  __builtin_amdgcn_sched_barrier(0);                                        \
  tile_compute(lds + cur * 32768, lds + cur * 32768 + 16384, acc, wr, wc, lane);

// G6: w1-conv+ho-mean GEMM, K-split: part[ks] = A_s[:,ksK] @ w1r[:,ksK]^T.
__global__ __launch_bounds__(256)
void k_gemm_s(const bf16* __restrict__ A_s, const bf16* __restrict__ w1r,
              float* __restrict__ part)
{
  __shared__ __attribute__((aligned(16))) char lds[65536];
  const int by = blockIdx.x, kspl = blockIdx.y;
  const int t = threadIdx.x, lane = t & 63, w = t >> 6, wr = w >> 1, wc = w & 1;
  const int tr = t >> 3;
  const int cphys = ((t & 7) << 4) ^ ((tr & 7) << 4);
  const char* pa[4]; const char* pb[4];
  #pragma unroll
  for (int i = 0; i < 4; ++i) {
    int r = i * 32 + tr;
    pa[i] = (const char*)A_s + (size_t)r * 9216 + kspl * 2304 + cphys;
    pb[i] = (const char*)w1r + (size_t)(by * 128 + r) * 9216 + kspl * 2304 + cphys;
  }
  const int lo = t * 16;
  auto stage = [&](int ks, char* base) {
    #pragma unroll
    for (int i = 0; i < 4; ++i) GLDS16(pa[i] + ks * 128, base + lo + i * 4096);
    #pragma unroll
    for (int i = 0; i < 4; ++i) GLDS16(pb[i] + ks * 128, base + 16384 + lo + i * 4096);
  };
  f32x4 acc[4][4] = {};
  PIPELINE_LOOP(18)
  const int rb = (lane >> 4) << 2, cl = lane & 15;
  #pragma unroll
  for (int i = 0; i < 4; ++i)
    #pragma unroll
    for (int j = 0; j < 4; ++j)
      #pragma unroll
      for (int r = 0; r < 4; ++r) {
        int row = wr * 64 + i * 16 + rb + r;
        int col = by * 128 + wc * 64 + j * 16 + cl;
        part[(size_t)kspl * 65536 + row * 512 + col] = acc[i][j][r];
      }
}

// K-split reduce + f7m add -> out[:, :512]
__global__ __launch_bounds__(512)
void k_red(const float* __restrict__ part, const float* __restrict__ f7m,
           float* __restrict__ out)
{
  int idx = blockIdx.x * 512 + threadIdx.x;   // 65536
  float s = part[idx] + part[65536 + idx] + part[131072 + idx] + part[196608 + idx];
  int row = idx >> 9, col = idx & 511;
  out[row * 1024 + col] = s + f7m[idx];
}

// P0: transpose+cast interact (n,2304,256) f32 -> A1 bf16 [(nl*256+p)][2304].
__global__ void k_tin(const float* __restrict__ in, bf16* __restrict__ A1, int n0)
{
  __shared__ float tile[64][36];
  const int k0 = blockIdx.x * 64, p0 = blockIdx.y * 32, nl = blockIdx.z;
  const int n = n0 + nl;
  const int t = threadIdx.x;
  const float* src = in + (size_t)n * 2304 * 256;
  #pragma unroll
  for (int rep = 0; rep < 2; ++rep) {
    int idx = t + rep * 256;
    int row = idx >> 3, c4 = (idx & 7) * 4;
    float4 v = *(const float4*)(src + (size_t)(k0 + row) * 256 + p0 + c4);
    tile[row][c4] = v.x; tile[row][c4 + 1] = v.y;
    tile[row][c4 + 2] = v.z; tile[row][c4 + 3] = v.w;
  }
  __syncthreads();
  const int pl = t >> 3, ke = (t & 7) * 8;
  v8bf o;
  #pragma unroll
  for (int e = 0; e < 8; ++e) o[e] = (bf16)tile[ke + e][pl];
  bf16* dst = A1 + (size_t)nl * 256 * 2304;
  *(v8bf*)(dst + (size_t)(p0 + pl) * 2304 + k0 + ke) = o;
}

// P1: cast w_reduce f32 -> bf16
__global__ void k_castw(const float* __restrict__ wsrc, bf16* __restrict__ wb, int nelem)
{
  int idx = (blockIdx.x * 256 + threadIdx.x) * 4;
  if (idx >= nelem) return;
  float4 v = *(const float4*)(wsrc + idx);
  bf16 o0 = (bf16)v.x, o1 = (bf16)v.y, o2 = (bf16)v.z, o3 = (bf16)v.w;
  bf16* d = wb + idx;
  d[0] = o0; d[1] = o1; d[2] = o2; d[3] = o3;
}

// P2: (co,ci,3,3) f32 -> wt [tensor<4][tap][co][ci] bf16; w1 -> w1r [co][tap][ci]
__global__ void k_wtrans(const float* __restrict__ s0, const float* __restrict__ s1,
                         const float* __restrict__ s2, const float* __restrict__ s3,
                         const float* __restrict__ s4, bf16* __restrict__ wt,
                         bf16* __restrict__ w1r)
{
  const float* src;
  switch (blockIdx.y) {
    case 0: src = s0; break; case 1: src = s1; break; case 2: src = s2; break;
    case 3: src = s3; break; default: src = s4; break;
  }
  int q = blockIdx.x * 256 + threadIdx.x;
  const float* sp = src + (size_t)q * 9;
  float tmp[9];
  #pragma unroll
  for (int e = 0; e < 9; ++e) tmp[e] = sp[e];
  if (blockIdx.y < 4) {
    bf16* dst = wt + (size_t)blockIdx.y * 2359296;
    #pragma unroll
    for (int e = 0; e < 9; ++e) dst[(size_t)e * 262144 + q] = (bf16)tmp[e];
  } else {
    int co = q >> 9, ci = q & 511;
    #pragma unroll
    for (int e = 0; e < 9; ++e) w1r[(size_t)(co * 9 + e) * 512 + ci] = (bf16)tmp[e];
  }
}

// K3: maxpool 3x3 s2 p1, 14x14 -> 7x7, bf16, 2 channels/thread
__global__ void k_pool(const bf16* __restrict__ f14, bf16* __restrict__ f7b)
{
  int idx = blockIdx.x * 256 + threadIdx.x;
  int c2 = idx & 255;
  int pp = idx >> 8;
  int n = pp / 49, p7 = pp - n * 49;
  int y = p7 / 7, x = p7 - 7 * (p7 / 7);
  int y0 = 2 * y - 1, x0 = 2 * x - 1;
  const unsigned* f14u = (const unsigned*)f14;
  float m0 = -3.4e38f, m1 = -3.4e38f;
  #pragma unroll
  for (int dy = 0; dy < 3; ++dy) {
    int iy = y0 + dy; if ((unsigned)iy >= 14u) continue;
    #pragma unroll
    for (int dx = 0; dx < 3; ++dx) {
      int ix = x0 + dx; if ((unsigned)ix >= 14u) continue;
      unsigned vv = f14u[(size_t)(n * 196 + iy * 14 + ix) * 256 + c2];
      m0 = fmaxf(m0, __builtin_bit_cast(float, vv << 16));
      m1 = fmaxf(m1, __builtin_bit_cast(float, vv & 0xffff0000u));
    }
  }
  bf16 b0 = (bf16)m0, b1 = (bf16)m1;
  unsigned pk = (unsigned)__builtin_bit_cast(unsigned short, b0)
              | ((unsigned)__builtin_bit_cast(unsigned short, b1) << 16);
  ((unsigned*)f7b)[idx] = pk;
}

// K5: group attention (8x8 within group, mask from rois)
__global__ __launch_bounds__(256)
void k_attn(const bf16* __restrict__ q, const bf16* __restrict__ k,
            const bf16* __restrict__ v, const float* __restrict__ rois,
            float* __restrict__ virt)
{
  const int p = blockIdx.x, g = blockIdx.y, t = threadIdx.x;
  __shared__ float sS[8][9];
  __shared__ float sP[8][9];
  __shared__ __attribute__((aligned(16))) bf16 sV[8][512];
  {
    int u = t;
    #pragma unroll
    for (int rep = 0; rep < 2; ++rep, u += 256) {
      int j = u >> 6, ch = u & 63;
      *(v8bf*)&sV[j][ch * 8] = *(const v8bf*)(v + ((size_t)(g * 8 + j) * 49 + p) * 512 + ch * 8);
    }
  }
  int pi = t >> 2, ls = t & 3;
  int i = pi >> 3, j = pi & 7;
  const bf16* qi = q + ((size_t)(g * 8 + i) * 49 + p) * 512;
  const bf16* kj = k + ((size_t)(g * 8 + j) * 49 + p) * 512;
  float s = 0.f;
  for (int ch = ls * 16; ch < ls * 16 + 16; ++ch) {
    v8bf a = *(const v8bf*)(qi + ch * 8);
    v8bf b = *(const v8bf*)(kj + ch * 8);
    #pragma unroll
    for (int e = 0; e < 8; ++e) s += (float)a[e] * (float)b[e];
  }
  s += __shfl_xor(s, 1);
  s += __shfl_xor(s, 2);
  if (ls == 0) sS[i][j] = s * 0.04419417382415922f;
  __syncthreads();
  if (t < 8) {
    float gi = rois[(g * 8 + t) * 5];
    float pv[8]; float mx = -3.4e38f;
    #pragma unroll
    for (int jj = 0; jj < 8; ++jj) {
      float gj = rois[(g * 8 + jj) * 5];
      float sv = (gi == gj) ? sS[t][jj] : -1e30f;
      pv[jj] = sv; mx = fmaxf(mx, sv);
    }
    float sum = 0.f;
    #pragma unroll
    for (int jj = 0; jj < 8; ++jj) { float e = expf(pv[jj] - mx); pv[jj] = e; sum += e; }
    float inv = 1.f / sum;
    #pragma unroll
    for (int jj = 0; jj < 8; ++jj) sP[t][jj] = pv[jj] * inv;
  }
  __syncthreads();
  int i2 = t >> 5, c0 = (t & 31) * 16;
  float o[16];
  #pragma unroll
  for (int e = 0; e < 16; ++e) o[e] = 0.f;
  #pragma unroll
  for (int jj = 0; jj < 8; ++jj) {
    float ww = sP[i2][jj];
    v8bf v0 = *(const v8bf*)&sV[jj][c0];
    v8bf v1 = *(const v8bf*)&sV[jj][c0 + 8];
    #pragma unroll
    for (int e = 0; e < 8; ++e) { o[e] += ww * (float)v0[e]; o[8 + e] += ww * (float)v1[e]; }
  }
  float* dst = virt + ((size_t)(g * 8 + i2) * 49 + p) * 512 + c0;
  #pragma unroll
  for (int e = 0; e < 16; ++e) dst[e] = o[e];
}

// K6: fused LN(stats+apply)+windowed-sums (blocks 0..127) and fc (128..255).
__global__ __launch_bounds__(512)
void k_ln_fc(const float* __restrict__ virt, const float* __restrict__ gamma,
             const float* __restrict__ beta, const bf16* __restrict__ f7b,
             bf16* __restrict__ A_s, float* __restrict__ f7m,
             const float* __restrict__ obm, const float* __restrict__ wfc,
             float* __restrict__ out)
{
  const int t = threadIdx.x;
  if (blockIdx.x >= 128) {
    __shared__ float sO[1024];
    int n = blockIdx.x - 128;
    for (int u = t; u < 1024; u += 512) sO[u] = obm[n * 1024 + u];
    __syncthreads();
    const float4* wp = (const float4*)(wfc + (size_t)t * 1024);
    float s = 0.f;
    for (int c4 = 0; c4 < 256; ++c4) {
      float4 w = wp[c4];
      s += w.x * sO[c4 * 4] + w.y * sO[c4 * 4 + 1] + w.z * sO[c4 * 4 + 2] + w.w * sO[c4 * 4 + 3];
    }
    out[n * 1024 + 512 + t] = fmaxf(s, 0.f);
    return;
  }
  const int n = blockIdx.x;
  const float* p = virt + (size_t)n * 25088 + t;
  float xv[49];
  float s1 = 0.f, s2 = 0.f;
  #pragma unroll
  for (int pp = 0; pp < 49; ++pp) {
    float x = p[pp * 512];
    xv[pp] = x; s1 += x; s2 += x * x;
  }
  __shared__ float r1[512], r2[512];
  r1[t] = s1; r2[t] = s2; __syncthreads();
  for (int off = 256; off; off >>= 1) {
    if (t < off) { r1[t] += r1[t + off]; r2[t] += r2[t + off]; }
    __syncthreads();
  }
  float mu = r1[0] * (1.f / 25088.f);
  float var = r2[0] * (1.f / 25088.f) - mu * mu;
  float rstd = rsqrtf(var + 1e-5f);
  float g = gamma[t], be = beta[t];
  const bf16* fp = f7b + (size_t)n * 25088 + t;
  float T = 0, R0 = 0, R6 = 0, C0 = 0, C6 = 0;
  float X00 = 0, X06 = 0, X60 = 0, X66 = 0, F = 0;
  #pragma unroll
  for (int pp = 0; pp < 49; ++pp) {
    const int u = pp / 7, v = pp - 7 * (pp / 7);
    float y = fmaxf((xv[pp] - mu) * rstd * g + be, 0.f);
    T += y;
    if (u == 0) R0 += y;
    if (u == 6) R6 += y;
    if (v == 0) C0 += y;
    if (v == 6) C6 += y;
    if (pp == 0)  X00 = y;
    if (pp == 6)  X06 = y;
    if (pp == 42) X60 = y;
    if (pp == 48) X66 = y;
    F += (float)fp[pp * 512];
  }
  float sv[9] = { T-R6-C6+X66, T-R6, T-R6-C0+X60,
                  T-C6,        T,    T-C0,
                  T-R0-C6+X06, T-R0, T-R0-C0+X00 };
  bf16* Ap = A_s + (size_t)n * 4608 + t;
  #pragma unroll
  for (int tap = 0; tap < 9; ++tap)
    Ap[tap * 512] = (bf16)(sv[tap] * (1.f / 49.f));
  f7m[n * 512 + t] = F * (1.f / 49.f);
}

// ---------------------------------------------------------------------------
extern "C" void kernel_launch(void* const* d_in, const int* in_sizes, int n_in,
                              void* d_out, int out_size, void* d_ws, size_t ws_size,
                              hipStream_t stream) {
  const float* rois     = (const float*)d_in[0];
  const float* interact = (const float*)d_in[1];
  const float* bbox     = (const float*)d_in[2];
  const float* w_reduce = (const float*)d_in[3];
  const float* w_rsize  = (const float*)d_in[4];
  const float* wq       = (const float*)d_in[5];
  const float* wk       = (const float*)d_in[6];
  const float* wv       = (const float*)d_in[7];
  const float* w1       = (const float*)d_in[8];
  const float* gamma    = (const float*)d_in[9];
  const float* beta     = (const float*)d_in[10];
  const float* wfc      = (const float*)d_in[11];
  float* out = (float*)d_out;
  char* ws = (char*)d_ws;

  size_t o = 0;
  auto take = [&](size_t sz) { size_t r = o; o += (sz + 255) & ~(size_t)255; return r; };
  bf16*  wrb   = (bf16*)(ws + take(2359296));
  bf16*  wt    = (bf16*)(ws + take(18874368));   // [4][9][512][512] bf16 (rsize,q,k,v)
  bf16*  w1r   = (bf16*)(ws + take(4718592));    // [512 co][9 tap][512 ci] bf16
  char*  Rf1   = ws + take(33554432);            // f1 (33.6MB) -> later q,k,v (19.3MB)
  bf16*  f7b   = (bf16*)(ws + take(6422528));
  float* virt  = (float*)(ws + take(12845056));
  bf16*  A_s   = (bf16*)(ws + take(1179648));
  float* f7m   = (float*)(ws + take(262144));
  float* part  = (float*)(ws + take(1048576));   // [4 ks][128][512] f32
  float* obm   = (float*)(ws + take(524288));
  bf16*  zp    = (bf16*)(ws + take(256));
  size_t fixedEnd = o;
  const size_t A1_FULL = 150994944;
  bool full = (ws_size >= fixedEnd + A1_FULL);
  bf16* A1  = (bf16*)(ws + fixedEnd);
  bf16* f14 = (bf16*)(ws + fixedEnd);

  bf16* f1 = (bf16*)Rf1;
  bf16* qb = (bf16*)Rf1;
  bf16* kb = qb + 3211264;
  bf16* vb = kb + 3211264;

  hipMemsetAsync(zp, 0, 256, stream);

  k_castw<<<1152, 256, 0, stream>>>(w_reduce, wrb, 1179648);
  k_wtrans<<<dim3(1024, 5), 256, 0, stream>>>(w_rsize, wq, wk, wv, w1, wt, w1r);

  if (full) {
    k_tin<<<dim3(36, 8, 128), 256, 0, stream>>>(interact, A1, 0);
    k_gemm_reduce<<<256, 512, 0, stream>>>(A1, wrb, f1, 0);
  } else {
    for (int ch = 0; ch < 4; ++ch) {
      k_tin<<<dim3(36, 8, 32), 256, 0, stream>>>(interact, A1, ch * 32);
      k_gemm_reduce<<<64, 512, 0, stream>>>(A1, wrb, f1, ch * 8192);
    }
  }

  k_conv_rsize<<<196, 512, 0, stream>>>(f1, wt, f14);
  k_pool<<<6272, 256, 0, stream>>>(f14, f7b);

  // fused qkv convs (blocks 0-149) + obm (150-1173)
  k_conv_qkv<<<1174, 512, 0, stream>>>(f7b, wt + (size_t)1 * 2359296, qb, zp, bbox, obm);

  k_attn<<<dim3(49, 16), 256, 0, stream>>>(qb, kb, vb, rois, virt);

  k_ln_fc<<<256, 512, 0, stream>>>(virt, gamma, beta, f7b, A_s, f7m, obm, wfc, out);

  k_gemm_s<<<dim3(4, 4), 256, 0, stream>>>(A_s, w1r, part);
  k_red<<<128, 512, 0, stream>>>(part, f7m, out);
}

// Round 7
// 543.020 us; speedup vs baseline: 1.7521x; 1.0154x over previous
//
#include <hip/hip_runtime.h>
#include <hip/hip_bf16.h>
#include <math.h>

typedef __bf16 bf16;
typedef __bf16 v8bf __attribute__((ext_vector_type(8)));
typedef float f32x4 __attribute__((ext_vector_type(4)));

// async global->LDS, 16B per lane (per-thread LDS offset is t*16, lane-linear).
#define GLDS16(g, l) __builtin_amdgcn_global_load_lds( \
    (const __attribute__((address_space(1))) void*)(g), \
    (__attribute__((address_space(3))) void*)(l), 16, 0, 0)

// bijective XCD-chunk swizzle (m204 variant, works for any nwg)
__device__ __forceinline__ int xcd_swz(int bid, int nwg) {
  int xcd = bid & 7, off = bid >> 3;
  int q = nwg >> 3, r = nwg & 7;
  return (xcd < r ? xcd * (q + 1) : r * (q + 1) + (xcd - r) * q) + off;
}

// ===========================================================================
// 256x128 MFMA core, BK=32, ring-3 LDS (3 x 24KB = 72KB -> 2 blocks/CU),
// 256 thr = 4 waves (2M x 2N), per-wave output 128x64 (8x4 fragments):
// 32 MFMA per 12 ds_read_b128 (B-frags reused across both M-halves).
// Slot: A 16KB = [128 lds-rows][128B], lds-row r packs global A-rows (r, r+128)
// (64B of k each); B 8KB = [64 rows][128B] packing B-rows (r, r+64).
// XOR swizzle: phys col = logical ^ ((row&7)<<4).
// Staging (linear gload_lds): thread t, issue i -> lds-row i*32+(t>>3), phys
// col (t&7)*16; logical lb = ((t&7)<<4)^(((t>>3)&7)<<4); hi=lb>>6 picks the
// packed row half (+128 A / +64 B), kb=lb&63 the k-byte. 6 gloads per group
// (4 A + 2 B). Pipeline: compute g from s0, stage g+2 into s2 (s2 = slot of
// g-1, all reads done before the end-of-(g-1) barrier), vmcnt(12) = stages
// g+1,g+2 in flight; tail vmcnt 6 -> 0. Barrier after vmcnt makes all waves'
// stage(g) landings visible. MFMA C/D: col=lane&15, row=4*(lane>>4)+reg.
// ===========================================================================
#define RING_COMPUTE() do { \
  v8bf b_[4], a_[4]; \
  _Pragma("unroll") for (int _j = 0; _j < 4; ++_j) { \
    int _lr = _j * 16 + l15; \
    int _c = (wn * 64 + colb) ^ ((_lr & 7) << 4); \
    b_[_j] = *(const v8bf*)(s0 + 16384 + _lr * 128 + _c); } \
  _Pragma("unroll") for (int _i = 0; _i < 4; ++_i) { \
    int _lr = _i * 16 + l15; \
    int _c = (wm * 64 + colb) ^ ((_lr & 7) << 4); \
    a_[_i] = *(const v8bf*)(s0 + _lr * 128 + _c); } \
  __builtin_amdgcn_s_setprio(1); \
  _Pragma("unroll") for (int _i = 0; _i < 4; ++_i) \
  _Pragma("unroll") for (int _j = 0; _j < 4; ++_j) \
    acc[_i][_j] = __builtin_amdgcn_mfma_f32_16x16x32_bf16(a_[_i], b_[_j], acc[_i][_j], 0, 0, 0); \
  __builtin_amdgcn_s_setprio(0); \
  _Pragma("unroll") for (int _i = 0; _i < 4; ++_i) { \
    int _lr = (_i + 4) * 16 + l15; \
    int _c = (wm * 64 + colb) ^ ((_lr & 7) << 4); \
    a_[_i] = *(const v8bf*)(s0 + _lr * 128 + _c); } \
  __builtin_amdgcn_s_setprio(1); \
  _Pragma("unroll") for (int _i = 0; _i < 4; ++_i) \
  _Pragma("unroll") for (int _j = 0; _j < 4; ++_j) \
    acc[_i + 4][_j] = __builtin_amdgcn_mfma_f32_16x16x32_bf16(a_[_i], b_[_j], acc[_i + 4][_j], 0, 0, 0); \
  __builtin_amdgcn_s_setprio(0); \
} while (0)

#define RING_LOOP(NG, STAGE) do { \
  STAGE(0, s0); STAGE(1, s1); \
  for (int g = 0; g < (NG); ++g) { \
    if (g + 2 < (NG)) { STAGE(g + 2, s2); } \
    if (g + 2 < (NG))       asm volatile("s_waitcnt vmcnt(12)" ::: "memory"); \
    else if (g + 2 == (NG)) asm volatile("s_waitcnt vmcnt(6)" ::: "memory"); \
    else                    asm volatile("s_waitcnt vmcnt(0)" ::: "memory"); \
    __builtin_amdgcn_s_barrier(); \
    __builtin_amdgcn_sched_barrier(0); \
    RING_COMPUTE(); \
    __builtin_amdgcn_sched_barrier(0); \
    __builtin_amdgcn_s_barrier(); \
    char* _tmp = s0; s0 = s1; s1 = s2; s2 = _tmp; \
  } \
} while (0)

// ---------------------------------------------------------------------------
// G1: 1x1 reduce conv + ReLU. A = interact^T bf16 [m][2304], B = wrb [512][2304].
// Grid: (M/256) x 4, by fast for A-tile L2 reuse. Groups: 2304/32 = 72.
// ---------------------------------------------------------------------------
__global__ __launch_bounds__(256, 2)
void k_gemm_reduce(const bf16* __restrict__ A, const bf16* __restrict__ B,
                   bf16* __restrict__ f1, int mbase)
{
  __shared__ __attribute__((aligned(16))) char lds[73728];
  char *s0 = lds, *s1 = lds + 24576, *s2 = lds + 49152;
  const int s = xcd_swz(blockIdx.x, gridDim.x);
  const int by = s & 3, bx = s >> 2;
  const int t = threadIdx.x, lane = t & 63, w = t >> 6;
  const int wm = w >> 1, wn = w & 1;
  const int l15 = lane & 15, colb = (lane >> 4) << 4;
  const int tr = t >> 3;
  const int lb = ((t & 7) << 4) ^ ((tr & 7) << 4);
  const int hi = lb >> 6, kb = lb & 63;
  const int t16 = t * 16;
  const char* pa[4]; const char* pb[2];
  #pragma unroll
  for (int i = 0; i < 4; ++i)
    pa[i] = (const char*)A + (size_t)(bx * 256 + i * 32 + tr + hi * 128) * 4608 + kb;
  #pragma unroll
  for (int i = 0; i < 2; ++i)
    pb[i] = (const char*)B + (size_t)(by * 128 + i * 32 + tr + hi * 64) * 4608 + kb;
  #define SG(kt, ring) do { \
    _Pragma("unroll") for (int _i = 0; _i < 4; ++_i) \
      GLDS16(pa[_i] + (size_t)(kt) * 64, (ring) + _i * 4096 + t16); \
    _Pragma("unroll") for (int _i = 0; _i < 2; ++_i) \
      GLDS16(pb[_i] + (size_t)(kt) * 64, (ring) + 16384 + _i * 4096 + t16); } while (0)
  f32x4 acc[8][4] = {};
  RING_LOOP(72, SG);
  const int rbase = (lane >> 4) << 2, cl = lane & 15;
  #pragma unroll
  for (int i = 0; i < 8; ++i)
    #pragma unroll
    for (int j = 0; j < 4; ++j)
      #pragma unroll
      for (int r = 0; r < 4; ++r) {
        int row = mbase + bx * 256 + wm * 128 + i * 16 + rbase + r;
        int col = by * 128 + wn * 64 + j * 16 + cl;
        f1[(size_t)row * 512 + col] = (bf16)fmaxf(acc[i][j][r], 0.f);
      }
}

// ---------------------------------------------------------------------------
// G2: 3x3 VALID conv (16x16 -> 14x14). f1 NHWC bf16 -> f14 NHWC bf16.
// M=25088 (98 bx) x 4 by = 392 blocks. Groups: 144 (9 taps x 16).
// ---------------------------------------------------------------------------
__global__ __launch_bounds__(256, 2)
void k_conv_rsize(const bf16* __restrict__ f1, const bf16* __restrict__ wt,
                  bf16* __restrict__ f14)
{
  __shared__ __attribute__((aligned(16))) char lds[73728];
  char *s0 = lds, *s1 = lds + 24576, *s2 = lds + 49152;
  const int s = xcd_swz(blockIdx.x, gridDim.x);
  const int by = s & 3, bx = s >> 2;
  const int t = threadIdx.x, lane = t & 63, w = t >> 6;
  const int wm = w >> 1, wn = w & 1;
  const int l15 = lane & 15, colb = (lane >> 4) << 4;
  const int tr = t >> 3;
  const int lb = ((t & 7) << 4) ^ ((tr & 7) << 4);
  const int hi = lb >> 6, kb = lb & 63;
  const int t16 = t * 16;
  int abase[4]; const char* pb[2];
  #pragma unroll
  for (int i = 0; i < 4; ++i) {
    int m = bx * 256 + i * 32 + tr + hi * 128;
    int n = m / 196, rem = m - n * 196;
    int y = rem / 14, x = rem - 14 * (rem / 14);
    abase[i] = n * 256 + y * 16 + x;
  }
  #pragma unroll
  for (int i = 0; i < 2; ++i)
    pb[i] = (const char*)wt + (size_t)(by * 128 + i * 32 + tr + hi * 64) * 1024 + kb;
  const char* f1c = (const char*)f1 + kb;
  #define SC(kt, ring) do { int _tap = (kt) >> 4, _ko = ((kt) & 15) << 6; \
    int _dy = (_tap * 11) >> 5, _dx = _tap - _dy * 3; \
    int _df = (_dy * 16 + _dx) << 10; \
    _Pragma("unroll") for (int _i = 0; _i < 4; ++_i) \
      GLDS16(f1c + ((size_t)abase[_i] << 10) + _df + _ko, (ring) + _i * 4096 + t16); \
    _Pragma("unroll") for (int _i = 0; _i < 2; ++_i) \
      GLDS16(pb[_i] + (size_t)_tap * 524288 + _ko, (ring) + 16384 + _i * 4096 + t16); } while (0)
  f32x4 acc[8][4] = {};
  RING_LOOP(144, SC);
  const int rbase = (lane >> 4) << 2, cl = lane & 15;
  #pragma unroll
  for (int i = 0; i < 8; ++i)
    #pragma unroll
    for (int j = 0; j < 4; ++j)
      #pragma unroll
      for (int r = 0; r < 4; ++r) {
        int row = bx * 256 + wm * 128 + i * 16 + rbase + r;
        int col = by * 128 + wn * 64 + j * 16 + cl;
        f14[(size_t)row * 512 + col] = (bf16)acc[i][j][r];
      }
}

// ---------------------------------------------------------------------------
// G4: fused q/k/v 3x3 SAME conv on 7x7. M=6272 (25 bx, masked tail) x
// 12 (tensor x by) = 300 conv blocks; blocks 300..2347 = obm mean (overlaps
// bbox HBM reads with qkv compute). Groups: 144.
// ---------------------------------------------------------------------------
__global__ __launch_bounds__(256, 2)
void k_conv_qkv(const bf16* __restrict__ fin, const bf16* __restrict__ wt,
                bf16* __restrict__ qkv, const bf16* __restrict__ zp,
                const float* __restrict__ bbox, float* __restrict__ obm)
{
  __shared__ __attribute__((aligned(16))) char lds[73728];
  char *s0 = lds, *s1 = lds + 24576, *s2 = lds + 49152;
  const int t = threadIdx.x;
  if (blockIdx.x >= 300) {
    int bid = blockIdx.x - 300;           // 2048 blocks: 128 n x 16 cgroups
    int n = bid >> 4;
    int c = (bid & 15) * 64 + (t >> 2);
    int seg = t & 3;
    const float4* p4 = (const float4*)(bbox + ((size_t)n * 1024 + c) * 196);
    float sum = 0.f;
    for (int k = seg; k < 49; k += 4) { float4 ww = p4[k]; sum += ww.x + ww.y + ww.z + ww.w; }
    sum += __shfl_xor(sum, 1);
    sum += __shfl_xor(sum, 2);
    if (seg == 0) obm[n * 1024 + c] = sum * (1.f / 196.f);
    return;
  }
  const int s = xcd_swz(blockIdx.x, 300);
  const int q12 = s % 12, bx = s / 12;
  const int tensor = q12 >> 2, byl = q12 & 3;
  const char* wtc = (const char*)wt + (size_t)tensor * 4718592;
  bf16* outp = qkv + (size_t)tensor * 3211264;
  const int lane = t & 63, w = t >> 6;
  const int wm = w >> 1, wn = w & 1;
  const int l15 = lane & 15, colb = (lane >> 4) << 4;
  const int tr = t >> 3;
  const int lb = ((t & 7) << 4) ^ ((tr & 7) << 4);
  const int hi = lb >> 6, kb = lb & 63;
  const int t16 = t * 16;
  int nb[4], py[4], px[4]; const char* pb[2];
  #pragma unroll
  for (int i = 0; i < 4; ++i) {
    int m = bx * 256 + i * 32 + tr + hi * 128;
    if (m > 6271) m = 6271;
    int n = m / 49, rem = m - n * 49;
    nb[i] = n * 49;
    py[i] = rem / 7 - 1;
    px[i] = rem - 7 * (rem / 7) - 1;
  }
  #pragma unroll
  for (int i = 0; i < 2; ++i)
    pb[i] = wtc + (size_t)(byl * 128 + i * 32 + tr + hi * 64) * 1024 + kb;
  const char* finc = (const char*)fin + kb;
  const char* zpc = (const char*)zp;
  #define SQ(kt, ring) do { int _tap = (kt) >> 4, _ko = ((kt) & 15) << 6; \
    int _dy = (_tap * 11) >> 5, _dx = _tap - _dy * 3; \
    _Pragma("unroll") for (int _i = 0; _i < 4; ++_i) { \
      int _iy = py[_i] + _dy, _ix = px[_i] + _dx; \
      const char* _sp = ((unsigned)_iy < 7u && (unsigned)_ix < 7u) \
          ? finc + (size_t)(nb[_i] + _iy * 7 + _ix) * 1024 + _ko : zpc; \
      GLDS16(_sp, (ring) + _i * 4096 + t16); } \
    _Pragma("unroll") for (int _i = 0; _i < 2; ++_i) \
      GLDS16(pb[_i] + (size_t)_tap * 524288 + _ko, (ring) + 16384 + _i * 4096 + t16); } while (0)
  f32x4 acc[8][4] = {};
  RING_LOOP(144, SQ);
  const int rbase = (lane >> 4) << 2, cl = lane & 15;
  #pragma unroll
  for (int i = 0; i < 8; ++i)
    #pragma unroll
    for (int j = 0; j < 4; ++j)
      #pragma unroll
      for (int r = 0; r < 4; ++r) {
        int row = bx * 256 + wm * 128 + i * 16 + rbase + r;
        if (row < 6272) {
          int col = byl * 128 + wn * 64 + j * 16 + cl;
          outp[(size_t)row * 512 + col] = (bf16)acc[i][j][r];
        }
      }
}

// ===========================================================================
// Old 128x128 core (kept for the tiny gemm_s)
// ===========================================================================
__device__ __forceinline__ void tile_compute(const char* ldsA, const char* ldsB,
                                             f32x4 (&acc)[4][4], int wr, int wc, int lane) {
  const int l15 = lane & 15;
  const int colb = (lane >> 4) << 4;
  #pragma unroll
  for (int kk = 0; kk < 2; ++kk) {
    v8bf a[4], b[4];
    #pragma unroll
    for (int i = 0; i < 4; ++i) {
      int ra = wr * 64 + i * 16 + l15;
      int ca = ((kk << 6) | colb) ^ ((ra & 7) << 4);
      a[i] = *(const v8bf*)(ldsA + ra * 128 + ca);
    }
    #pragma unroll
    for (int j = 0; j < 4; ++j) {
      int rb = wc * 64 + j * 16 + l15;
      int cb = ((kk << 6) | colb) ^ ((rb & 7) << 4);
      b[j] = *(const v8bf*)(ldsB + rb * 128 + cb);
    }
    __builtin_amdgcn_s_setprio(1);
    #pragma unroll
    for (int i = 0; i < 4; ++i)
      #pragma unroll
      for (int j = 0; j < 4; ++j)
        acc[i][j] = __builtin_amdgcn_mfma_f32_16x16x32_bf16(a[i], b[j], acc[i][j], 0, 0, 0);
    __builtin_amdgcn_s_setprio(0);
  }
}

#define PIPELINE_LOOP(NK)                                                   \
  stage(0, lds);                                                            \
  stage(1, lds + 32768);                                                    \
  int cur = 0;                                                              \
  for (int ks = 0; ks < (NK) - 1; ++ks) {                                   \
    asm volatile("s_waitcnt vmcnt(8)" ::: "memory");                        \
    __builtin_amdgcn_s_barrier();                                           \
    __builtin_amdgcn_sched_barrier(0);                                      \
    tile_compute(lds + cur * 32768, lds + cur * 32768 + 16384, acc, wr, wc, lane); \
    __builtin_amdgcn_sched_barrier(0);                                      \
    __builtin_amdgcn_s_barrier();                                           \
    __builtin_amdgcn_sched_barrier(0);                                      \
    if (ks + 2 < (NK)) stage(ks + 2, lds + cur * 32768);                    \
    cur ^= 1;                                                               \
  }                                                                         \
  asm volatile("s_waitcnt vmcnt(0)" ::: "memory");                          \
  __builtin_amdgcn_s_barrier();                                             \
  __builtin_amdgcn_sched_barrier(0);                                        \
  tile_compute(lds + cur * 32768, lds + cur * 32768 + 16384, acc, wr, wc, lane);

// G6: w1-conv+ho-mean GEMM, K-split: part[ks] = A_s[:,ksK] @ w1r[:,ksK]^T.
__global__ __launch_bounds__(256)
void k_gemm_s(const bf16* __restrict__ A_s, const bf16* __restrict__ w1r,
              float* __restrict__ part)
{
  __shared__ __attribute__((aligned(16))) char lds[65536];
  const int by = blockIdx.x, kspl = blockIdx.y;
  const int t = threadIdx.x, lane = t & 63, w = t >> 6, wr = w >> 1, wc = w & 1;
  const int tr = t >> 3;
  const int cphys = ((t & 7) << 4) ^ ((tr & 7) << 4);
  const char* pa[4]; const char* pb[4];
  #pragma unroll
  for (int i = 0; i < 4; ++i) {
    int r = i * 32 + tr;
    pa[i] = (const char*)A_s + (size_t)r * 9216 + kspl * 2304 + cphys;
    pb[i] = (const char*)w1r + (size_t)(by * 128 + r) * 9216 + kspl * 2304 + cphys;
  }
  const int lo = t * 16;
  auto stage = [&](int ks, char* base) {
    #pragma unroll
    for (int i = 0; i < 4; ++i) GLDS16(pa[i] + ks * 128, base + lo + i * 4096);
    #pragma unroll
    for (int i = 0; i < 4; ++i) GLDS16(pb[i] + ks * 128, base + 16384 + lo + i * 4096);
  };
  f32x4 acc[4][4] = {};
  PIPELINE_LOOP(18)
  const int rb = (lane >> 4) << 2, cl = lane & 15;
  #pragma unroll
  for (int i = 0; i < 4; ++i)
    #pragma unroll
    for (int j = 0; j < 4; ++j)
      #pragma unroll
      for (int r = 0; r < 4; ++r) {
        int row = wr * 64 + i * 16 + rb + r;
        int col = by * 128 + wc * 64 + j * 16 + cl;
        part[(size_t)kspl * 65536 + row * 512 + col] = acc[i][j][r];
      }
}

// K-split reduce + f7m add -> out[:, :512]
__global__ __launch_bounds__(512)
void k_red(const float* __restrict__ part, const float* __restrict__ f7m,
           float* __restrict__ out)
{
  int idx = blockIdx.x * 512 + threadIdx.x;   // 65536
  float s = part[idx] + part[65536 + idx] + part[131072 + idx] + part[196608 + idx];
  int row = idx >> 9, col = idx & 511;
  out[row * 1024 + col] = s + f7m[idx];
}

// P0: transpose+cast interact (n,2304,256) f32 -> A1 bf16 [(nl*256+p)][2304].
__global__ void k_tin(const float* __restrict__ in, bf16* __restrict__ A1, int n0)
{
  __shared__ float tile[64][36];
  const int k0 = blockIdx.x * 64, p0 = blockIdx.y * 32, nl = blockIdx.z;
  const int n = n0 + nl;
  const int t = threadIdx.x;
  const float* src = in + (size_t)n * 2304 * 256;
  #pragma unroll
  for (int rep = 0; rep < 2; ++rep) {
    int idx = t + rep * 256;
    int row = idx >> 3, c4 = (idx & 7) * 4;
    float4 v = *(const float4*)(src + (size_t)(k0 + row) * 256 + p0 + c4);
    tile[row][c4] = v.x; tile[row][c4 + 1] = v.y;
    tile[row][c4 + 2] = v.z; tile[row][c4 + 3] = v.w;
  }
  __syncthreads();
  const int pl = t >> 3, ke = (t & 7) * 8;
  v8bf o;
  #pragma unroll
  for (int e = 0; e < 8; ++e) o[e] = (bf16)tile[ke + e][pl];
  bf16* dst = A1 + (size_t)nl * 256 * 2304;
  *(v8bf*)(dst + (size_t)(p0 + pl) * 2304 + k0 + ke) = o;
}

// P1: cast w_reduce f32 -> bf16
__global__ void k_castw(const float* __restrict__ wsrc, bf16* __restrict__ wb, int nelem)
{
  int idx = (blockIdx.x * 256 + threadIdx.x) * 4;
  if (idx >= nelem) return;
  float4 v = *(const float4*)(wsrc + idx);
  bf16 o0 = (bf16)v.x, o1 = (bf16)v.y, o2 = (bf16)v.z, o3 = (bf16)v.w;
  bf16* d = wb + idx;
  d[0] = o0; d[1] = o1; d[2] = o2; d[3] = o3;
}

// P2: (co,ci,3,3) f32 -> wt [tensor<4][tap][co][ci] bf16; w1 -> w1r [co][tap][ci]
__global__ void k_wtrans(const float* __restrict__ s0, const float* __restrict__ s1,
                         const float* __restrict__ s2, const float* __restrict__ s3,
                         const float* __restrict__ s4, bf16* __restrict__ wt,
                         bf16* __restrict__ w1r)
{
  const float* src;
  switch (blockIdx.y) {
    case 0: src = s0; break; case 1: src = s1; break; case 2: src = s2; break;
    case 3: src = s3; break; default: src = s4; break;
  }
  int q = blockIdx.x * 256 + threadIdx.x;
  const float* sp = src + (size_t)q * 9;
  float tmp[9];
  #pragma unroll
  for (int e = 0; e < 9; ++e) tmp[e] = sp[e];
  if (blockIdx.y < 4) {
    bf16* dst = wt + (size_t)blockIdx.y * 2359296;
    #pragma unroll
    for (int e = 0; e < 9; ++e) dst[(size_t)e * 262144 + q] = (bf16)tmp[e];
  } else {
    int co = q >> 9, ci = q & 511;
    #pragma unroll
    for (int e = 0; e < 9; ++e) w1r[(size_t)(co * 9 + e) * 512 + ci] = (bf16)tmp[e];
  }
}

// K3: maxpool 3x3 s2 p1, 14x14 -> 7x7, bf16, 2 channels/thread
__global__ void k_pool(const bf16* __restrict__ f14, bf16* __restrict__ f7b)
{
  int idx = blockIdx.x * 256 + threadIdx.x;
  int c2 = idx & 255;
  int pp = idx >> 8;
  int n = pp / 49, p7 = pp - n * 49;
  int y = p7 / 7, x = p7 - 7 * (p7 / 7);
  int y0 = 2 * y - 1, x0 = 2 * x - 1;
  const unsigned* f14u = (const unsigned*)f14;
  float m0 = -3.4e38f, m1 = -3.4e38f;
  #pragma unroll
  for (int dy = 0; dy < 3; ++dy) {
    int iy = y0 + dy; if ((unsigned)iy >= 14u) continue;
    #pragma unroll
    for (int dx = 0; dx < 3; ++dx) {
      int ix = x0 + dx; if ((unsigned)ix >= 14u) continue;
      unsigned vv = f14u[(size_t)(n * 196 + iy * 14 + ix) * 256 + c2];
      m0 = fmaxf(m0, __builtin_bit_cast(float, vv << 16));
      m1 = fmaxf(m1, __builtin_bit_cast(float, vv & 0xffff0000u));
    }
  }
  bf16 b0 = (bf16)m0, b1 = (bf16)m1;
  unsigned pk = (unsigned)__builtin_bit_cast(unsigned short, b0)
              | ((unsigned)__builtin_bit_cast(unsigned short, b1) << 16);
  ((unsigned*)f7b)[idx] = pk;
}

// K5: group attention (8x8 within group, mask from rois)
__global__ __launch_bounds__(256)
void k_attn(const bf16* __restrict__ q, const bf16* __restrict__ k,
            const bf16* __restrict__ v, const float* __restrict__ rois,
            float* __restrict__ virt)
{
  const int p = blockIdx.x, g = blockIdx.y, t = threadIdx.x;
  __shared__ float sS[8][9];
  __shared__ float sP[8][9];
  __shared__ __attribute__((aligned(16))) bf16 sV[8][512];
  {
    int u = t;
    #pragma unroll
    for (int rep = 0; rep < 2; ++rep, u += 256) {
      int j = u >> 6, ch = u & 63;
      *(v8bf*)&sV[j][ch * 8] = *(const v8bf*)(v + ((size_t)(g * 8 + j) * 49 + p) * 512 + ch * 8);
    }
  }
  int pi = t >> 2, ls = t & 3;
  int i = pi >> 3, j = pi & 7;
  const bf16* qi = q + ((size_t)(g * 8 + i) * 49 + p) * 512;
  const bf16* kj = k + ((size_t)(g * 8 + j) * 49 + p) * 512;
  float s = 0.f;
  for (int ch = ls * 16; ch < ls * 16 + 16; ++ch) {
    v8bf a = *(const v8bf*)(qi + ch * 8);
    v8bf b = *(const v8bf*)(kj + ch * 8);
    #pragma unroll
    for (int e = 0; e < 8; ++e) s += (float)a[e] * (float)b[e];
  }
  s += __shfl_xor(s, 1);
  s += __shfl_xor(s, 2);
  if (ls == 0) sS[i][j] = s * 0.04419417382415922f;
  __syncthreads();
  if (t < 8) {
    float gi = rois[(g * 8 + t) * 5];
    float pv[8]; float mx = -3.4e38f;
    #pragma unroll
    for (int jj = 0; jj < 8; ++jj) {
      float gj = rois[(g * 8 + jj) * 5];
      float sv = (gi == gj) ? sS[t][jj] : -1e30f;
      pv[jj] = sv; mx = fmaxf(mx, sv);
    }
    float sum = 0.f;
    #pragma unroll
    for (int jj = 0; jj < 8; ++jj) { float e = expf(pv[jj] - mx); pv[jj] = e; sum += e; }
    float inv = 1.f / sum;
    #pragma unroll
    for (int jj = 0; jj < 8; ++jj) sP[t][jj] = pv[jj] * inv;
  }
  __syncthreads();
  int i2 = t >> 5, c0 = (t & 31) * 16;
  float o[16];
  #pragma unroll
  for (int e = 0; e < 16; ++e) o[e] = 0.f;
  #pragma unroll
  for (int jj = 0; jj < 8; ++jj) {
    float ww = sP[i2][jj];
    v8bf v0 = *(const v8bf*)&sV[jj][c0];
    v8bf v1 = *(const v8bf*)&sV[jj][c0 + 8];
    #pragma unroll
    for (int e = 0; e < 8; ++e) { o[e] += ww * (float)v0[e]; o[8 + e] += ww * (float)v1[e]; }
  }
  float* dst = virt + ((size_t)(g * 8 + i2) * 49 + p) * 512 + c0;
  #pragma unroll
  for (int e = 0; e < 16; ++e) dst[e] = o[e];
}

// K6: fused LN(stats+apply)+windowed-sums (blocks 0..127) and fc (128..255).
__global__ __launch_bounds__(512)
void k_ln_fc(const float* __restrict__ virt, const float* __restrict__ gamma,
             const float* __restrict__ beta, const bf16* __restrict__ f7b,
             bf16* __restrict__ A_s, float* __restrict__ f7m,
             const float* __restrict__ obm, const float* __restrict__ wfc,
             float* __restrict__ out)
{
  const int t = threadIdx.x;
  if (blockIdx.x >= 128) {
    __shared__ float sO[1024];
    int n = blockIdx.x - 128;
    for (int u = t; u < 1024; u += 512) sO[u] = obm[n * 1024 + u];
    __syncthreads();
    const float4* wp = (const float4*)(wfc + (size_t)t * 1024);
    float s = 0.f;
    for (int c4 = 0; c4 < 256; ++c4) {
      float4 w = wp[c4];
      s += w.x * sO[c4 * 4] + w.y * sO[c4 * 4 + 1] + w.z * sO[c4 * 4 + 2] + w.w * sO[c4 * 4 + 3];
    }
    out[n * 1024 + 512 + t] = fmaxf(s, 0.f);
    return;
  }
  const int n = blockIdx.x;
  const float* p = virt + (size_t)n * 25088 + t;
  float xv[49];
  float s1 = 0.f, s2 = 0.f;
  #pragma unroll
  for (int pp = 0; pp < 49; ++pp) {
    float x = p[pp * 512];
    xv[pp] = x; s1 += x; s2 += x * x;
  }
  __shared__ float r1[512], r2[512];
  r1[t] = s1; r2[t] = s2; __syncthreads();
  for (int off = 256; off; off >>= 1) {
    if (t < off) { r1[t] += r1[t + off]; r2[t] += r2[t + off]; }
    __syncthreads();
  }
  float mu = r1[0] * (1.f / 25088.f);
  float var = r2[0] * (1.f / 25088.f) - mu * mu;
  float rstd = rsqrtf(var + 1e-5f);
  float g = gamma[t], be = beta[t];
  const bf16* fp = f7b + (size_t)n * 25088 + t;
  float T = 0, R0 = 0, R6 = 0, C0 = 0, C6 = 0;
  float X00 = 0, X06 = 0, X60 = 0, X66 = 0, F = 0;
  #pragma unroll
  for (int pp = 0; pp < 49; ++pp) {
    const int u = pp / 7, v = pp - 7 * (pp / 7);
    float y = fmaxf((xv[pp] - mu) * rstd * g + be, 0.f);
    T += y;
    if (u == 0) R0 += y;
    if (u == 6) R6 += y;
    if (v == 0) C0 += y;
    if (v == 6) C6 += y;
    if (pp == 0)  X00 = y;
    if (pp == 6)  X06 = y;
    if (pp == 42) X60 = y;
    if (pp == 48) X66 = y;
    F += (float)fp[pp * 512];
  }
  float sv[9] = { T-R6-C6+X66, T-R6, T-R6-C0+X60,
                  T-C6,        T,    T-C0,
                  T-R0-C6+X06, T-R0, T-R0-C0+X00 };
  bf16* Ap = A_s + (size_t)n * 4608 + t;
  #pragma unroll
  for (int tap = 0; tap < 9; ++tap)
    Ap[tap * 512] = (bf16)(sv[tap] * (1.f / 49.f));
  f7m[n * 512 + t] = F * (1.f / 49.f);
}

// ---------------------------------------------------------------------------
extern "C" void kernel_launch(void* const* d_in, const int* in_sizes, int n_in,
                              void* d_out, int out_size, void* d_ws, size_t ws_size,
                              hipStream_t stream) {
  const float* rois     = (const float*)d_in[0];
  const float* interact = (const float*)d_in[1];
  const float* bbox     = (const float*)d_in[2];
  const float* w_reduce = (const float*)d_in[3];
  const float* w_rsize  = (const float*)d_in[4];
  const float* wq       = (const float*)d_in[5];
  const float* wk       = (const float*)d_in[6];
  const float* wv       = (const float*)d_in[7];
  const float* w1       = (const float*)d_in[8];
  const float* gamma    = (const float*)d_in[9];
  const float* beta     = (const float*)d_in[10];
  const float* wfc      = (const float*)d_in[11];
  float* out = (float*)d_out;
  char* ws = (char*)d_ws;

  size_t o = 0;
  auto take = [&](size_t sz) { size_t r = o; o += (sz + 255) & ~(size_t)255; return r; };
  bf16*  wrb   = (bf16*)(ws + take(2359296));
  bf16*  wt    = (bf16*)(ws + take(18874368));   // [4][9][512][512] bf16 (rsize,q,k,v)
  bf16*  w1r   = (bf16*)(ws + take(4718592));    // [512 co][9 tap][512 ci] bf16
  char*  Rf1   = ws + take(33554432);            // f1 (33.6MB) -> later q,k,v (19.3MB)
  bf16*  f7b   = (bf16*)(ws + take(6422528));
  float* virt  = (float*)(ws + take(12845056));
  bf16*  A_s   = (bf16*)(ws + take(1179648));
  float* f7m   = (float*)(ws + take(262144));
  float* part  = (float*)(ws + take(1048576));   // [4 ks][128][512] f32
  float* obm   = (float*)(ws + take(524288));
  bf16*  zp    = (bf16*)(ws + take(256));
  size_t fixedEnd = o;
  const size_t A1_FULL = 150994944;
  bool full = (ws_size >= fixedEnd + A1_FULL);
  bf16* A1  = (bf16*)(ws + fixedEnd);
  bf16* f14 = (bf16*)(ws + fixedEnd);

  bf16* f1 = (bf16*)Rf1;
  bf16* qb = (bf16*)Rf1;
  bf16* kb = qb + 3211264;
  bf16* vb = kb + 3211264;

  hipMemsetAsync(zp, 0, 256, stream);

  k_castw<<<1152, 256, 0, stream>>>(w_reduce, wrb, 1179648);
  k_wtrans<<<dim3(1024, 5), 256, 0, stream>>>(w_rsize, wq, wk, wv, w1, wt, w1r);

  if (full) {
    k_tin<<<dim3(36, 8, 128), 256, 0, stream>>>(interact, A1, 0);
    k_gemm_reduce<<<512, 256, 0, stream>>>(A1, wrb, f1, 0);
  } else {
    for (int ch = 0; ch < 4; ++ch) {
      k_tin<<<dim3(36, 8, 32), 256, 0, stream>>>(interact, A1, ch * 32);
      k_gemm_reduce<<<128, 256, 0, stream>>>(A1, wrb, f1, ch * 8192);
    }
  }

  k_conv_rsize<<<392, 256, 0, stream>>>(f1, wt, f14);
  k_pool<<<6272, 256, 0, stream>>>(f14, f7b);

  // fused qkv convs (blocks 0-299) + obm (300-2347)
  k_conv_qkv<<<2348, 256, 0, stream>>>(f7b, wt + (size_t)1 * 2359296, qb, zp, bbox, obm);

  k_attn<<<dim3(49, 16), 256, 0, stream>>>(qb, kb, vb, rois, virt);

  k_ln_fc<<<256, 512, 0, stream>>>(virt, gamma, beta, f7b, A_s, f7m, obm, wfc, out);

  k_gemm_s<<<dim3(4, 4), 256, 0, stream>>>(A_s, w1r, part);
  k_red<<<128, 512, 0, stream>>>(part, f7m, out);
}